// Round 3
// baseline (918.296 us; speedup 1.0000x reference)
//
#include <hip/hip_runtime.h>
#include <hip/hip_bf16.h>
#include <math.h>

#define B2    2048
#define NPM   30
#define EPM   120

// ---------------------------------------------------------------------------
// 4x4 micro-tile FMA helper
// ---------------------------------------------------------------------------
__device__ __forceinline__ void fma44(float (&acc)[4][4], const float4 a, const float4 w) {
  acc[0][0] = fmaf(a.x, w.x, acc[0][0]); acc[0][1] = fmaf(a.x, w.y, acc[0][1]);
  acc[0][2] = fmaf(a.x, w.z, acc[0][2]); acc[0][3] = fmaf(a.x, w.w, acc[0][3]);
  acc[1][0] = fmaf(a.y, w.x, acc[1][0]); acc[1][1] = fmaf(a.y, w.y, acc[1][1]);
  acc[1][2] = fmaf(a.y, w.z, acc[1][2]); acc[1][3] = fmaf(a.y, w.w, acc[1][3]);
  acc[2][0] = fmaf(a.z, w.x, acc[2][0]); acc[2][1] = fmaf(a.z, w.y, acc[2][1]);
  acc[2][2] = fmaf(a.z, w.z, acc[2][2]); acc[2][3] = fmaf(a.z, w.w, acc[2][3]);
  acc[3][0] = fmaf(a.w, w.x, acc[3][0]); acc[3][1] = fmaf(a.w, w.y, acc[3][1]);
  acc[3][2] = fmaf(a.w, w.z, acc[3][2]); acc[3][3] = fmaf(a.w, w.w, acc[3][3]);
}

// ---------------------------------------------------------------------------
// S1: per-molecule degrees, rsqrt factors, layer-1 scatter in LDS.
// Writes agg1[node][80] (cols 74..79 = 0), rsOv[node], rsIv[node].
// grid = ng*2048 (g0 = starting graph).
// ---------------------------------------------------------------------------
__global__ __launch_bounds__(256) void s1_kernel(
    const float* __restrict__ h1, const float* __restrict__ h2,
    const int* __restrict__ src1, const int* __restrict__ dst1,
    const int* __restrict__ src2, const int* __restrict__ dst2,
    float* __restrict__ agg1, float* __restrict__ rsOv, float* __restrict__ rsIv,
    int g0)
{
  const int bid = blockIdx.x;
  const int gl  = bid >> 11;             // local graph index
  const int g   = g0 + gl;               // actual graph 0/1
  const int m   = bid & 2047;
  const int tid = threadIdx.x;
  const float* hsrc = g ? h2 : h1;
  const int*   src  = g ? src2 : src1;
  const int*   dst  = g ? dst2 : dst1;

  __shared__ float XB[NPM * 74];
  __shared__ float AG[NPM * 80];
  __shared__ int   esrc[EPM], edst[EPM];
  __shared__ int   degO[32], degI[32];
  __shared__ float rsO[32], rsI[32];

  if (tid < 32) { degO[tid] = 0; degI[tid] = 0; }
  for (int i = tid; i < NPM * 80; i += 256) AG[i] = 0.f;
  __syncthreads();
  if (tid < EPM) {
    int s = src[m * EPM + tid] - m * NPM;
    int d = dst[m * EPM + tid] - m * NPM;
    esrc[tid] = s; edst[tid] = d;
    atomicAdd(&degO[s], 1); atomicAdd(&degI[d], 1);
  }
  __syncthreads();
  if (tid < NPM) {
    rsO[tid] = rsqrtf((float)max(degO[tid], 1));
    rsI[tid] = rsqrtf((float)max(degI[tid], 1));
    int node = (gl * B2 + m) * NPM + tid;
    rsOv[node] = rsO[tid]; rsIv[node] = rsI[tid];
  }
  __syncthreads();
  for (int i = tid; i < NPM * 74; i += 256) {
    int r = i / 74;
    XB[i] = hsrc[m * (NPM * 74) + i] * rsO[r];
  }
  __syncthreads();
  for (int i = tid; i < EPM * 74; i += 256) {
    int e = i / 74, c = i - e * 74;
    atomicAdd(&AG[edst[e] * 80 + c], XB[esrc[e] * 74 + c]);
  }
  __syncthreads();
  const long base = (long)((gl * B2 + m) * NPM) * 80;
  for (int i = tid; i < NPM * 80; i += 256) {
    int r = i / 80, c = i - r * 80;
    agg1[base + i] = (c < 74) ? AG[i] * rsI[r] : 0.f;
  }
}

// ---------------------------------------------------------------------------
// G1: t1s = relu(agg1 @ Wg1 + bg1) * rsOv[row].
// A: [M][80] (K padded to 80), W: [74][128] (rows >=74 guarded to 0).
// Single K-chunk staged fully in LDS. grid = (M/64, 2).
// ---------------------------------------------------------------------------
__global__ __launch_bounds__(256) void g1_kernel(
    const float* __restrict__ A, const float* __restrict__ W,
    const float* __restrict__ bias, const float* __restrict__ rsOv,
    float* __restrict__ C)
{
  __shared__ float At[80 * 64];   // [k][r]
  __shared__ float Ws[80 * 64];   // [k][c]
  const int tid = threadIdx.x;
  const int rowBase = blockIdx.x * 64, colBase = blockIdx.y * 64;
  const int rgrp = tid >> 4, cgrp = tid & 15;
  const int r0 = rgrp * 4, c0 = cgrp * 4;

  for (int t = tid; t < 1280; t += 256) {
    int row = t & 63, k = (t >> 6) << 2;
    float4 v = *(const float4*)&A[(long)(rowBase + row) * 80 + k];
    At[(k + 0) * 64 + row] = v.x; At[(k + 1) * 64 + row] = v.y;
    At[(k + 2) * 64 + row] = v.z; At[(k + 3) * 64 + row] = v.w;
  }
  for (int t = tid; t < 1280; t += 256) {
    int d = t >> 4, c4 = (t & 15) << 2;
    float4 w = (d < 74) ? *(const float4*)&W[d * 128 + colBase + c4]
                        : make_float4(0.f, 0.f, 0.f, 0.f);
    *(float4*)&Ws[d * 64 + c4] = w;
  }
  __syncthreads();
  float acc[4][4] = {{0.f}};
  #pragma unroll 8
  for (int d = 0; d < 80; ++d) {
    float4 a = *(const float4*)&At[d * 64 + r0];
    float4 w = *(const float4*)&Ws[d * 64 + c0];
    fma44(acc, a, w);
  }
  float4 bv = *(const float4*)&bias[colBase + c0];
  for (int i = 0; i < 4; ++i) {
    float s = rsOv[rowBase + r0 + i];
    float4 o;
    o.x = fmaxf(acc[i][0] + bv.x, 0.f) * s;
    o.y = fmaxf(acc[i][1] + bv.y, 0.f) * s;
    o.z = fmaxf(acc[i][2] + bv.z, 0.f) * s;
    o.w = fmaxf(acc[i][3] + bv.w, 0.f) * s;
    *(float4*)&C[(long)(rowBase + r0 + i) * 128 + colBase + c0] = o;
  }
}

// ---------------------------------------------------------------------------
// S2: layer-2 scatter. agg2[node][128] = rsI * scatter(t1s).
// grid = ng*2048.
// ---------------------------------------------------------------------------
__global__ __launch_bounds__(256) void s2_kernel(
    const float* __restrict__ t1s,
    const int* __restrict__ src1, const int* __restrict__ dst1,
    const int* __restrict__ src2, const int* __restrict__ dst2,
    const float* __restrict__ rsIv, float* __restrict__ agg2, int g0)
{
  const int bid = blockIdx.x;
  const int gl = bid >> 11, g = g0 + gl, m = bid & 2047;
  const int tid = threadIdx.x;
  const int* src = g ? src2 : src1;
  const int* dst = g ? dst2 : dst1;
  __shared__ float AG[NPM * 128];
  __shared__ int esrc[EPM], edst[EPM];
  for (int i = tid; i < NPM * 128; i += 256) AG[i] = 0.f;
  if (tid < EPM) {
    esrc[tid] = src[m * EPM + tid] - m * NPM;
    edst[tid] = dst[m * EPM + tid] - m * NPM;
  }
  __syncthreads();
  const long nb = (long)(gl * B2 + m) * NPM;
  for (int i = tid; i < EPM * 128; i += 256) {
    int e = i >> 7, c = i & 127;
    atomicAdd(&AG[edst[e] * 128 + c], t1s[(nb + esrc[e]) * 128 + c]);
  }
  __syncthreads();
  for (int i = tid; i < NPM * 128; i += 256) {
    int r = i >> 7;
    agg2[nb * 128 + i] = AG[i] * rsIv[nb + r];
  }
}

// ---------------------------------------------------------------------------
// G2+pool: t2 = relu(agg2 @ Wg2 + bg2); xcat[mol] = mean_rows(t2)*sf.
// Molecule-aligned 60-row tiles (2 molecules/block). grid = (M/60, 2).
// ---------------------------------------------------------------------------
__global__ __launch_bounds__(256) void g2pool_kernel(
    const float* __restrict__ A, const float* __restrict__ W,
    const float* __restrict__ bias, const float* __restrict__ s1x,
    float* __restrict__ xcat, int Mrows, int gmbase)
{
  __shared__ float At[64 * 64];
  __shared__ float Ws[64 * 64];
  __shared__ float cs[2 * 64];
  const int tid = threadIdx.x;
  const int rowBase = blockIdx.x * 60, colBase = blockIdx.y * 64;
  const int rgrp = tid >> 4, cgrp = tid & 15;
  const int r0 = rgrp * 4, c0 = cgrp * 4;
  if (tid < 128) cs[tid] = 0.f;
  float acc[4][4] = {{0.f}};
  for (int k0 = 0; k0 < 128; k0 += 64) {
    for (int t = tid; t < 1024; t += 256) {
      int row = t & 63, kk = (t >> 6) << 2;
      float4 v = make_float4(0.f, 0.f, 0.f, 0.f);
      if (rowBase + row < Mrows)
        v = *(const float4*)&A[(long)(rowBase + row) * 128 + k0 + kk];
      At[(kk + 0) * 64 + row] = v.x; At[(kk + 1) * 64 + row] = v.y;
      At[(kk + 2) * 64 + row] = v.z; At[(kk + 3) * 64 + row] = v.w;
    }
    for (int t = tid; t < 1024; t += 256) {
      int d = t >> 4, c4 = (t & 15) << 2;
      *(float4*)&Ws[d * 64 + c4] = *(const float4*)&W[(k0 + d) * 128 + colBase + c4];
    }
    __syncthreads();
    #pragma unroll 8
    for (int d = 0; d < 64; ++d) {
      float4 a = *(const float4*)&At[d * 64 + r0];
      float4 w = *(const float4*)&Ws[d * 64 + c0];
      fma44(acc, a, w);
    }
    __syncthreads();
  }
  float4 bv = *(const float4*)&bias[colBase + c0];
  for (int i = 0; i < 4; ++i) {
    int lr = r0 + i;
    if (lr < 60) {
      int moll = (lr >= NPM) ? 1 : 0;
      atomicAdd(&cs[moll * 64 + c0 + 0], fmaxf(acc[i][0] + bv.x, 0.f));
      atomicAdd(&cs[moll * 64 + c0 + 1], fmaxf(acc[i][1] + bv.y, 0.f));
      atomicAdd(&cs[moll * 64 + c0 + 2], fmaxf(acc[i][2] + bv.z, 0.f));
      atomicAdd(&cs[moll * 64 + c0 + 3], fmaxf(acc[i][3] + bv.w, 0.f));
    }
  }
  __syncthreads();
  if (tid < 128) {
    int moll = tid >> 6, c = tid & 63;
    int gm = gmbase + (rowBase / 30) + moll;     // global pooled-row index
    int gg = gm >> 11, mm = gm & 2047;
    float sf = gg ? (1.f - s1x[mm]) : s1x[mm];
    xcat[gm * 128 + colBase + c] = cs[moll * 64 + c] * (1.f / 30.f) * sf;
  }
}

// ---------------------------------------------------------------------------
// Generic fp32 GEMM: C = [relu]( A(MxK) @ W(KxN) [+ bias] ).  64x64 tile.
// ---------------------------------------------------------------------------
template<int RELU, int BIAS>
__global__ __launch_bounds__(256) void gemm_kernel(
    const float* __restrict__ A, const float* __restrict__ W,
    const float* __restrict__ bias, float* __restrict__ C,
    int M, int Ncols, int K)
{
  __shared__ float At[64 * 64];
  __shared__ float Ws[64 * 64];
  const int tid = threadIdx.x;
  const int rowBase = blockIdx.x * 64, colBase = blockIdx.y * 64;
  const int rgrp = tid >> 4, cgrp = tid & 15;
  const int r0 = rgrp * 4, c0 = cgrp * 4;
  float acc[4][4] = {{0.f}};
  for (int k0 = 0; k0 < K; k0 += 64) {
    for (int t = tid; t < 1024; t += 256) {
      int row = t & 63, kk = (t >> 6) << 2;
      float4 v = *(const float4*)&A[(rowBase + row) * K + k0 + kk];
      At[(kk + 0) * 64 + row] = v.x; At[(kk + 1) * 64 + row] = v.y;
      At[(kk + 2) * 64 + row] = v.z; At[(kk + 3) * 64 + row] = v.w;
    }
    for (int t = tid; t < 1024; t += 256) {
      int d = t >> 4, c4 = (t & 15) << 2;
      *(float4*)&Ws[d * 64 + c4] = *(const float4*)&W[(k0 + d) * Ncols + colBase + c4];
    }
    __syncthreads();
    #pragma unroll 8
    for (int d = 0; d < 64; ++d) {
      float4 a = *(const float4*)&At[d * 64 + r0];
      float4 w = *(const float4*)&Ws[d * 64 + c0];
      fma44(acc, a, w);
    }
    __syncthreads();
  }
  float4 bv = make_float4(0.f, 0.f, 0.f, 0.f);
  if (BIAS) bv = *(const float4*)&bias[colBase + c0];
  for (int i = 0; i < 4; ++i) {
    float4 o;
    o.x = acc[i][0] + bv.x; o.y = acc[i][1] + bv.y;
    o.z = acc[i][2] + bv.z; o.w = acc[i][3] + bv.w;
    if (RELU) { o.x = fmaxf(o.x, 0.f); o.y = fmaxf(o.y, 0.f); o.z = fmaxf(o.z, 0.f); o.w = fmaxf(o.w, 0.f); }
    *(float4*)&C[(rowBase + r0 + i) * Ncols + colBase + c0] = o;
  }
}

// ---------------------------------------------------------------------------
// Classifier layer 1 on concatenated halves: o1 = relu([x[:B]|x[B:]] @ W + b)
// ---------------------------------------------------------------------------
__global__ __launch_bounds__(256) void gemm_cat_kernel(
    const float* __restrict__ X, const float* __restrict__ W,
    const float* __restrict__ bias, float* __restrict__ C)
{
  __shared__ float At[64 * 64];
  __shared__ float Ws[64 * 64];
  const int tid = threadIdx.x;
  const int rowBase = blockIdx.x * 64, colBase = blockIdx.y * 64;
  const int rgrp = tid >> 4, cgrp = tid & 15;
  const int r0 = rgrp * 4, c0 = cgrp * 4;
  float acc[4][4] = {{0.f}};
  for (int k0 = 0; k0 < 256; k0 += 64) {
    const float* base = (k0 < 128) ? X : (X + B2 * 128);
    const int kc = k0 & 127;
    for (int t = tid; t < 1024; t += 256) {
      int row = t & 63, kk = (t >> 6) << 2;
      float4 v = *(const float4*)&base[(rowBase + row) * 128 + kc + kk];
      At[(kk + 0) * 64 + row] = v.x; At[(kk + 1) * 64 + row] = v.y;
      At[(kk + 2) * 64 + row] = v.z; At[(kk + 3) * 64 + row] = v.w;
    }
    for (int t = tid; t < 1024; t += 256) {
      int d = t >> 4, c4 = (t & 15) << 2;
      *(float4*)&Ws[d * 64 + c4] = *(const float4*)&W[(k0 + d) * 128 + colBase + c4];
    }
    __syncthreads();
    #pragma unroll 8
    for (int d = 0; d < 64; ++d) {
      float4 a = *(const float4*)&At[d * 64 + r0];
      float4 w = *(const float4*)&Ws[d * 64 + c0];
      fma44(acc, a, w);
    }
    __syncthreads();
  }
  float4 bv = *(const float4*)&bias[colBase + c0];
  for (int i = 0; i < 4; ++i) {
    float4 o;
    o.x = fmaxf(acc[i][0] + bv.x, 0.f); o.y = fmaxf(acc[i][1] + bv.y, 0.f);
    o.z = fmaxf(acc[i][2] + bv.z, 0.f); o.w = fmaxf(acc[i][3] + bv.w, 0.f);
    *(float4*)&C[(rowBase + r0 + i) * 128 + colBase + c0] = o;
  }
}

// ---------------------------------------------------------------------------
// Fused z-GEMM + eh-fold (eh MLP layer-1 computed inline).
// ---------------------------------------------------------------------------
__global__ __launch_bounds__(256) void zfold_kernel(
    const float* __restrict__ xp, const float* __restrict__ We2,
    const float* __restrict__ interhb, const float* __restrict__ ia1,
    const float* __restrict__ ia2, const float* __restrict__ We1,
    const float* __restrict__ be1,
    float* __restrict__ aggA, float* __restrict__ aggB)
{
  __shared__ float xsT[128 * 36];
  __shared__ float Ws[64 * 128];
  __shared__ float ehs[3][16][32];
  __shared__ float accAs[16 * 128], accBs[16 * 128];
  const int tid = threadIdx.x;
  const int mg = blockIdx.x >> 1, kh = blockIdx.x & 1;
  const int i0 = mg * 16;

  for (int t = tid; t < 1024; t += 256) {
    int row = t & 31, d4 = t >> 5;
    int gr = (row < 16) ? (i0 + row) : (B2 + i0 + row - 16);
    float4 v = *(const float4*)&xp[gr * 128 + d4 * 4];
    xsT[(d4 * 4 + 0) * 36 + row] = v.x; xsT[(d4 * 4 + 1) * 36 + row] = v.y;
    xsT[(d4 * 4 + 2) * 36 + row] = v.z; xsT[(d4 * 4 + 3) * 36 + row] = v.w;
  }
  for (int t = tid; t < 512; t += 256) {
    int mm = t >> 5, k = t & 31;
    float a = We1[k], b = be1[k];
    ehs[0][mm][k] = fmaxf(fmaf(interhb[i0 + mm], a, b), 0.f);
    ehs[1][mm][k] = fmaxf(fmaf(ia1[i0 + mm],     a, b), 0.f);
    ehs[2][mm][k] = fmaxf(fmaf(ia2[i0 + mm],     a, b), 0.f);
  }
  for (int t = tid; t < 16 * 128; t += 256) { accAs[t] = 0.f; accBs[t] = 0.f; }

  const int rgrp = tid >> 5, cgrp = tid & 31;
  const int r0 = rgrp * 4, c0 = cgrp * 4;
  const int side = rgrp >> 2;
  float accLo[4][4] = {{0.f}}, accHi[4][4] = {{0.f}};

  for (int kk = 0; kk < 16; ++kk) {
    const int k = kh * 16 + kk;
    float z[4][4] = {{0.f}};
    for (int ch = 0; ch < 2; ++ch) {
      __syncthreads();
      for (int t = tid; t < 2048; t += 256) {
        int d = t >> 5, c4 = (t & 31) << 2;
        *(float4*)&Ws[d * 128 + c4] =
            *(const float4*)&We2[k * 16384 + (ch * 64 + d) * 128 + c4];
      }
      __syncthreads();
      #pragma unroll 4
      for (int d = 0; d < 64; ++d) {
        float4 a = *(const float4*)&xsT[(ch * 64 + d) * 36 + r0];
        float4 w = *(const float4*)&Ws[d * 128 + c0];
        fma44(z, a, w);
      }
    }
    #pragma unroll
    for (int i = 0; i < 4; ++i) {
      int mm = (r0 + i) & 15;
      float uLo = side ? ehs[0][mm][k] : ehs[1][mm][k];
      float uHi = side ? ehs[2][mm][k] : ehs[0][mm][k];
      #pragma unroll
      for (int j = 0; j < 4; ++j) {
        accLo[i][j] = fmaf(uLo, z[i][j], accLo[i][j]);
        accHi[i][j] = fmaf(uHi, z[i][j], accHi[i][j]);
      }
    }
  }
  __syncthreads();
  for (int i = 0; i < 4; ++i) {
    int mm = (r0 + i) & 15;
    for (int j = 0; j < 4; ++j) {
      atomicAdd(&accAs[mm * 128 + c0 + j], accLo[i][j]);
      atomicAdd(&accBs[mm * 128 + c0 + j], accHi[i][j]);
    }
  }
  __syncthreads();
  for (int t = tid; t < 2048; t += 256) {
    int mm = t >> 7, c = t & 127;
    atomicAdd(&aggA[(i0 + mm) * 128 + c], accAs[mm * 128 + c]);
    atomicAdd(&aggB[(i0 + mm) * 128 + c], accBs[mm * 128 + c]);
  }
}

__global__ __launch_bounds__(256) void xin_kernel(
    const float* __restrict__ aggA, const float* __restrict__ aggB,
    const float* __restrict__ zb, const float* __restrict__ bnn,
    float* __restrict__ x_in)
{
  int idx = blockIdx.x * 256 + threadIdx.x;
  int i = idx >> 7, c = idx & 127;
  float zs = zb[i * 128 + c] + zb[(i + B2) * 128 + c] + bnn[c];
  x_in[i * 128 + c]        = fmaxf(aggA[idx] + zs, 0.f);
  x_in[(i + B2) * 128 + c] = fmaxf(aggB[idx] + zs, 0.f);
}

__global__ __launch_bounds__(256) void gru_kernel(
    const float* __restrict__ gi, const float* __restrict__ gh,
    const float* __restrict__ xp, float* __restrict__ xnew)
{
  int idx = blockIdx.x * 256 + threadIdx.x;
  int n = idx >> 7, j = idx & 127;
  float ir = gi[n * 384 + j], iz = gi[n * 384 + 128 + j], ih = gi[n * 384 + 256 + j];
  float hr = gh[n * 384 + j], hz = gh[n * 384 + 128 + j], hn = gh[n * 384 + 256 + j];
  float h  = xp[idx];
  float r  = 1.f / (1.f + expf(-(ir + hr)));
  float zg = 1.f / (1.f + expf(-(iz + hz)));
  float ng = tanhf(ih + r * hn);
  xnew[idx] = (1.f - zg) * ng + zg * h;
}

__global__ __launch_bounds__(256) void final_kernel(
    const float* __restrict__ o2, const float* __restrict__ Wcl3,
    const float* __restrict__ bcl3, float* __restrict__ out)
{
  int idx = blockIdx.x * 256 + threadIdx.x;
  int i = idx >> 1, c = idx & 1;
  float acc = bcl3[c];
  for (int k = 0; k < 128; ++k) acc = fmaf(o2[i * 128 + k], Wcl3[k * 2 + c], acc);
  out[idx] = acc;
}

// ---------------------------------------------------------------------------
extern "C" void kernel_launch(void* const* d_in, const int* in_sizes, int n_in,
                              void* d_out, int out_size, void* d_ws, size_t ws_size,
                              hipStream_t stream)
{
  const float* h1   = (const float*)d_in[0];
  const float* h2   = (const float*)d_in[1];
  const float* s1x  = (const float*)d_in[2];
  const float* ihb  = (const float*)d_in[3];
  const float* ia1  = (const float*)d_in[4];
  const float* ia2  = (const float*)d_in[5];
  const float* Wg1  = (const float*)d_in[6];
  const float* bg1  = (const float*)d_in[7];
  const float* Wg2  = (const float*)d_in[8];
  const float* bg2  = (const float*)d_in[9];
  const float* Wp   = (const float*)d_in[10];
  const float* bp   = (const float*)d_in[11];
  const float* We1  = (const float*)d_in[12];
  const float* be1  = (const float*)d_in[13];
  const float* We2  = (const float*)d_in[14];
  const float* be2  = (const float*)d_in[15];
  const float* bnn  = (const float*)d_in[16];
  const float* Wih  = (const float*)d_in[17];
  const float* bih  = (const float*)d_in[18];
  const float* Whh  = (const float*)d_in[19];
  const float* bhh  = (const float*)d_in[20];
  const float* Wcl1 = (const float*)d_in[21];
  const float* bcl1 = (const float*)d_in[22];
  const float* Wcl2 = (const float*)d_in[23];
  const float* bcl2 = (const float*)d_in[24];
  const float* Wcl3 = (const float*)d_in[25];
  const float* bcl3 = (const float*)d_in[26];
  const int*   src1 = (const int*)d_in[27];
  const int*   dst1 = (const int*)d_in[28];
  const int*   src2 = (const int*)d_in[29];
  const int*   dst2 = (const int*)d_in[30];
  float* out = (float*)d_out;
  float* ws  = (float*)d_ws;

  // Path selection (deterministic: depends only on ws_size).
  // full: both graphs in one pass; seq: per-graph, halved buffers.
  const size_t needFull = (size_t)(15728640 + 9830400 + 15728640 + 2 * 122880 + 6815744) * 4;
  const int full = (ws_size >= needFull) ? 1 : 0;
  const int ng = full ? 2 : 1;
  const long TS = (long)61440 * ng * 128;   // t1s / agg2 size
  const long A1 = (long)61440 * ng * 80;    // agg1 size
  const long NN = (long)61440 * ng;         // node count per pass

  float* t1s  = ws;
  float* agg1 = ws + TS;
  float* agg2 = ws + TS + A1;
  float* rsOv = ws + TS + A1 + TS;
  float* rsIv = rsOv + NN;
  float* dwn  = rsIv + NN;                  // downstream region

  float* xcat = dwn;
  float* xp   = dwn + 524288;
  float* zb   = dwn + 1048576;
  float* aggA = dwn + 1572864;
  float* aggB = dwn + 1835008;
  float* x_in = dwn + 2097152;
  float* gi   = dwn + 2621440;
  float* gh   = dwn + 4194304;
  float* xnew = dwn + 5767168;
  float* o1   = dwn + 6291456;
  float* o2   = dwn + 6553600;

  // ---- GraphConv pipeline ----
  if (full) {
    s1_kernel<<<4096, 256, 0, stream>>>(h1, h2, src1, dst1, src2, dst2,
                                        agg1, rsOv, rsIv, 0);
    g1_kernel<<<dim3(1920, 2), 256, 0, stream>>>(agg1, Wg1, bg1, rsOv, t1s);
    s2_kernel<<<4096, 256, 0, stream>>>(t1s, src1, dst1, src2, dst2, rsIv, agg2, 0);
    g2pool_kernel<<<dim3(2048, 2), 256, 0, stream>>>(agg2, Wg2, bg2, s1x, xcat,
                                                     122880, 0);
  } else {
    for (int g = 0; g < 2; ++g) {
      s1_kernel<<<2048, 256, 0, stream>>>(h1, h2, src1, dst1, src2, dst2,
                                          agg1, rsOv, rsIv, g);
      g1_kernel<<<dim3(960, 2), 256, 0, stream>>>(agg1, Wg1, bg1, rsOv, t1s);
      s2_kernel<<<2048, 256, 0, stream>>>(t1s, src1, dst1, src2, dst2, rsIv, agg2, g);
      g2pool_kernel<<<dim3(1024, 2), 256, 0, stream>>>(agg2, Wg2, bg2, s1x, xcat,
                                                       61440, g * 2048);
    }
  }

  // ---- solvent-system MPNN + GRU + classifier ----
  gemm_kernel<1, 1><<<dim3(64, 2), 256, 0, stream>>>(xcat, Wp, bp, xp, 4096, 128, 128);
  gemm_kernel<0, 0><<<dim3(64, 2), 256, 0, stream>>>(xp, be2, nullptr, zb, 4096, 128, 128);
  hipMemsetAsync(aggA, 0, 2 * 262144 * sizeof(float), stream);
  zfold_kernel<<<256, 256, 0, stream>>>(xp, We2, ihb, ia1, ia2, We1, be1, aggA, aggB);
  xin_kernel<<<1024, 256, 0, stream>>>(aggA, aggB, zb, bnn, x_in);
  gemm_kernel<0, 1><<<dim3(64, 6), 256, 0, stream>>>(x_in, Wih, bih, gi, 4096, 384, 128);
  gemm_kernel<0, 1><<<dim3(64, 6), 256, 0, stream>>>(xp, Whh, bhh, gh, 4096, 384, 128);
  gru_kernel<<<2048, 256, 0, stream>>>(gi, gh, xp, xnew);
  gemm_cat_kernel<<<dim3(32, 2), 256, 0, stream>>>(xnew, Wcl1, bcl1, o1);
  gemm_kernel<1, 1><<<dim3(32, 2), 256, 0, stream>>>(o1, Wcl2, bcl2, o2, 2048, 128, 128);
  final_kernel<<<16, 256, 0, stream>>>(o2, Wcl3, bcl3, out);
}

// Round 4
// 452.522 us; speedup vs baseline: 2.0293x; 2.0293x over previous
//
#include <hip/hip_runtime.h>
#include <hip/hip_bf16.h>
#include <math.h>

#define B2    2048
#define NPM   30
#define EPM   120

// ---------------------------------------------------------------------------
// 4x4 micro-tile FMA helper
// ---------------------------------------------------------------------------
__device__ __forceinline__ void fma44(float (&acc)[4][4], const float4 a, const float4 w) {
  acc[0][0] = fmaf(a.x, w.x, acc[0][0]); acc[0][1] = fmaf(a.x, w.y, acc[0][1]);
  acc[0][2] = fmaf(a.x, w.z, acc[0][2]); acc[0][3] = fmaf(a.x, w.w, acc[0][3]);
  acc[1][0] = fmaf(a.y, w.x, acc[1][0]); acc[1][1] = fmaf(a.y, w.y, acc[1][1]);
  acc[1][2] = fmaf(a.y, w.z, acc[1][2]); acc[1][3] = fmaf(a.y, w.w, acc[1][3]);
  acc[2][0] = fmaf(a.z, w.x, acc[2][0]); acc[2][1] = fmaf(a.z, w.y, acc[2][1]);
  acc[2][2] = fmaf(a.z, w.z, acc[2][2]); acc[2][3] = fmaf(a.z, w.w, acc[2][3]);
  acc[3][0] = fmaf(a.w, w.x, acc[3][0]); acc[3][1] = fmaf(a.w, w.y, acc[3][1]);
  acc[3][2] = fmaf(a.w, w.z, acc[3][2]); acc[3][3] = fmaf(a.w, w.w, acc[3][3]);
}

__device__ __forceinline__ void fmas4(float (&acc)[4], float s, const float4 w) {
  acc[0] = fmaf(s, w.x, acc[0]); acc[1] = fmaf(s, w.y, acc[1]);
  acc[2] = fmaf(s, w.z, acc[2]); acc[3] = fmaf(s, w.w, acc[3]);
}

// ---------------------------------------------------------------------------
// adj: build normalized dense adjacency Â[d][s] = cnt(s->d)*rsI[d]*rsO[s]
// per molecule (30x32 padded, row-major). 4 molecules per block (1/wave).
// ---------------------------------------------------------------------------
__global__ __launch_bounds__(256) void adj_kernel(
    const int* __restrict__ src1, const int* __restrict__ dst1,
    const int* __restrict__ src2, const int* __restrict__ dst2,
    float* __restrict__ Abuf)
{
  __shared__ float cnt[4][30 * 33];
  __shared__ float rsOa[4][32], rsIa[4][32];
  const int tid = threadIdx.x, wid = tid >> 6, lane = tid & 63;
  const int gm = blockIdx.x * 4 + wid;
  const int g = gm >> 11, m = gm & 2047;
  const int* src = g ? src2 : src1;
  const int* dst = g ? dst2 : dst1;

  for (int i = lane; i < 30 * 33; i += 64) cnt[wid][i] = 0.f;
  __syncthreads();
  for (int e = lane; e < EPM; e += 64) {
    int s = src[m * EPM + e] - m * NPM;
    int d = dst[m * EPM + e] - m * NPM;
    atomicAdd(&cnt[wid][d * 33 + s], 1.0f);
  }
  __syncthreads();
  if (lane < NPM) {                       // in-degree: row sum
    float sum = 0.f;
    for (int s = 0; s < NPM; ++s) sum += cnt[wid][lane * 33 + s];
    rsIa[wid][lane] = rsqrtf(fmaxf(sum, 1.f));
  } else if (lane >= 32 && lane < 32 + NPM) {   // out-degree: col sum
    int s = lane - 32; float sum = 0.f;
    for (int d = 0; d < NPM; ++d) sum += cnt[wid][d * 33 + s];
    rsOa[wid][s] = rsqrtf(fmaxf(sum, 1.f));
  }
  __syncthreads();
  const long base = (long)gm * 960;
  for (int i = lane; i < 960; i += 64) {
    int d = i >> 5, s = i & 31;
    float v = (d < NPM && s < NPM)
            ? cnt[wid][d * 33 + s] * rsIa[wid][d] * rsOa[wid][s] : 0.f;
    Abuf[base + i] = v;
  }
}

// ---------------------------------------------------------------------------
// g1agg2: per 2-molecule block (full 128 cols):
//   y1 = X @ Wg1            (K=74, LDS-staged GEMM)
//   t1 = relu(Â@y1 + bg1)   (dense 30x30 LDS matmul)
//   agg2 = Â@t1  -> global
// Thread covers 4 rows x (4+4 split) cols: c0..c0+3 and c0+64..c0+67.
// ---------------------------------------------------------------------------
__global__ __launch_bounds__(256, 2) void g1agg2_kernel(
    const float* __restrict__ h1, const float* __restrict__ h2,
    const float* __restrict__ Abuf,
    const float* __restrict__ Wg1, const float* __restrict__ bg1,
    float* __restrict__ agg2)
{
  __shared__ float pool[15360];
  __shared__ float AbL[2 * 990];
  float* XT  = pool;          // [80][64]  (k-major)
  float* Ws  = pool + 5120;   // [80][128]
  float* y1s = pool;          // [60][128] (after GEMM1)
  float* t1s = pool + 7680;   // [60][128]

  const int tid = threadIdx.x;
  const int p = blockIdx.x;              // molecule pair 0..2047
  const int g = p >> 10;
  const int mloc = (p & 1023) * 2;       // molecule within graph
  const float* hsrc = g ? h2 : h1;

  // stage XT[k][r] = h[row r][feat k], rows 0..59 (2 molecules), k padded to 80
  for (int t = tid; t < 2560; t += 256) {
    int r = t & 63, k2 = (t >> 6) << 1;
    float2 v = make_float2(0.f, 0.f);
    if (r < 60 && k2 < 74)
      v = *(const float2*)&hsrc[((long)(mloc * 30 + r)) * 74 + k2];
    XT[k2 * 64 + r]       = v.x;
    XT[(k2 + 1) * 64 + r] = v.y;
  }
  // stage Ws = Wg1 (74x128, rows>=74 zero)
  for (int t = tid; t < 2560; t += 256) {
    int d = t >> 5, c4 = (t & 31) << 2;
    float4 w = (d < 74) ? *(const float4*)&Wg1[d * 128 + c4]
                        : make_float4(0.f, 0.f, 0.f, 0.f);
    *(float4*)&Ws[d * 128 + c4] = w;
  }
  // stage Â for both molecules (stride 33 to spread banks)
  {
    const long ab = (long)(g * 2048 + mloc) * 960;
    for (int t = tid; t < 1920; t += 256) {
      int mm = (t >= 960) ? 1 : 0; int j = t - mm * 960;
      int d = j >> 5, s = j & 31;
      AbL[mm * 990 + d * 33 + s] = Abuf[ab + t];
    }
  }
  __syncthreads();

  const int rgrp = tid >> 4, cgrp = tid & 15;
  const int c0 = cgrp * 4;               // cols c0..c0+3 and c0+64..c0+67
  float accA[4][4], accB[4][4];

  // ---- GEMM1: y1 = X @ Wg1 ----
  {
    const int r0 = rgrp * 4;
    for (int i = 0; i < 4; ++i)
      for (int j = 0; j < 4; ++j) { accA[i][j] = 0.f; accB[i][j] = 0.f; }
    #pragma unroll 8
    for (int k = 0; k < 80; ++k) {
      float4 a  = *(const float4*)&XT[k * 64 + r0];
      float4 w0 = *(const float4*)&Ws[k * 128 + c0];
      float4 w1 = *(const float4*)&Ws[k * 128 + c0 + 64];
      fma44(accA, a, w0);
      fma44(accB, a, w1);
    }
  }
  __syncthreads();
  // write y1 (no bias/relu yet)
  {
    const int r0 = rgrp * 4;
    for (int i = 0; i < 4; ++i) {
      int r = r0 + i;
      if (r < 60) {
        *(float4*)&y1s[r * 128 + c0]      = make_float4(accA[i][0], accA[i][1], accA[i][2], accA[i][3]);
        *(float4*)&y1s[r * 128 + c0 + 64] = make_float4(accB[i][0], accB[i][1], accB[i][2], accB[i][3]);
      }
    }
  }
  __syncthreads();

  const int mol = rgrp >> 3;             // 0/1
  const int d0  = (rgrp & 7) * 4;        // 0..28 (d0+i < 30 guard)
  const float* Am = &AbL[mol * 990];
  float4 bv0 = *(const float4*)&bg1[c0];
  float4 bv1 = *(const float4*)&bg1[c0 + 64];

  // ---- t1 = relu(Â@y1 + b1) ----
  {
    for (int i = 0; i < 4; ++i)
      for (int j = 0; j < 4; ++j) { accA[i][j] = 0.f; accB[i][j] = 0.f; }
    #pragma unroll 5
    for (int s = 0; s < 30; ++s) {
      float4 ya = *(const float4*)&y1s[(mol * 30 + s) * 128 + c0];
      float4 yb = *(const float4*)&y1s[(mol * 30 + s) * 128 + c0 + 64];
      for (int i = 0; i < 4; ++i) {
        float ab = Am[(d0 + i) * 33 + s];
        fmas4(accA[i], ab, ya);
        fmas4(accB[i], ab, yb);
      }
    }
    for (int i = 0; i < 4; ++i) {
      int d = d0 + i;
      if (d < NPM) {
        int r = mol * 30 + d;
        float4 oa, ob;
        oa.x = fmaxf(accA[i][0] + bv0.x, 0.f); oa.y = fmaxf(accA[i][1] + bv0.y, 0.f);
        oa.z = fmaxf(accA[i][2] + bv0.z, 0.f); oa.w = fmaxf(accA[i][3] + bv0.w, 0.f);
        ob.x = fmaxf(accB[i][0] + bv1.x, 0.f); ob.y = fmaxf(accB[i][1] + bv1.y, 0.f);
        ob.z = fmaxf(accB[i][2] + bv1.z, 0.f); ob.w = fmaxf(accB[i][3] + bv1.w, 0.f);
        *(float4*)&t1s[r * 128 + c0]      = oa;
        *(float4*)&t1s[r * 128 + c0 + 64] = ob;
      }
    }
  }
  __syncthreads();

  // ---- agg2 = Â@t1 -> global ----
  {
    for (int i = 0; i < 4; ++i)
      for (int j = 0; j < 4; ++j) { accA[i][j] = 0.f; accB[i][j] = 0.f; }
    #pragma unroll 5
    for (int s = 0; s < 30; ++s) {
      float4 ta = *(const float4*)&t1s[(mol * 30 + s) * 128 + c0];
      float4 tb = *(const float4*)&t1s[(mol * 30 + s) * 128 + c0 + 64];
      for (int i = 0; i < 4; ++i) {
        float ab = Am[(d0 + i) * 33 + s];
        fmas4(accA[i], ab, ta);
        fmas4(accB[i], ab, tb);
      }
    }
    for (int i = 0; i < 4; ++i) {
      int d = d0 + i;
      if (d < NPM) {
        long row = ((long)p * 60 + mol * 30 + d) * 128;
        *(float4*)&agg2[row + c0]      = make_float4(accA[i][0], accA[i][1], accA[i][2], accA[i][3]);
        *(float4*)&agg2[row + c0 + 64] = make_float4(accB[i][0], accB[i][1], accB[i][2], accB[i][3]);
      }
    }
  }
}

// ---------------------------------------------------------------------------
// G2+pool: t2 = relu(agg2 @ Wg2 + bg2); xcat[mol] = mean_rows(t2)*sf.
// Molecule-aligned 60-row tiles (2 molecules/block). grid = (2048, 2).
// ---------------------------------------------------------------------------
__global__ __launch_bounds__(256) void g2pool_kernel(
    const float* __restrict__ A, const float* __restrict__ W,
    const float* __restrict__ bias, const float* __restrict__ s1x,
    float* __restrict__ xcat, int Mrows, int gmbase)
{
  __shared__ float At[64 * 64];
  __shared__ float Ws[64 * 64];
  __shared__ float cs[2 * 64];
  const int tid = threadIdx.x;
  const int rowBase = blockIdx.x * 60, colBase = blockIdx.y * 64;
  const int rgrp = tid >> 4, cgrp = tid & 15;
  const int r0 = rgrp * 4, c0 = cgrp * 4;
  if (tid < 128) cs[tid] = 0.f;
  float acc[4][4] = {{0.f}};
  for (int k0 = 0; k0 < 128; k0 += 64) {
    for (int t = tid; t < 1024; t += 256) {
      int row = t & 63, kk = (t >> 6) << 2;
      float4 v = make_float4(0.f, 0.f, 0.f, 0.f);
      if (rowBase + row < Mrows)
        v = *(const float4*)&A[(long)(rowBase + row) * 128 + k0 + kk];
      At[(kk + 0) * 64 + row] = v.x; At[(kk + 1) * 64 + row] = v.y;
      At[(kk + 2) * 64 + row] = v.z; At[(kk + 3) * 64 + row] = v.w;
    }
    for (int t = tid; t < 1024; t += 256) {
      int d = t >> 4, c4 = (t & 15) << 2;
      *(float4*)&Ws[d * 64 + c4] = *(const float4*)&W[(k0 + d) * 128 + colBase + c4];
    }
    __syncthreads();
    #pragma unroll 8
    for (int d = 0; d < 64; ++d) {
      float4 a = *(const float4*)&At[d * 64 + r0];
      float4 w = *(const float4*)&Ws[d * 64 + c0];
      fma44(acc, a, w);
    }
    __syncthreads();
  }
  float4 bv = *(const float4*)&bias[colBase + c0];
  for (int i = 0; i < 4; ++i) {
    int lr = r0 + i;
    if (lr < 60) {
      int moll = (lr >= NPM) ? 1 : 0;
      atomicAdd(&cs[moll * 64 + c0 + 0], fmaxf(acc[i][0] + bv.x, 0.f));
      atomicAdd(&cs[moll * 64 + c0 + 1], fmaxf(acc[i][1] + bv.y, 0.f));
      atomicAdd(&cs[moll * 64 + c0 + 2], fmaxf(acc[i][2] + bv.z, 0.f));
      atomicAdd(&cs[moll * 64 + c0 + 3], fmaxf(acc[i][3] + bv.w, 0.f));
    }
  }
  __syncthreads();
  if (tid < 128) {
    int moll = tid >> 6, c = tid & 63;
    int gm = gmbase + (rowBase / 30) + moll;
    int gg = gm >> 11, mm = gm & 2047;
    float sf = gg ? (1.f - s1x[mm]) : s1x[mm];
    xcat[gm * 128 + colBase + c] = cs[moll * 64 + c] * (1.f / 30.f) * sf;
  }
}

// ---------------------------------------------------------------------------
// Generic fp32 GEMM: C = [relu]( A(MxK) @ W(KxN) [+ bias] ).  64x64 tile.
// ---------------------------------------------------------------------------
template<int RELU, int BIAS>
__global__ __launch_bounds__(256) void gemm_kernel(
    const float* __restrict__ A, const float* __restrict__ W,
    const float* __restrict__ bias, float* __restrict__ C,
    int M, int Ncols, int K)
{
  __shared__ float At[64 * 64];
  __shared__ float Ws[64 * 64];
  const int tid = threadIdx.x;
  const int rowBase = blockIdx.x * 64, colBase = blockIdx.y * 64;
  const int rgrp = tid >> 4, cgrp = tid & 15;
  const int r0 = rgrp * 4, c0 = cgrp * 4;
  float acc[4][4] = {{0.f}};
  for (int k0 = 0; k0 < K; k0 += 64) {
    for (int t = tid; t < 1024; t += 256) {
      int row = t & 63, kk = (t >> 6) << 2;
      float4 v = *(const float4*)&A[(rowBase + row) * K + k0 + kk];
      At[(kk + 0) * 64 + row] = v.x; At[(kk + 1) * 64 + row] = v.y;
      At[(kk + 2) * 64 + row] = v.z; At[(kk + 3) * 64 + row] = v.w;
    }
    for (int t = tid; t < 1024; t += 256) {
      int d = t >> 4, c4 = (t & 15) << 2;
      *(float4*)&Ws[d * 64 + c4] = *(const float4*)&W[(k0 + d) * Ncols + colBase + c4];
    }
    __syncthreads();
    #pragma unroll 8
    for (int d = 0; d < 64; ++d) {
      float4 a = *(const float4*)&At[d * 64 + r0];
      float4 w = *(const float4*)&Ws[d * 64 + c0];
      fma44(acc, a, w);
    }
    __syncthreads();
  }
  float4 bv = make_float4(0.f, 0.f, 0.f, 0.f);
  if (BIAS) bv = *(const float4*)&bias[colBase + c0];
  for (int i = 0; i < 4; ++i) {
    float4 o;
    o.x = acc[i][0] + bv.x; o.y = acc[i][1] + bv.y;
    o.z = acc[i][2] + bv.z; o.w = acc[i][3] + bv.w;
    if (RELU) { o.x = fmaxf(o.x, 0.f); o.y = fmaxf(o.y, 0.f); o.z = fmaxf(o.z, 0.f); o.w = fmaxf(o.w, 0.f); }
    *(float4*)&C[(rowBase + r0 + i) * Ncols + colBase + c0] = o;
  }
}

// ---------------------------------------------------------------------------
// Classifier layer 1 on concatenated halves: o1 = relu([x[:B]|x[B:]] @ W + b)
// ---------------------------------------------------------------------------
__global__ __launch_bounds__(256) void gemm_cat_kernel(
    const float* __restrict__ X, const float* __restrict__ W,
    const float* __restrict__ bias, float* __restrict__ C)
{
  __shared__ float At[64 * 64];
  __shared__ float Ws[64 * 64];
  const int tid = threadIdx.x;
  const int rowBase = blockIdx.x * 64, colBase = blockIdx.y * 64;
  const int rgrp = tid >> 4, cgrp = tid & 15;
  const int r0 = rgrp * 4, c0 = cgrp * 4;
  float acc[4][4] = {{0.f}};
  for (int k0 = 0; k0 < 256; k0 += 64) {
    const float* base = (k0 < 128) ? X : (X + B2 * 128);
    const int kc = k0 & 127;
    for (int t = tid; t < 1024; t += 256) {
      int row = t & 63, kk = (t >> 6) << 2;
      float4 v = *(const float4*)&base[(rowBase + row) * 128 + kc + kk];
      At[(kk + 0) * 64 + row] = v.x; At[(kk + 1) * 64 + row] = v.y;
      At[(kk + 2) * 64 + row] = v.z; At[(kk + 3) * 64 + row] = v.w;
    }
    for (int t = tid; t < 1024; t += 256) {
      int d = t >> 4, c4 = (t & 15) << 2;
      *(float4*)&Ws[d * 64 + c4] = *(const float4*)&W[(k0 + d) * 128 + colBase + c4];
    }
    __syncthreads();
    #pragma unroll 8
    for (int d = 0; d < 64; ++d) {
      float4 a = *(const float4*)&At[d * 64 + r0];
      float4 w = *(const float4*)&Ws[d * 64 + c0];
      fma44(acc, a, w);
    }
    __syncthreads();
  }
  float4 bv = *(const float4*)&bias[colBase + c0];
  for (int i = 0; i < 4; ++i) {
    float4 o;
    o.x = fmaxf(acc[i][0] + bv.x, 0.f); o.y = fmaxf(acc[i][1] + bv.y, 0.f);
    o.z = fmaxf(acc[i][2] + bv.z, 0.f); o.w = fmaxf(acc[i][3] + bv.w, 0.f);
    *(float4*)&C[(rowBase + r0 + i) * 128 + colBase + c0] = o;
  }
}

// ---------------------------------------------------------------------------
// Fused z-GEMM + eh-fold (eh MLP layer-1 computed inline).
// ---------------------------------------------------------------------------
__global__ __launch_bounds__(256) void zfold_kernel(
    const float* __restrict__ xp, const float* __restrict__ We2,
    const float* __restrict__ interhb, const float* __restrict__ ia1,
    const float* __restrict__ ia2, const float* __restrict__ We1,
    const float* __restrict__ be1,
    float* __restrict__ aggA, float* __restrict__ aggB)
{
  __shared__ float xsT[128 * 36];
  __shared__ float Ws[64 * 128];
  __shared__ float ehs[3][16][32];
  __shared__ float accAs[16 * 128], accBs[16 * 128];
  const int tid = threadIdx.x;
  const int mg = blockIdx.x >> 1, kh = blockIdx.x & 1;
  const int i0 = mg * 16;

  for (int t = tid; t < 1024; t += 256) {
    int row = t & 31, d4 = t >> 5;
    int gr = (row < 16) ? (i0 + row) : (B2 + i0 + row - 16);
    float4 v = *(const float4*)&xp[gr * 128 + d4 * 4];
    xsT[(d4 * 4 + 0) * 36 + row] = v.x; xsT[(d4 * 4 + 1) * 36 + row] = v.y;
    xsT[(d4 * 4 + 2) * 36 + row] = v.z; xsT[(d4 * 4 + 3) * 36 + row] = v.w;
  }
  for (int t = tid; t < 512; t += 256) {
    int mm = t >> 5, k = t & 31;
    float a = We1[k], b = be1[k];
    ehs[0][mm][k] = fmaxf(fmaf(interhb[i0 + mm], a, b), 0.f);
    ehs[1][mm][k] = fmaxf(fmaf(ia1[i0 + mm],     a, b), 0.f);
    ehs[2][mm][k] = fmaxf(fmaf(ia2[i0 + mm],     a, b), 0.f);
  }
  for (int t = tid; t < 16 * 128; t += 256) { accAs[t] = 0.f; accBs[t] = 0.f; }

  const int rgrp = tid >> 5, cgrp = tid & 31;
  const int r0 = rgrp * 4, c0 = cgrp * 4;
  const int side = rgrp >> 2;
  float accLo[4][4] = {{0.f}}, accHi[4][4] = {{0.f}};

  for (int kk = 0; kk < 16; ++kk) {
    const int k = kh * 16 + kk;
    float z[4][4] = {{0.f}};
    for (int ch = 0; ch < 2; ++ch) {
      __syncthreads();
      for (int t = tid; t < 2048; t += 256) {
        int d = t >> 5, c4 = (t & 31) << 2;
        *(float4*)&Ws[d * 128 + c4] =
            *(const float4*)&We2[k * 16384 + (ch * 64 + d) * 128 + c4];
      }
      __syncthreads();
      #pragma unroll 4
      for (int d = 0; d < 64; ++d) {
        float4 a = *(const float4*)&xsT[(ch * 64 + d) * 36 + r0];
        float4 w = *(const float4*)&Ws[d * 128 + c0];
        fma44(z, a, w);
      }
    }
    #pragma unroll
    for (int i = 0; i < 4; ++i) {
      int mm = (r0 + i) & 15;
      float uLo = side ? ehs[0][mm][k] : ehs[1][mm][k];
      float uHi = side ? ehs[2][mm][k] : ehs[0][mm][k];
      #pragma unroll
      for (int j = 0; j < 4; ++j) {
        accLo[i][j] = fmaf(uLo, z[i][j], accLo[i][j]);
        accHi[i][j] = fmaf(uHi, z[i][j], accHi[i][j]);
      }
    }
  }
  __syncthreads();
  for (int i = 0; i < 4; ++i) {
    int mm = (r0 + i) & 15;
    for (int j = 0; j < 4; ++j) {
      atomicAdd(&accAs[mm * 128 + c0 + j], accLo[i][j]);
      atomicAdd(&accBs[mm * 128 + c0 + j], accHi[i][j]);
    }
  }
  __syncthreads();
  for (int t = tid; t < 2048; t += 256) {
    int mm = t >> 7, c = t & 127;
    atomicAdd(&aggA[(i0 + mm) * 128 + c], accAs[mm * 128 + c]);
    atomicAdd(&aggB[(i0 + mm) * 128 + c], accBs[mm * 128 + c]);
  }
}

__global__ __launch_bounds__(256) void xin_kernel(
    const float* __restrict__ aggA, const float* __restrict__ aggB,
    const float* __restrict__ zb, const float* __restrict__ bnn,
    float* __restrict__ x_in)
{
  int idx = blockIdx.x * 256 + threadIdx.x;
  int i = idx >> 7, c = idx & 127;
  float zs = zb[i * 128 + c] + zb[(i + B2) * 128 + c] + bnn[c];
  x_in[i * 128 + c]        = fmaxf(aggA[idx] + zs, 0.f);
  x_in[(i + B2) * 128 + c] = fmaxf(aggB[idx] + zs, 0.f);
}

__global__ __launch_bounds__(256) void gru_kernel(
    const float* __restrict__ gi, const float* __restrict__ gh,
    const float* __restrict__ xp, float* __restrict__ xnew)
{
  int idx = blockIdx.x * 256 + threadIdx.x;
  int n = idx >> 7, j = idx & 127;
  float ir = gi[n * 384 + j], iz = gi[n * 384 + 128 + j], ih = gi[n * 384 + 256 + j];
  float hr = gh[n * 384 + j], hz = gh[n * 384 + 128 + j], hn = gh[n * 384 + 256 + j];
  float h  = xp[idx];
  float r  = 1.f / (1.f + expf(-(ir + hr)));
  float zg = 1.f / (1.f + expf(-(iz + hz)));
  float ng = tanhf(ih + r * hn);
  xnew[idx] = (1.f - zg) * ng + zg * h;
}

__global__ __launch_bounds__(256) void final_kernel(
    const float* __restrict__ o2, const float* __restrict__ Wcl3,
    const float* __restrict__ bcl3, float* __restrict__ out)
{
  int idx = blockIdx.x * 256 + threadIdx.x;
  int i = idx >> 1, c = idx & 1;
  float acc = bcl3[c];
  for (int k = 0; k < 128; ++k) acc = fmaf(o2[i * 128 + k], Wcl3[k * 2 + c], acc);
  out[idx] = acc;
}

// ---------------------------------------------------------------------------
extern "C" void kernel_launch(void* const* d_in, const int* in_sizes, int n_in,
                              void* d_out, int out_size, void* d_ws, size_t ws_size,
                              hipStream_t stream)
{
  const float* h1   = (const float*)d_in[0];
  const float* h2   = (const float*)d_in[1];
  const float* s1x  = (const float*)d_in[2];
  const float* ihb  = (const float*)d_in[3];
  const float* ia1  = (const float*)d_in[4];
  const float* ia2  = (const float*)d_in[5];
  const float* Wg1  = (const float*)d_in[6];
  const float* bg1  = (const float*)d_in[7];
  const float* Wg2  = (const float*)d_in[8];
  const float* bg2  = (const float*)d_in[9];
  const float* Wp   = (const float*)d_in[10];
  const float* bp   = (const float*)d_in[11];
  const float* We1  = (const float*)d_in[12];
  const float* be1  = (const float*)d_in[13];
  const float* We2  = (const float*)d_in[14];
  const float* be2  = (const float*)d_in[15];
  const float* bnn  = (const float*)d_in[16];
  const float* Wih  = (const float*)d_in[17];
  const float* bih  = (const float*)d_in[18];
  const float* Whh  = (const float*)d_in[19];
  const float* bhh  = (const float*)d_in[20];
  const float* Wcl1 = (const float*)d_in[21];
  const float* bcl1 = (const float*)d_in[22];
  const float* Wcl2 = (const float*)d_in[23];
  const float* bcl2 = (const float*)d_in[24];
  const float* Wcl3 = (const float*)d_in[25];
  const float* bcl3 = (const float*)d_in[26];
  const int*   src1 = (const int*)d_in[27];
  const int*   dst1 = (const int*)d_in[28];
  const int*   src2 = (const int*)d_in[29];
  const int*   dst2 = (const int*)d_in[30];
  float* out = (float*)d_out;
  float* ws  = (float*)d_ws;

  float* Abuf = ws;                          // 4096*960  = 3,932,160
  float* agg2 = ws + 3932160;                // 122880*128 = 15,728,640
  float* dwn  = ws + 19660800;

  float* xcat = dwn;
  float* xp   = dwn + 524288;
  float* zb   = dwn + 1048576;
  float* aggA = dwn + 1572864;
  float* aggB = dwn + 1835008;
  float* x_in = dwn + 2097152;
  float* gi   = dwn + 2621440;
  float* gh   = dwn + 4194304;
  float* xnew = dwn + 5767168;
  float* o1   = dwn + 6291456;
  float* o2   = dwn + 6553600;

  // ---- GraphConv pipeline (dense per-molecule adjacency) ----
  adj_kernel<<<1024, 256, 0, stream>>>(src1, dst1, src2, dst2, Abuf);
  g1agg2_kernel<<<2048, 256, 0, stream>>>(h1, h2, Abuf, Wg1, bg1, agg2);
  g2pool_kernel<<<dim3(2048, 2), 256, 0, stream>>>(agg2, Wg2, bg2, s1x, xcat,
                                                   122880, 0);

  // ---- solvent-system MPNN + GRU + classifier ----
  gemm_kernel<1, 1><<<dim3(64, 2), 256, 0, stream>>>(xcat, Wp, bp, xp, 4096, 128, 128);
  gemm_kernel<0, 0><<<dim3(64, 2), 256, 0, stream>>>(xp, be2, nullptr, zb, 4096, 128, 128);
  hipMemsetAsync(aggA, 0, 2 * 262144 * sizeof(float), stream);
  zfold_kernel<<<256, 256, 0, stream>>>(xp, We2, ihb, ia1, ia2, We1, be1, aggA, aggB);
  xin_kernel<<<1024, 256, 0, stream>>>(aggA, aggB, zb, bnn, x_in);
  gemm_kernel<0, 1><<<dim3(64, 6), 256, 0, stream>>>(x_in, Wih, bih, gi, 4096, 384, 128);
  gemm_kernel<0, 1><<<dim3(64, 6), 256, 0, stream>>>(xp, Whh, bhh, gh, 4096, 384, 128);
  gru_kernel<<<2048, 256, 0, stream>>>(gi, gh, xp, xnew);
  gemm_cat_kernel<<<dim3(32, 2), 256, 0, stream>>>(xnew, Wcl1, bcl1, o1);
  gemm_kernel<1, 1><<<dim3(32, 2), 256, 0, stream>>>(o1, Wcl2, bcl2, o2, 2048, 128, 128);
  final_kernel<<<16, 256, 0, stream>>>(o2, Wcl3, bcl3, out);
}

// Round 5
// 381.649 us; speedup vs baseline: 2.4061x; 1.1857x over previous
//
#include <hip/hip_runtime.h>
#include <hip/hip_bf16.h>
#include <math.h>

#define B2    2048
#define NPM   30
#define EPM   120

// ---------------------------------------------------------------------------
// micro-tile FMA helpers
// ---------------------------------------------------------------------------
__device__ __forceinline__ void fma44(float (&acc)[4][4], const float4 a, const float4 w) {
  acc[0][0] = fmaf(a.x, w.x, acc[0][0]); acc[0][1] = fmaf(a.x, w.y, acc[0][1]);
  acc[0][2] = fmaf(a.x, w.z, acc[0][2]); acc[0][3] = fmaf(a.x, w.w, acc[0][3]);
  acc[1][0] = fmaf(a.y, w.x, acc[1][0]); acc[1][1] = fmaf(a.y, w.y, acc[1][1]);
  acc[1][2] = fmaf(a.y, w.z, acc[1][2]); acc[1][3] = fmaf(a.y, w.w, acc[1][3]);
  acc[2][0] = fmaf(a.z, w.x, acc[2][0]); acc[2][1] = fmaf(a.z, w.y, acc[2][1]);
  acc[2][2] = fmaf(a.z, w.z, acc[2][2]); acc[2][3] = fmaf(a.z, w.w, acc[2][3]);
  acc[3][0] = fmaf(a.w, w.x, acc[3][0]); acc[3][1] = fmaf(a.w, w.y, acc[3][1]);
  acc[3][2] = fmaf(a.w, w.z, acc[3][2]); acc[3][3] = fmaf(a.w, w.w, acc[3][3]);
}

__device__ __forceinline__ void fmas4(float (&acc)[4], float s, const float4 w) {
  acc[0] = fmaf(s, w.x, acc[0]); acc[1] = fmaf(s, w.y, acc[1]);
  acc[2] = fmaf(s, w.z, acc[2]); acc[3] = fmaf(s, w.w, acc[3]);
}

__device__ __forceinline__ void fma48(float (&acc)[4][8], const float4 a,
                                      const float4 w0, const float4 w1) {
  const float av[4] = {a.x, a.y, a.z, a.w};
  #pragma unroll
  for (int i = 0; i < 4; ++i) {
    acc[i][0] = fmaf(av[i], w0.x, acc[i][0]); acc[i][1] = fmaf(av[i], w0.y, acc[i][1]);
    acc[i][2] = fmaf(av[i], w0.z, acc[i][2]); acc[i][3] = fmaf(av[i], w0.w, acc[i][3]);
    acc[i][4] = fmaf(av[i], w1.x, acc[i][4]); acc[i][5] = fmaf(av[i], w1.y, acc[i][5]);
    acc[i][6] = fmaf(av[i], w1.z, acc[i][6]); acc[i][7] = fmaf(av[i], w1.w, acc[i][7]);
  }
}

// ---------------------------------------------------------------------------
// adj: build normalized dense adjacency Â[d][s] = cnt(s->d)*rsI[d]*rsO[s]
// per molecule (30x32 padded, row-major). 4 molecules per block (1/wave).
// ---------------------------------------------------------------------------
__global__ __launch_bounds__(256) void adj_kernel(
    const int* __restrict__ src1, const int* __restrict__ dst1,
    const int* __restrict__ src2, const int* __restrict__ dst2,
    float* __restrict__ Abuf)
{
  __shared__ float cnt[4][30 * 33];
  __shared__ float rsOa[4][32], rsIa[4][32];
  const int tid = threadIdx.x, wid = tid >> 6, lane = tid & 63;
  const int gm = blockIdx.x * 4 + wid;
  const int g = gm >> 11, m = gm & 2047;
  const int* src = g ? src2 : src1;
  const int* dst = g ? dst2 : dst1;

  for (int i = lane; i < 30 * 33; i += 64) cnt[wid][i] = 0.f;
  __syncthreads();
  for (int e = lane; e < EPM; e += 64) {
    int s = src[m * EPM + e] - m * NPM;
    int d = dst[m * EPM + e] - m * NPM;
    atomicAdd(&cnt[wid][d * 33 + s], 1.0f);
  }
  __syncthreads();
  if (lane < NPM) {                       // in-degree: row sum
    float sum = 0.f;
    for (int s = 0; s < NPM; ++s) sum += cnt[wid][lane * 33 + s];
    rsIa[wid][lane] = rsqrtf(fmaxf(sum, 1.f));
  } else if (lane >= 32 && lane < 32 + NPM) {   // out-degree: col sum
    int s = lane - 32; float sum = 0.f;
    for (int d = 0; d < NPM; ++d) sum += cnt[wid][d * 33 + s];
    rsOa[wid][s] = rsqrtf(fmaxf(sum, 1.f));
  }
  __syncthreads();
  const long base = (long)gm * 960;
  for (int i = lane; i < 960; i += 64) {
    int d = i >> 5, s = i & 31;
    float v = (d < NPM && s < NPM)
            ? cnt[wid][d * 33 + s] * rsIa[wid][d] * rsOa[wid][s] : 0.f;
    Abuf[base + i] = v;
  }
}

// ---------------------------------------------------------------------------
// g1agg2: per 2-molecule block (full 128 cols):
//   y1 = X @ Wg1, t1 = relu(Â@y1 + bg1), agg2 = Â@t1 -> global
// ---------------------------------------------------------------------------
__global__ __launch_bounds__(256, 2) void g1agg2_kernel(
    const float* __restrict__ h1, const float* __restrict__ h2,
    const float* __restrict__ Abuf,
    const float* __restrict__ Wg1, const float* __restrict__ bg1,
    float* __restrict__ agg2)
{
  __shared__ float pool[15360];
  __shared__ float AbL[2 * 990];
  float* XT  = pool;          // [80][64]  (k-major)
  float* Ws  = pool + 5120;   // [80][128]
  float* y1s = pool;          // [60][128] (after GEMM1)
  float* t1s = pool + 7680;   // [60][128]

  const int tid = threadIdx.x;
  const int p = blockIdx.x;              // molecule pair 0..2047
  const int g = p >> 10;
  const int mloc = (p & 1023) * 2;       // molecule within graph
  const float* hsrc = g ? h2 : h1;

  for (int t = tid; t < 2560; t += 256) {
    int r = t & 63, k2 = (t >> 6) << 1;
    float2 v = make_float2(0.f, 0.f);
    if (r < 60 && k2 < 74)
      v = *(const float2*)&hsrc[((long)(mloc * 30 + r)) * 74 + k2];
    XT[k2 * 64 + r]       = v.x;
    XT[(k2 + 1) * 64 + r] = v.y;
  }
  for (int t = tid; t < 2560; t += 256) {
    int d = t >> 5, c4 = (t & 31) << 2;
    float4 w = (d < 74) ? *(const float4*)&Wg1[d * 128 + c4]
                        : make_float4(0.f, 0.f, 0.f, 0.f);
    *(float4*)&Ws[d * 128 + c4] = w;
  }
  {
    const long ab = (long)(g * 2048 + mloc) * 960;
    for (int t = tid; t < 1920; t += 256) {
      int mm = (t >= 960) ? 1 : 0; int j = t - mm * 960;
      int d = j >> 5, s = j & 31;
      AbL[mm * 990 + d * 33 + s] = Abuf[ab + t];
    }
  }
  __syncthreads();

  const int rgrp = tid >> 4, cgrp = tid & 15;
  const int c0 = cgrp * 4;
  float accA[4][4], accB[4][4];

  // ---- GEMM1: y1 = X @ Wg1 ----
  {
    const int r0 = rgrp * 4;
    for (int i = 0; i < 4; ++i)
      for (int j = 0; j < 4; ++j) { accA[i][j] = 0.f; accB[i][j] = 0.f; }
    #pragma unroll 8
    for (int k = 0; k < 80; ++k) {
      float4 a  = *(const float4*)&XT[k * 64 + r0];
      float4 w0 = *(const float4*)&Ws[k * 128 + c0];
      float4 w1 = *(const float4*)&Ws[k * 128 + c0 + 64];
      fma44(accA, a, w0);
      fma44(accB, a, w1);
    }
  }
  __syncthreads();
  {
    const int r0 = rgrp * 4;
    for (int i = 0; i < 4; ++i) {
      int r = r0 + i;
      if (r < 60) {
        *(float4*)&y1s[r * 128 + c0]      = make_float4(accA[i][0], accA[i][1], accA[i][2], accA[i][3]);
        *(float4*)&y1s[r * 128 + c0 + 64] = make_float4(accB[i][0], accB[i][1], accB[i][2], accB[i][3]);
      }
    }
  }
  __syncthreads();

  const int mol = rgrp >> 3;
  const int d0  = (rgrp & 7) * 4;
  const float* Am = &AbL[mol * 990];
  float4 bv0 = *(const float4*)&bg1[c0];
  float4 bv1 = *(const float4*)&bg1[c0 + 64];

  // ---- t1 = relu(Â@y1 + b1) ----
  {
    for (int i = 0; i < 4; ++i)
      for (int j = 0; j < 4; ++j) { accA[i][j] = 0.f; accB[i][j] = 0.f; }
    #pragma unroll 5
    for (int s = 0; s < 30; ++s) {
      float4 ya = *(const float4*)&y1s[(mol * 30 + s) * 128 + c0];
      float4 yb = *(const float4*)&y1s[(mol * 30 + s) * 128 + c0 + 64];
      for (int i = 0; i < 4; ++i) {
        float ab = Am[(d0 + i) * 33 + s];
        fmas4(accA[i], ab, ya);
        fmas4(accB[i], ab, yb);
      }
    }
    for (int i = 0; i < 4; ++i) {
      int d = d0 + i;
      if (d < NPM) {
        int r = mol * 30 + d;
        float4 oa, ob;
        oa.x = fmaxf(accA[i][0] + bv0.x, 0.f); oa.y = fmaxf(accA[i][1] + bv0.y, 0.f);
        oa.z = fmaxf(accA[i][2] + bv0.z, 0.f); oa.w = fmaxf(accA[i][3] + bv0.w, 0.f);
        ob.x = fmaxf(accB[i][0] + bv1.x, 0.f); ob.y = fmaxf(accB[i][1] + bv1.y, 0.f);
        ob.z = fmaxf(accB[i][2] + bv1.z, 0.f); ob.w = fmaxf(accB[i][3] + bv1.w, 0.f);
        *(float4*)&t1s[r * 128 + c0]      = oa;
        *(float4*)&t1s[r * 128 + c0 + 64] = ob;
      }
    }
  }
  __syncthreads();

  // ---- agg2 = Â@t1 -> global ----
  {
    for (int i = 0; i < 4; ++i)
      for (int j = 0; j < 4; ++j) { accA[i][j] = 0.f; accB[i][j] = 0.f; }
    #pragma unroll 5
    for (int s = 0; s < 30; ++s) {
      float4 ta = *(const float4*)&t1s[(mol * 30 + s) * 128 + c0];
      float4 tb = *(const float4*)&t1s[(mol * 30 + s) * 128 + c0 + 64];
      for (int i = 0; i < 4; ++i) {
        float ab = Am[(d0 + i) * 33 + s];
        fmas4(accA[i], ab, ta);
        fmas4(accB[i], ab, tb);
      }
    }
    for (int i = 0; i < 4; ++i) {
      int d = d0 + i;
      if (d < NPM) {
        long row = ((long)p * 60 + mol * 30 + d) * 128;
        *(float4*)&agg2[row + c0]      = make_float4(accA[i][0], accA[i][1], accA[i][2], accA[i][3]);
        *(float4*)&agg2[row + c0 + 64] = make_float4(accB[i][0], accB[i][1], accB[i][2], accB[i][3]);
      }
    }
  }
}

// ---------------------------------------------------------------------------
// G2+pool: t2 = relu(agg2 @ Wg2 + bg2); xcat[mol] = mean_rows(t2)*sf.
// One block per 60-row tile, FULL 128 cols, 4x8 micro-tile. grid = 2048.
// ---------------------------------------------------------------------------
__global__ __launch_bounds__(256) void g2pool_kernel(
    const float* __restrict__ A, const float* __restrict__ W,
    const float* __restrict__ bias, const float* __restrict__ s1x,
    float* __restrict__ xcat)
{
  __shared__ float At[64 * 64];     // [k][row]
  __shared__ float Ws[64 * 128];    // [k][col]
  __shared__ float cs[2 * 128];
  const int tid = threadIdx.x;
  const long rowBase = (long)blockIdx.x * 60;
  const int rgrp = tid >> 4, cgrp = tid & 15;
  const int r0 = rgrp * 4, c0 = cgrp * 8;
  cs[tid] = 0.f;
  float acc[4][8] = {{0.f}};
  for (int k0 = 0; k0 < 128; k0 += 64) {
    for (int t = tid; t < 1024; t += 256) {
      int row = t & 63, kk = (t >> 6) << 2;
      float4 v = make_float4(0.f, 0.f, 0.f, 0.f);
      if (row < 60)
        v = *(const float4*)&A[(rowBase + row) * 128 + k0 + kk];
      At[(kk + 0) * 64 + row] = v.x; At[(kk + 1) * 64 + row] = v.y;
      At[(kk + 2) * 64 + row] = v.z; At[(kk + 3) * 64 + row] = v.w;
    }
    for (int t = tid; t < 2048; t += 256) {
      int d = t >> 5, c4 = (t & 31) << 2;
      *(float4*)&Ws[d * 128 + c4] = *(const float4*)&W[(k0 + d) * 128 + c4];
    }
    __syncthreads();
    #pragma unroll 8
    for (int d = 0; d < 64; ++d) {
      float4 a  = *(const float4*)&At[d * 64 + r0];
      float4 w0 = *(const float4*)&Ws[d * 128 + c0];
      float4 w1 = *(const float4*)&Ws[d * 128 + c0 + 4];
      fma48(acc, a, w0, w1);
    }
    __syncthreads();
  }
  float4 bv0 = *(const float4*)&bias[c0];
  float4 bv1 = *(const float4*)&bias[c0 + 4];
  const float bb[8] = {bv0.x, bv0.y, bv0.z, bv0.w, bv1.x, bv1.y, bv1.z, bv1.w};
  float p0[8] = {0,0,0,0,0,0,0,0}, p1[8] = {0,0,0,0,0,0,0,0};
  for (int i = 0; i < 4; ++i) {
    int r = r0 + i;
    if (r < 60) {
      float* p = (r < NPM) ? p0 : p1;
      #pragma unroll
      for (int j = 0; j < 8; ++j) p[j] += fmaxf(acc[i][j] + bb[j], 0.f);
    }
  }
  #pragma unroll
  for (int j = 0; j < 8; ++j) {
    atomicAdd(&cs[c0 + j],       p0[j]);
    atomicAdd(&cs[128 + c0 + j], p1[j]);
  }
  __syncthreads();
  {
    int moll = tid >> 7, c = tid & 127;
    int gm = blockIdx.x * 2 + moll;
    int gg = gm >> 11, mm = gm & 2047;
    float sf = gg ? (1.f - s1x[mm]) : s1x[mm];
    xcat[(long)gm * 128 + c] = cs[moll * 128 + c] * (1.f / 30.f) * sf;
  }
}

// ---------------------------------------------------------------------------
// Generic fp32 GEMM: C = [relu]( A(MxK) @ W(KxN) [+ bias] ).  64x64 tile.
// ---------------------------------------------------------------------------
template<int RELU, int BIAS>
__global__ __launch_bounds__(256) void gemm_kernel(
    const float* __restrict__ A, const float* __restrict__ W,
    const float* __restrict__ bias, float* __restrict__ C,
    int M, int Ncols, int K)
{
  __shared__ float At[64 * 64];
  __shared__ float Ws[64 * 64];
  const int tid = threadIdx.x;
  const int rowBase = blockIdx.x * 64, colBase = blockIdx.y * 64;
  const int rgrp = tid >> 4, cgrp = tid & 15;
  const int r0 = rgrp * 4, c0 = cgrp * 4;
  float acc[4][4] = {{0.f}};
  for (int k0 = 0; k0 < K; k0 += 64) {
    for (int t = tid; t < 1024; t += 256) {
      int row = t & 63, kk = (t >> 6) << 2;
      float4 v = *(const float4*)&A[(rowBase + row) * K + k0 + kk];
      At[(kk + 0) * 64 + row] = v.x; At[(kk + 1) * 64 + row] = v.y;
      At[(kk + 2) * 64 + row] = v.z; At[(kk + 3) * 64 + row] = v.w;
    }
    for (int t = tid; t < 1024; t += 256) {
      int d = t >> 4, c4 = (t & 15) << 2;
      *(float4*)&Ws[d * 64 + c4] = *(const float4*)&W[(k0 + d) * Ncols + colBase + c4];
    }
    __syncthreads();
    #pragma unroll 8
    for (int d = 0; d < 64; ++d) {
      float4 a = *(const float4*)&At[d * 64 + r0];
      float4 w = *(const float4*)&Ws[d * 64 + c0];
      fma44(acc, a, w);
    }
    __syncthreads();
  }
  float4 bv = make_float4(0.f, 0.f, 0.f, 0.f);
  if (BIAS) bv = *(const float4*)&bias[colBase + c0];
  for (int i = 0; i < 4; ++i) {
    float4 o;
    o.x = acc[i][0] + bv.x; o.y = acc[i][1] + bv.y;
    o.z = acc[i][2] + bv.z; o.w = acc[i][3] + bv.w;
    if (RELU) { o.x = fmaxf(o.x, 0.f); o.y = fmaxf(o.y, 0.f); o.z = fmaxf(o.z, 0.f); o.w = fmaxf(o.w, 0.f); }
    *(float4*)&C[(rowBase + r0 + i) * Ncols + colBase + c0] = o;
  }
}

// ---------------------------------------------------------------------------
// Classifier layer 1 on concatenated halves: o1 = relu([x[:B]|x[B:]] @ W + b)
// ---------------------------------------------------------------------------
__global__ __launch_bounds__(256) void gemm_cat_kernel(
    const float* __restrict__ X, const float* __restrict__ W,
    const float* __restrict__ bias, float* __restrict__ C)
{
  __shared__ float At[64 * 64];
  __shared__ float Ws[64 * 64];
  const int tid = threadIdx.x;
  const int rowBase = blockIdx.x * 64, colBase = blockIdx.y * 64;
  const int rgrp = tid >> 4, cgrp = tid & 15;
  const int r0 = rgrp * 4, c0 = cgrp * 4;
  float acc[4][4] = {{0.f}};
  for (int k0 = 0; k0 < 256; k0 += 64) {
    const float* base = (k0 < 128) ? X : (X + B2 * 128);
    const int kc = k0 & 127;
    for (int t = tid; t < 1024; t += 256) {
      int row = t & 63, kk = (t >> 6) << 2;
      float4 v = *(const float4*)&base[(rowBase + row) * 128 + kc + kk];
      At[(kk + 0) * 64 + row] = v.x; At[(kk + 1) * 64 + row] = v.y;
      At[(kk + 2) * 64 + row] = v.z; At[(kk + 3) * 64 + row] = v.w;
    }
    for (int t = tid; t < 1024; t += 256) {
      int d = t >> 4, c4 = (t & 15) << 2;
      *(float4*)&Ws[d * 64 + c4] = *(const float4*)&W[(k0 + d) * 128 + colBase + c4];
    }
    __syncthreads();
    #pragma unroll 8
    for (int d = 0; d < 64; ++d) {
      float4 a = *(const float4*)&At[d * 64 + r0];
      float4 w = *(const float4*)&Ws[d * 64 + c0];
      fma44(acc, a, w);
    }
    __syncthreads();
  }
  float4 bv = *(const float4*)&bias[colBase + c0];
  for (int i = 0; i < 4; ++i) {
    float4 o;
    o.x = fmaxf(acc[i][0] + bv.x, 0.f); o.y = fmaxf(acc[i][1] + bv.y, 0.f);
    o.z = fmaxf(acc[i][2] + bv.z, 0.f); o.w = fmaxf(acc[i][3] + bv.w, 0.f);
    *(float4*)&C[(rowBase + r0 + i) * 128 + colBase + c0] = o;
  }
}

// ---------------------------------------------------------------------------
// Fused z-GEMM + eh-fold. grid = 128 mixture-groups x 4 k-quarters (8 k each).
// ---------------------------------------------------------------------------
__global__ __launch_bounds__(256) void zfold_kernel(
    const float* __restrict__ xp, const float* __restrict__ We2,
    const float* __restrict__ interhb, const float* __restrict__ ia1,
    const float* __restrict__ ia2, const float* __restrict__ We1,
    const float* __restrict__ be1,
    float* __restrict__ aggA, float* __restrict__ aggB)
{
  __shared__ float xsT[128 * 36];
  __shared__ float Ws[64 * 128];
  __shared__ float ehs[3][16][32];
  __shared__ float accAs[16 * 128], accBs[16 * 128];
  const int tid = threadIdx.x;
  const int mg = blockIdx.x >> 2, kq = blockIdx.x & 3;
  const int i0 = mg * 16;

  for (int t = tid; t < 1024; t += 256) {
    int row = t & 31, d4 = t >> 5;
    int gr = (row < 16) ? (i0 + row) : (B2 + i0 + row - 16);
    float4 v = *(const float4*)&xp[gr * 128 + d4 * 4];
    xsT[(d4 * 4 + 0) * 36 + row] = v.x; xsT[(d4 * 4 + 1) * 36 + row] = v.y;
    xsT[(d4 * 4 + 2) * 36 + row] = v.z; xsT[(d4 * 4 + 3) * 36 + row] = v.w;
  }
  for (int t = tid; t < 512; t += 256) {
    int mm = t >> 5, k = t & 31;
    float a = We1[k], b = be1[k];
    ehs[0][mm][k] = fmaxf(fmaf(interhb[i0 + mm], a, b), 0.f);
    ehs[1][mm][k] = fmaxf(fmaf(ia1[i0 + mm],     a, b), 0.f);
    ehs[2][mm][k] = fmaxf(fmaf(ia2[i0 + mm],     a, b), 0.f);
  }
  for (int t = tid; t < 16 * 128; t += 256) { accAs[t] = 0.f; accBs[t] = 0.f; }

  const int rgrp = tid >> 5, cgrp = tid & 31;
  const int r0 = rgrp * 4, c0 = cgrp * 4;
  const int side = rgrp >> 2;
  float accLo[4][4] = {{0.f}}, accHi[4][4] = {{0.f}};

  for (int kk = 0; kk < 8; ++kk) {
    const int k = kq * 8 + kk;
    float z[4][4] = {{0.f}};
    for (int ch = 0; ch < 2; ++ch) {
      __syncthreads();
      for (int t = tid; t < 2048; t += 256) {
        int d = t >> 5, c4 = (t & 31) << 2;
        *(float4*)&Ws[d * 128 + c4] =
            *(const float4*)&We2[k * 16384 + (ch * 64 + d) * 128 + c4];
      }
      __syncthreads();
      #pragma unroll 4
      for (int d = 0; d < 64; ++d) {
        float4 a = *(const float4*)&xsT[(ch * 64 + d) * 36 + r0];
        float4 w = *(const float4*)&Ws[d * 128 + c0];
        fma44(z, a, w);
      }
    }
    #pragma unroll
    for (int i = 0; i < 4; ++i) {
      int mm = (r0 + i) & 15;
      float uLo = side ? ehs[0][mm][k] : ehs[1][mm][k];
      float uHi = side ? ehs[2][mm][k] : ehs[0][mm][k];
      #pragma unroll
      for (int j = 0; j < 4; ++j) {
        accLo[i][j] = fmaf(uLo, z[i][j], accLo[i][j]);
        accHi[i][j] = fmaf(uHi, z[i][j], accHi[i][j]);
      }
    }
  }
  __syncthreads();
  for (int i = 0; i < 4; ++i) {
    int mm = (r0 + i) & 15;
    for (int j = 0; j < 4; ++j) {
      atomicAdd(&accAs[mm * 128 + c0 + j], accLo[i][j]);
      atomicAdd(&accBs[mm * 128 + c0 + j], accHi[i][j]);
    }
  }
  __syncthreads();
  for (int t = tid; t < 2048; t += 256) {
    int mm = t >> 7, c = t & 127;
    atomicAdd(&aggA[(i0 + mm) * 128 + c], accAs[mm * 128 + c]);
    atomicAdd(&aggB[(i0 + mm) * 128 + c], accBs[mm * 128 + c]);
  }
}

__global__ __launch_bounds__(256) void xin_kernel(
    const float* __restrict__ aggA, const float* __restrict__ aggB,
    const float* __restrict__ zb, const float* __restrict__ bnn,
    float* __restrict__ x_in)
{
  int idx = blockIdx.x * 256 + threadIdx.x;
  int i = idx >> 7, c = idx & 127;
  float zs = zb[i * 128 + c] + zb[(i + B2) * 128 + c] + bnn[c];
  x_in[i * 128 + c]        = fmaxf(aggA[idx] + zs, 0.f);
  x_in[(i + B2) * 128 + c] = fmaxf(aggB[idx] + zs, 0.f);
}

__global__ __launch_bounds__(256) void gru_kernel(
    const float* __restrict__ gi, const float* __restrict__ gh,
    const float* __restrict__ xp, float* __restrict__ xnew)
{
  int idx = blockIdx.x * 256 + threadIdx.x;
  int n = idx >> 7, j = idx & 127;
  float ir = gi[n * 384 + j], iz = gi[n * 384 + 128 + j], ih = gi[n * 384 + 256 + j];
  float hr = gh[n * 384 + j], hz = gh[n * 384 + 128 + j], hn = gh[n * 384 + 256 + j];
  float h  = xp[idx];
  float r  = 1.f / (1.f + expf(-(ir + hr)));
  float zg = 1.f / (1.f + expf(-(iz + hz)));
  float ng = tanhf(ih + r * hn);
  xnew[idx] = (1.f - zg) * ng + zg * h;
}

__global__ __launch_bounds__(256) void final_kernel(
    const float* __restrict__ o2, const float* __restrict__ Wcl3,
    const float* __restrict__ bcl3, float* __restrict__ out)
{
  int idx = blockIdx.x * 256 + threadIdx.x;
  int i = idx >> 1, c = idx & 1;
  float acc = bcl3[c];
  for (int k = 0; k < 128; ++k) acc = fmaf(o2[i * 128 + k], Wcl3[k * 2 + c], acc);
  out[idx] = acc;
}

// ---------------------------------------------------------------------------
extern "C" void kernel_launch(void* const* d_in, const int* in_sizes, int n_in,
                              void* d_out, int out_size, void* d_ws, size_t ws_size,
                              hipStream_t stream)
{
  const float* h1   = (const float*)d_in[0];
  const float* h2   = (const float*)d_in[1];
  const float* s1x  = (const float*)d_in[2];
  const float* ihb  = (const float*)d_in[3];
  const float* ia1  = (const float*)d_in[4];
  const float* ia2  = (const float*)d_in[5];
  const float* Wg1  = (const float*)d_in[6];
  const float* bg1  = (const float*)d_in[7];
  const float* Wg2  = (const float*)d_in[8];
  const float* bg2  = (const float*)d_in[9];
  const float* Wp   = (const float*)d_in[10];
  const float* bp   = (const float*)d_in[11];
  const float* We1  = (const float*)d_in[12];
  const float* be1  = (const float*)d_in[13];
  const float* We2  = (const float*)d_in[14];
  const float* be2  = (const float*)d_in[15];
  const float* bnn  = (const float*)d_in[16];
  const float* Wih  = (const float*)d_in[17];
  const float* bih  = (const float*)d_in[18];
  const float* Whh  = (const float*)d_in[19];
  const float* bhh  = (const float*)d_in[20];
  const float* Wcl1 = (const float*)d_in[21];
  const float* bcl1 = (const float*)d_in[22];
  const float* Wcl2 = (const float*)d_in[23];
  const float* bcl2 = (const float*)d_in[24];
  const float* Wcl3 = (const float*)d_in[25];
  const float* bcl3 = (const float*)d_in[26];
  const int*   src1 = (const int*)d_in[27];
  const int*   dst1 = (const int*)d_in[28];
  const int*   src2 = (const int*)d_in[29];
  const int*   dst2 = (const int*)d_in[30];
  float* out = (float*)d_out;
  float* ws  = (float*)d_ws;

  float* Abuf = ws;                          // 4096*960  = 3,932,160
  float* agg2 = ws + 3932160;                // 122880*128 = 15,728,640
  float* dwn  = ws + 19660800;

  float* xcat = dwn;
  float* xp   = dwn + 524288;
  float* zb   = dwn + 1048576;
  float* aggA = dwn + 1572864;
  float* aggB = dwn + 1835008;
  float* x_in = dwn + 2097152;
  float* gi   = dwn + 2621440;
  float* gh   = dwn + 4194304;
  float* xnew = dwn + 5767168;
  float* o1   = dwn + 6291456;
  float* o2   = dwn + 6553600;

  // ---- GraphConv pipeline (dense per-molecule adjacency) ----
  adj_kernel<<<1024, 256, 0, stream>>>(src1, dst1, src2, dst2, Abuf);
  g1agg2_kernel<<<2048, 256, 0, stream>>>(h1, h2, Abuf, Wg1, bg1, agg2);
  g2pool_kernel<<<2048, 256, 0, stream>>>(agg2, Wg2, bg2, s1x, xcat);

  // ---- solvent-system MPNN + GRU + classifier ----
  gemm_kernel<1, 1><<<dim3(64, 2), 256, 0, stream>>>(xcat, Wp, bp, xp, 4096, 128, 128);
  gemm_kernel<0, 0><<<dim3(64, 2), 256, 0, stream>>>(xp, be2, nullptr, zb, 4096, 128, 128);
  hipMemsetAsync(aggA, 0, 2 * 262144 * sizeof(float), stream);
  zfold_kernel<<<512, 256, 0, stream>>>(xp, We2, ihb, ia1, ia2, We1, be1, aggA, aggB);
  xin_kernel<<<1024, 256, 0, stream>>>(aggA, aggB, zb, bnn, x_in);
  gemm_kernel<0, 1><<<dim3(64, 6), 256, 0, stream>>>(x_in, Wih, bih, gi, 4096, 384, 128);
  gemm_kernel<0, 1><<<dim3(64, 6), 256, 0, stream>>>(xp, Whh, bhh, gh, 4096, 384, 128);
  gru_kernel<<<2048, 256, 0, stream>>>(gi, gh, xp, xnew);
  gemm_cat_kernel<<<dim3(32, 2), 256, 0, stream>>>(xnew, Wcl1, bcl1, o1);
  gemm_kernel<1, 1><<<dim3(32, 2), 256, 0, stream>>>(o1, Wcl2, bcl2, o2, 2048, 128, 128);
  final_kernel<<<16, 256, 0, stream>>>(o2, Wcl3, bcl3, out);
}

// Round 6
// 379.041 us; speedup vs baseline: 2.4227x; 1.0069x over previous
//
#include <hip/hip_runtime.h>
#include <hip/hip_bf16.h>
#include <math.h>

#define B2    2048
#define NPM   30
#define EPM   120

typedef __attribute__((ext_vector_type(8))) short short8;
typedef __attribute__((ext_vector_type(4))) float f32x4;

__device__ __forceinline__ ushort f2bf(float x) {
  unsigned u = __float_as_uint(x);
  return (ushort)((u + 0x7FFFu + ((u >> 16) & 1u)) >> 16);
}
__device__ __forceinline__ float bf2f(ushort h) {
  return __uint_as_float(((unsigned)h) << 16);
}

// ---------------------------------------------------------------------------
// micro-tile FMA helpers (fp32 kernels)
// ---------------------------------------------------------------------------
__device__ __forceinline__ void fma44(float (&acc)[4][4], const float4 a, const float4 w) {
  acc[0][0] = fmaf(a.x, w.x, acc[0][0]); acc[0][1] = fmaf(a.x, w.y, acc[0][1]);
  acc[0][2] = fmaf(a.x, w.z, acc[0][2]); acc[0][3] = fmaf(a.x, w.w, acc[0][3]);
  acc[1][0] = fmaf(a.y, w.x, acc[1][0]); acc[1][1] = fmaf(a.y, w.y, acc[1][1]);
  acc[1][2] = fmaf(a.y, w.z, acc[1][2]); acc[1][3] = fmaf(a.y, w.w, acc[1][3]);
  acc[2][0] = fmaf(a.z, w.x, acc[2][0]); acc[2][1] = fmaf(a.z, w.y, acc[2][1]);
  acc[2][2] = fmaf(a.z, w.z, acc[2][2]); acc[2][3] = fmaf(a.z, w.w, acc[2][3]);
  acc[3][0] = fmaf(a.w, w.x, acc[3][0]); acc[3][1] = fmaf(a.w, w.y, acc[3][1]);
  acc[3][2] = fmaf(a.w, w.z, acc[3][2]); acc[3][3] = fmaf(a.w, w.w, acc[3][3]);
}

__device__ __forceinline__ void fmas4(float (&acc)[4], float s, const float4 w) {
  acc[0] = fmaf(s, w.x, acc[0]); acc[1] = fmaf(s, w.y, acc[1]);
  acc[2] = fmaf(s, w.z, acc[2]); acc[3] = fmaf(s, w.w, acc[3]);
}

__device__ __forceinline__ void fma48(float (&acc)[4][8], const float4 a,
                                      const float4 w0, const float4 w1) {
  const float av[4] = {a.x, a.y, a.z, a.w};
  #pragma unroll
  for (int i = 0; i < 4; ++i) {
    acc[i][0] = fmaf(av[i], w0.x, acc[i][0]); acc[i][1] = fmaf(av[i], w0.y, acc[i][1]);
    acc[i][2] = fmaf(av[i], w0.z, acc[i][2]); acc[i][3] = fmaf(av[i], w0.w, acc[i][3]);
    acc[i][4] = fmaf(av[i], w1.x, acc[i][4]); acc[i][5] = fmaf(av[i], w1.y, acc[i][5]);
    acc[i][6] = fmaf(av[i], w1.z, acc[i][6]); acc[i][7] = fmaf(av[i], w1.w, acc[i][7]);
  }
}

// ---------------------------------------------------------------------------
// prep: W[K][N] fp32 -> transposed bf16 split: hi/lo[N][K]
// ---------------------------------------------------------------------------
__global__ __launch_bounds__(256) void prep_kernel(
    const float* __restrict__ W, ushort* __restrict__ hi, ushort* __restrict__ lo,
    int K, int N)
{
  int idx = blockIdx.x * 256 + threadIdx.x;
  int tot = N * (K >> 3);
  if (idx >= tot) return;
  int n = idx / (K >> 3);
  int k8 = (idx - n * (K >> 3)) << 3;
  #pragma unroll
  for (int j = 0; j < 8; ++j) {
    float x = W[(long)(k8 + j) * N + n];
    ushort h = f2bf(x);
    hi[(long)n * K + k8 + j] = h;
    lo[(long)n * K + k8 + j] = f2bf(x - bf2f(h));
  }
}

// ---------------------------------------------------------------------------
// MFMA GEMM, split-bf16 (3 mfma / fragment): C = [relu](A @ W [+ bias]).
// A fp32 [M][lda]; W pre-split bf16 transposed [N][K]. Tile 64x32, 2 waves.
// CAT: rows come from A (k<128) / A2 (k>=128), both stride lda.
// ---------------------------------------------------------------------------
template<int RELU, int BIAS, int CAT>
__global__ __launch_bounds__(128) void gemm_mfma_kernel(
    const float* __restrict__ A, const float* __restrict__ A2,
    const ushort* __restrict__ Wh, const ushort* __restrict__ Wl,
    const float* __restrict__ bias, float* __restrict__ C,
    int M, int N, int K, int lda)
{
  __shared__ __align__(16) ushort Ah[64 * 72], Al[64 * 72];
  __shared__ __align__(16) ushort Bh[32 * 72], Bl[32 * 72];
  const int tid = threadIdx.x;
  const int w = tid >> 6, l = tid & 63;
  const long rowBase = (long)blockIdx.x * 64;
  const int colBase = blockIdx.y * 32;

  f32x4 acc[2][2];
  #pragma unroll
  for (int fr = 0; fr < 2; ++fr)
    #pragma unroll
    for (int fc = 0; fc < 2; ++fc)
      acc[fr][fc] = (f32x4){0.f, 0.f, 0.f, 0.f};

  for (int k0 = 0; k0 < K; k0 += 64) {
    const float* Ab = (CAT && k0 >= 128) ? A2 : A;
    const int kc = CAT ? (k0 & 127) : k0;
    // stage A tile (64 rows x 64 k), fp32 -> bf16 hi/lo
    #pragma unroll
    for (int q = 0; q < 8; ++q) {
      int lin = tid + 128 * q;              // 0..1023 float4s
      int r = lin >> 4, k4 = (lin & 15) << 2;
      float4 v = *(const float4*)&Ab[(rowBase + r) * lda + kc + k4];
      ushort4 h4, l4;
      h4.x = f2bf(v.x); l4.x = f2bf(v.x - bf2f(h4.x));
      h4.y = f2bf(v.y); l4.y = f2bf(v.y - bf2f(h4.y));
      h4.z = f2bf(v.z); l4.z = f2bf(v.z - bf2f(h4.z));
      h4.w = f2bf(v.w); l4.w = f2bf(v.w - bf2f(h4.w));
      *(ushort4*)&Ah[r * 72 + k4] = h4;
      *(ushort4*)&Al[r * 72 + k4] = l4;
    }
    // stage B tile (32 cols x 64 k), already bf16 transposed
    #pragma unroll
    for (int q = 0; q < 2; ++q) {
      int lin = tid + 128 * q;              // 0..255 ushort8s
      int n = lin >> 3, k8 = (lin & 7) << 3;
      *(uint4*)&Bh[n * 72 + k8] = *(const uint4*)&Wh[(long)(colBase + n) * K + k0 + k8];
      *(uint4*)&Bl[n * 72 + k8] = *(const uint4*)&Wl[(long)(colBase + n) * K + k0 + k8];
    }
    __syncthreads();
    #pragma unroll
    for (int ks = 0; ks < 2; ++ks) {
      const int ko = ks * 32 + (l >> 4) * 8;
      short8 ah[2], al8[2], bh[2], bl8[2];
      #pragma unroll
      for (int fr = 0; fr < 2; ++fr) {
        int r = w * 32 + fr * 16 + (l & 15);
        ah[fr]  = *(const short8*)&Ah[r * 72 + ko];
        al8[fr] = *(const short8*)&Al[r * 72 + ko];
      }
      #pragma unroll
      for (int fc = 0; fc < 2; ++fc) {
        int c = fc * 16 + (l & 15);
        bh[fc]  = *(const short8*)&Bh[c * 72 + ko];
        bl8[fc] = *(const short8*)&Bl[c * 72 + ko];
      }
      #pragma unroll
      for (int fr = 0; fr < 2; ++fr)
        #pragma unroll
        for (int fc = 0; fc < 2; ++fc) {
          acc[fr][fc] = __builtin_amdgcn_mfma_f32_16x16x32_bf16(al8[fr], bh[fc], acc[fr][fc], 0, 0, 0);
          acc[fr][fc] = __builtin_amdgcn_mfma_f32_16x16x32_bf16(ah[fr], bl8[fc], acc[fr][fc], 0, 0, 0);
          acc[fr][fc] = __builtin_amdgcn_mfma_f32_16x16x32_bf16(ah[fr], bh[fc], acc[fr][fc], 0, 0, 0);
        }
    }
    __syncthreads();
  }
  // epilogue: C row = rowBase + w*32 + fr*16 + (l>>4)*4 + i, col = colBase + fc*16 + (l&15)
  #pragma unroll
  for (int fc = 0; fc < 2; ++fc) {
    int col = colBase + fc * 16 + (l & 15);
    float bv = BIAS ? bias[col] : 0.f;
    #pragma unroll
    for (int fr = 0; fr < 2; ++fr) {
      #pragma unroll
      for (int i = 0; i < 4; ++i) {
        long row = rowBase + w * 32 + fr * 16 + ((l >> 4) << 2) + i;
        float v = acc[fr][fc][i] + bv;
        if (RELU) v = fmaxf(v, 0.f);
        C[row * N + col] = v;
      }
    }
  }
}

// ---------------------------------------------------------------------------
// adj: normalized dense adjacency Â[d][s] = cnt(s->d)*rsI[d]*rsO[s].
// ---------------------------------------------------------------------------
__global__ __launch_bounds__(256) void adj_kernel(
    const int* __restrict__ src1, const int* __restrict__ dst1,
    const int* __restrict__ src2, const int* __restrict__ dst2,
    float* __restrict__ Abuf)
{
  __shared__ float cnt[4][30 * 33];
  __shared__ float rsOa[4][32], rsIa[4][32];
  const int tid = threadIdx.x, wid = tid >> 6, lane = tid & 63;
  const int gm = blockIdx.x * 4 + wid;
  const int g = gm >> 11, m = gm & 2047;
  const int* src = g ? src2 : src1;
  const int* dst = g ? dst2 : dst1;

  for (int i = lane; i < 30 * 33; i += 64) cnt[wid][i] = 0.f;
  __syncthreads();
  for (int e = lane; e < EPM; e += 64) {
    int s = src[m * EPM + e] - m * NPM;
    int d = dst[m * EPM + e] - m * NPM;
    atomicAdd(&cnt[wid][d * 33 + s], 1.0f);
  }
  __syncthreads();
  if (lane < NPM) {
    float sum = 0.f;
    for (int s = 0; s < NPM; ++s) sum += cnt[wid][lane * 33 + s];
    rsIa[wid][lane] = rsqrtf(fmaxf(sum, 1.f));
  } else if (lane >= 32 && lane < 32 + NPM) {
    int s = lane - 32; float sum = 0.f;
    for (int d = 0; d < NPM; ++d) sum += cnt[wid][d * 33 + s];
    rsOa[wid][s] = rsqrtf(fmaxf(sum, 1.f));
  }
  __syncthreads();
  const long base = (long)gm * 960;
  for (int i = lane; i < 960; i += 64) {
    int d = i >> 5, s = i & 31;
    float v = (d < NPM && s < NPM)
            ? cnt[wid][d * 33 + s] * rsIa[wid][d] * rsOa[wid][s] : 0.f;
    Abuf[base + i] = v;
  }
}

// ---------------------------------------------------------------------------
// g1agg2: y1 = X @ Wg1, t1 = relu(Â@y1 + bg1), agg2 = Â@t1 -> global
// ---------------------------------------------------------------------------
__global__ __launch_bounds__(256, 2) void g1agg2_kernel(
    const float* __restrict__ h1, const float* __restrict__ h2,
    const float* __restrict__ Abuf,
    const float* __restrict__ Wg1, const float* __restrict__ bg1,
    float* __restrict__ agg2)
{
  __shared__ float pool[15360];
  __shared__ float AbL[2 * 990];
  float* XT  = pool;
  float* Ws  = pool + 5120;
  float* y1s = pool;
  float* t1s = pool + 7680;

  const int tid = threadIdx.x;
  const int p = blockIdx.x;
  const int g = p >> 10;
  const int mloc = (p & 1023) * 2;
  const float* hsrc = g ? h2 : h1;

  for (int t = tid; t < 2560; t += 256) {
    int r = t & 63, k2 = (t >> 6) << 1;
    float2 v = make_float2(0.f, 0.f);
    if (r < 60 && k2 < 74)
      v = *(const float2*)&hsrc[((long)(mloc * 30 + r)) * 74 + k2];
    XT[k2 * 64 + r]       = v.x;
    XT[(k2 + 1) * 64 + r] = v.y;
  }
  for (int t = tid; t < 2560; t += 256) {
    int d = t >> 5, c4 = (t & 31) << 2;
    float4 w = (d < 74) ? *(const float4*)&Wg1[d * 128 + c4]
                        : make_float4(0.f, 0.f, 0.f, 0.f);
    *(float4*)&Ws[d * 128 + c4] = w;
  }
  {
    const long ab = (long)(g * 2048 + mloc) * 960;
    for (int t = tid; t < 1920; t += 256) {
      int mm = (t >= 960) ? 1 : 0; int j = t - mm * 960;
      int d = j >> 5, s = j & 31;
      AbL[mm * 990 + d * 33 + s] = Abuf[ab + t];
    }
  }
  __syncthreads();

  const int rgrp = tid >> 4, cgrp = tid & 15;
  const int c0 = cgrp * 4;
  float accA[4][4], accB[4][4];

  {
    const int r0 = rgrp * 4;
    for (int i = 0; i < 4; ++i)
      for (int j = 0; j < 4; ++j) { accA[i][j] = 0.f; accB[i][j] = 0.f; }
    #pragma unroll 8
    for (int k = 0; k < 80; ++k) {
      float4 a  = *(const float4*)&XT[k * 64 + r0];
      float4 w0 = *(const float4*)&Ws[k * 128 + c0];
      float4 w1 = *(const float4*)&Ws[k * 128 + c0 + 64];
      fma44(accA, a, w0);
      fma44(accB, a, w1);
    }
  }
  __syncthreads();
  {
    const int r0 = rgrp * 4;
    for (int i = 0; i < 4; ++i) {
      int r = r0 + i;
      if (r < 60) {
        *(float4*)&y1s[r * 128 + c0]      = make_float4(accA[i][0], accA[i][1], accA[i][2], accA[i][3]);
        *(float4*)&y1s[r * 128 + c0 + 64] = make_float4(accB[i][0], accB[i][1], accB[i][2], accB[i][3]);
      }
    }
  }
  __syncthreads();

  const int mol = rgrp >> 3;
  const int d0  = (rgrp & 7) * 4;
  const float* Am = &AbL[mol * 990];
  float4 bv0 = *(const float4*)&bg1[c0];
  float4 bv1 = *(const float4*)&bg1[c0 + 64];

  {
    for (int i = 0; i < 4; ++i)
      for (int j = 0; j < 4; ++j) { accA[i][j] = 0.f; accB[i][j] = 0.f; }
    #pragma unroll 5
    for (int s = 0; s < 30; ++s) {
      float4 ya = *(const float4*)&y1s[(mol * 30 + s) * 128 + c0];
      float4 yb = *(const float4*)&y1s[(mol * 30 + s) * 128 + c0 + 64];
      for (int i = 0; i < 4; ++i) {
        float ab = Am[(d0 + i) * 33 + s];
        fmas4(accA[i], ab, ya);
        fmas4(accB[i], ab, yb);
      }
    }
    for (int i = 0; i < 4; ++i) {
      int d = d0 + i;
      if (d < NPM) {
        int r = mol * 30 + d;
        float4 oa, ob;
        oa.x = fmaxf(accA[i][0] + bv0.x, 0.f); oa.y = fmaxf(accA[i][1] + bv0.y, 0.f);
        oa.z = fmaxf(accA[i][2] + bv0.z, 0.f); oa.w = fmaxf(accA[i][3] + bv0.w, 0.f);
        ob.x = fmaxf(accB[i][0] + bv1.x, 0.f); ob.y = fmaxf(accB[i][1] + bv1.y, 0.f);
        ob.z = fmaxf(accB[i][2] + bv1.z, 0.f); ob.w = fmaxf(accB[i][3] + bv1.w, 0.f);
        *(float4*)&t1s[r * 128 + c0]      = oa;
        *(float4*)&t1s[r * 128 + c0 + 64] = ob;
      }
    }
  }
  __syncthreads();

  {
    for (int i = 0; i < 4; ++i)
      for (int j = 0; j < 4; ++j) { accA[i][j] = 0.f; accB[i][j] = 0.f; }
    #pragma unroll 5
    for (int s = 0; s < 30; ++s) {
      float4 ta = *(const float4*)&t1s[(mol * 30 + s) * 128 + c0];
      float4 tb = *(const float4*)&t1s[(mol * 30 + s) * 128 + c0 + 64];
      for (int i = 0; i < 4; ++i) {
        float ab = Am[(d0 + i) * 33 + s];
        fmas4(accA[i], ab, ta);
        fmas4(accB[i], ab, tb);
      }
    }
    for (int i = 0; i < 4; ++i) {
      int d = d0 + i;
      if (d < NPM) {
        long row = ((long)p * 60 + mol * 30 + d) * 128;
        *(float4*)&agg2[row + c0]      = make_float4(accA[i][0], accA[i][1], accA[i][2], accA[i][3]);
        *(float4*)&agg2[row + c0 + 64] = make_float4(accB[i][0], accB[i][1], accB[i][2], accB[i][3]);
      }
    }
  }
}

// ---------------------------------------------------------------------------
// G2+pool: 60-row tile, full 128 cols, 4x(4+4) micro-tile (c0 / c0+64 split).
// ---------------------------------------------------------------------------
__global__ __launch_bounds__(256) void g2pool_kernel(
    const float* __restrict__ A, const float* __restrict__ W,
    const float* __restrict__ bias, const float* __restrict__ s1x,
    float* __restrict__ xcat)
{
  __shared__ float At[64 * 64];
  __shared__ float Ws[64 * 128];
  __shared__ float cs[2 * 128];
  const int tid = threadIdx.x;
  const long rowBase = (long)blockIdx.x * 60;
  const int rgrp = tid >> 4, cgrp = tid & 15;
  const int r0 = rgrp * 4, c0 = cgrp * 4;
  cs[tid] = 0.f;
  float acc[4][8] = {{0.f}};
  for (int k0 = 0; k0 < 128; k0 += 64) {
    for (int t = tid; t < 1024; t += 256) {
      int row = t & 63, kk = (t >> 6) << 2;
      float4 v = make_float4(0.f, 0.f, 0.f, 0.f);
      if (row < 60)
        v = *(const float4*)&A[(rowBase + row) * 128 + k0 + kk];
      At[(kk + 0) * 64 + row] = v.x; At[(kk + 1) * 64 + row] = v.y;
      At[(kk + 2) * 64 + row] = v.z; At[(kk + 3) * 64 + row] = v.w;
    }
    for (int t = tid; t < 2048; t += 256) {
      int d = t >> 5, c4 = (t & 31) << 2;
      *(float4*)&Ws[d * 128 + c4] = *(const float4*)&W[(k0 + d) * 128 + c4];
    }
    __syncthreads();
    #pragma unroll 8
    for (int d = 0; d < 64; ++d) {
      float4 a  = *(const float4*)&At[d * 64 + r0];
      float4 w0 = *(const float4*)&Ws[d * 128 + c0];
      float4 w1 = *(const float4*)&Ws[d * 128 + c0 + 64];
      fma48(acc, a, w0, w1);
    }
    __syncthreads();
  }
  float4 bv0 = *(const float4*)&bias[c0];
  float4 bv1 = *(const float4*)&bias[c0 + 64];
  const float bb[8] = {bv0.x, bv0.y, bv0.z, bv0.w, bv1.x, bv1.y, bv1.z, bv1.w};
  float p0[8] = {0,0,0,0,0,0,0,0}, p1[8] = {0,0,0,0,0,0,0,0};
  for (int i = 0; i < 4; ++i) {
    int r = r0 + i;
    if (r < 60) {
      float* p = (r < NPM) ? p0 : p1;
      #pragma unroll
      for (int j = 0; j < 8; ++j) p[j] += fmaxf(acc[i][j] + bb[j], 0.f);
    }
  }
  #pragma unroll
  for (int j = 0; j < 4; ++j) {
    atomicAdd(&cs[c0 + j],            p0[j]);
    atomicAdd(&cs[c0 + 64 + j],       p0[j + 4]);
    atomicAdd(&cs[128 + c0 + j],      p1[j]);
    atomicAdd(&cs[128 + c0 + 64 + j], p1[j + 4]);
  }
  __syncthreads();
  {
    int moll = tid >> 7, c = tid & 127;
    int gm = blockIdx.x * 2 + moll;
    int gg = gm >> 11, mm = gm & 2047;
    float sf = gg ? (1.f - s1x[mm]) : s1x[mm];
    xcat[(long)gm * 128 + c] = cs[moll * 128 + c] * (1.f / 30.f) * sf;
  }
}

// ---------------------------------------------------------------------------
// Fused z-GEMM + eh-fold. grid = 128 mixture-groups x 4 k-quarters.
// ---------------------------------------------------------------------------
__global__ __launch_bounds__(256) void zfold_kernel(
    const float* __restrict__ xp, const float* __restrict__ We2,
    const float* __restrict__ interhb, const float* __restrict__ ia1,
    const float* __restrict__ ia2, const float* __restrict__ We1,
    const float* __restrict__ be1,
    float* __restrict__ aggA, float* __restrict__ aggB)
{
  __shared__ float xsT[128 * 36];
  __shared__ float Ws[64 * 128];
  __shared__ float ehs[3][16][32];
  __shared__ float accAs[16 * 128], accBs[16 * 128];
  const int tid = threadIdx.x;
  const int mg = blockIdx.x >> 2, kq = blockIdx.x & 3;
  const int i0 = mg * 16;

  for (int t = tid; t < 1024; t += 256) {
    int row = t & 31, d4 = t >> 5;
    int gr = (row < 16) ? (i0 + row) : (B2 + i0 + row - 16);
    float4 v = *(const float4*)&xp[gr * 128 + d4 * 4];
    xsT[(d4 * 4 + 0) * 36 + row] = v.x; xsT[(d4 * 4 + 1) * 36 + row] = v.y;
    xsT[(d4 * 4 + 2) * 36 + row] = v.z; xsT[(d4 * 4 + 3) * 36 + row] = v.w;
  }
  for (int t = tid; t < 512; t += 256) {
    int mm = t >> 5, k = t & 31;
    float a = We1[k], b = be1[k];
    ehs[0][mm][k] = fmaxf(fmaf(interhb[i0 + mm], a, b), 0.f);
    ehs[1][mm][k] = fmaxf(fmaf(ia1[i0 + mm],     a, b), 0.f);
    ehs[2][mm][k] = fmaxf(fmaf(ia2[i0 + mm],     a, b), 0.f);
  }
  for (int t = tid; t < 16 * 128; t += 256) { accAs[t] = 0.f; accBs[t] = 0.f; }

  const int rgrp = tid >> 5, cgrp = tid & 31;
  const int r0 = rgrp * 4, c0 = cgrp * 4;
  const int side = rgrp >> 2;
  float accLo[4][4] = {{0.f}}, accHi[4][4] = {{0.f}};

  for (int kk = 0; kk < 8; ++kk) {
    const int k = kq * 8 + kk;
    float z[4][4] = {{0.f}};
    for (int ch = 0; ch < 2; ++ch) {
      __syncthreads();
      for (int t = tid; t < 2048; t += 256) {
        int d = t >> 5, c4 = (t & 31) << 2;
        *(float4*)&Ws[d * 128 + c4] =
            *(const float4*)&We2[k * 16384 + (ch * 64 + d) * 128 + c4];
      }
      __syncthreads();
      #pragma unroll 4
      for (int d = 0; d < 64; ++d) {
        float4 a = *(const float4*)&xsT[(ch * 64 + d) * 36 + r0];
        float4 w = *(const float4*)&Ws[d * 128 + c0];
        fma44(z, a, w);
      }
    }
    #pragma unroll
    for (int i = 0; i < 4; ++i) {
      int mm = (r0 + i) & 15;
      float uLo = side ? ehs[0][mm][k] : ehs[1][mm][k];
      float uHi = side ? ehs[2][mm][k] : ehs[0][mm][k];
      #pragma unroll
      for (int j = 0; j < 4; ++j) {
        accLo[i][j] = fmaf(uLo, z[i][j], accLo[i][j]);
        accHi[i][j] = fmaf(uHi, z[i][j], accHi[i][j]);
      }
    }
  }
  __syncthreads();
  for (int i = 0; i < 4; ++i) {
    int mm = (r0 + i) & 15;
    for (int j = 0; j < 4; ++j) {
      atomicAdd(&accAs[mm * 128 + c0 + j], accLo[i][j]);
      atomicAdd(&accBs[mm * 128 + c0 + j], accHi[i][j]);
    }
  }
  __syncthreads();
  for (int t = tid; t < 2048; t += 256) {
    int mm = t >> 7, c = t & 127;
    atomicAdd(&aggA[(i0 + mm) * 128 + c], accAs[mm * 128 + c]);
    atomicAdd(&aggB[(i0 + mm) * 128 + c], accBs[mm * 128 + c]);
  }
}

__global__ __launch_bounds__(256) void xin_kernel(
    const float* __restrict__ aggA, const float* __restrict__ aggB,
    const float* __restrict__ zb, const float* __restrict__ bnn,
    float* __restrict__ x_in)
{
  int idx = blockIdx.x * 256 + threadIdx.x;
  int i = idx >> 7, c = idx & 127;
  float zs = zb[i * 128 + c] + zb[(i + B2) * 128 + c] + bnn[c];
  x_in[i * 128 + c]        = fmaxf(aggA[idx] + zs, 0.f);
  x_in[(i + B2) * 128 + c] = fmaxf(aggB[idx] + zs, 0.f);
}

__global__ __launch_bounds__(256) void gru_kernel(
    const float* __restrict__ gi, const float* __restrict__ gh,
    const float* __restrict__ xp, float* __restrict__ xnew)
{
  int idx = blockIdx.x * 256 + threadIdx.x;
  int n = idx >> 7, j = idx & 127;
  float ir = gi[n * 384 + j], iz = gi[n * 384 + 128 + j], ih = gi[n * 384 + 256 + j];
  float hr = gh[n * 384 + j], hz = gh[n * 384 + 128 + j], hn = gh[n * 384 + 256 + j];
  float h  = xp[idx];
  float r  = 1.f / (1.f + expf(-(ir + hr)));
  float zg = 1.f / (1.f + expf(-(iz + hz)));
  float ng = tanhf(ih + r * hn);
  xnew[idx] = (1.f - zg) * ng + zg * h;
}

__global__ __launch_bounds__(256) void final_kernel(
    const float* __restrict__ o2, const float* __restrict__ Wcl3,
    const float* __restrict__ bcl3, float* __restrict__ out)
{
  int idx = blockIdx.x * 256 + threadIdx.x;
  int i = idx >> 1, c = idx & 1;
  float acc = bcl3[c];
  for (int k = 0; k < 128; ++k) acc = fmaf(o2[i * 128 + k], Wcl3[k * 2 + c], acc);
  out[idx] = acc;
}

// ---------------------------------------------------------------------------
extern "C" void kernel_launch(void* const* d_in, const int* in_sizes, int n_in,
                              void* d_out, int out_size, void* d_ws, size_t ws_size,
                              hipStream_t stream)
{
  const float* h1   = (const float*)d_in[0];
  const float* h2   = (const float*)d_in[1];
  const float* s1x  = (const float*)d_in[2];
  const float* ihb  = (const float*)d_in[3];
  const float* ia1  = (const float*)d_in[4];
  const float* ia2  = (const float*)d_in[5];
  const float* Wg1  = (const float*)d_in[6];
  const float* bg1  = (const float*)d_in[7];
  const float* Wg2  = (const float*)d_in[8];
  const float* bg2  = (const float*)d_in[9];
  const float* Wp   = (const float*)d_in[10];
  const float* bp   = (const float*)d_in[11];
  const float* We1  = (const float*)d_in[12];
  const float* be1  = (const float*)d_in[13];
  const float* We2  = (const float*)d_in[14];
  const float* be2  = (const float*)d_in[15];
  const float* bnn  = (const float*)d_in[16];
  const float* Wih  = (const float*)d_in[17];
  const float* bih  = (const float*)d_in[18];
  const float* Whh  = (const float*)d_in[19];
  const float* bhh  = (const float*)d_in[20];
  const float* Wcl1 = (const float*)d_in[21];
  const float* bcl1 = (const float*)d_in[22];
  const float* Wcl2 = (const float*)d_in[23];
  const float* bcl2 = (const float*)d_in[24];
  const float* Wcl3 = (const float*)d_in[25];
  const float* bcl3 = (const float*)d_in[26];
  const int*   src1 = (const int*)d_in[27];
  const int*   dst1 = (const int*)d_in[28];
  const int*   src2 = (const int*)d_in[29];
  const int*   dst2 = (const int*)d_in[30];
  float* out = (float*)d_out;
  float* ws  = (float*)d_ws;

  float* Abuf = ws;                          // 4096*960
  float* agg2 = ws + 3932160;                // 122880*128
  float* dwn  = ws + 19660800;

  float* xcat = dwn;
  float* xp   = dwn + 524288;
  float* zb   = dwn + 1048576;
  float* aggA = dwn + 1572864;
  float* aggB = dwn + 1835008;
  float* x_in = dwn + 2097152;
  float* gi   = dwn + 2621440;
  float* gh   = dwn + 4194304;
  float* xnew = dwn + 5767168;
  float* o1   = dwn + 6291456;
  float* o2   = dwn + 6553600;

  // bf16-split transposed weights (ushort arrays)
  ushort* wt     = (ushort*)(dwn + 6815744);
  ushort* WpTh   = wt;               ushort* WpTl   = wt + 16384;
  ushort* be2Th  = wt + 32768;       ushort* be2Tl  = wt + 49152;
  ushort* WihTh  = wt + 65536;       ushort* WihTl  = wt + 114688;
  ushort* WhhTh  = wt + 163840;      ushort* WhhTl  = wt + 212992;
  ushort* Wcl1Th = wt + 262144;      ushort* Wcl1Tl = wt + 294912;
  ushort* Wcl2Th = wt + 327680;      ushort* Wcl2Tl = wt + 344064;

  // ---- weight prep (bf16 split + transpose) ----
  prep_kernel<<<8, 256, 0, stream>>>(Wp,   WpTh,   WpTl,   128, 128);
  prep_kernel<<<8, 256, 0, stream>>>(be2,  be2Th,  be2Tl,  128, 128);
  prep_kernel<<<24, 256, 0, stream>>>(Wih,  WihTh,  WihTl,  128, 384);
  prep_kernel<<<24, 256, 0, stream>>>(Whh,  WhhTh,  WhhTl,  128, 384);
  prep_kernel<<<16, 256, 0, stream>>>(Wcl1, Wcl1Th, Wcl1Tl, 256, 128);
  prep_kernel<<<8, 256, 0, stream>>>(Wcl2, Wcl2Th, Wcl2Tl, 128, 128);

  // ---- GraphConv pipeline (dense per-molecule adjacency) ----
  adj_kernel<<<1024, 256, 0, stream>>>(src1, dst1, src2, dst2, Abuf);
  g1agg2_kernel<<<2048, 256, 0, stream>>>(h1, h2, Abuf, Wg1, bg1, agg2);
  g2pool_kernel<<<2048, 256, 0, stream>>>(agg2, Wg2, bg2, s1x, xcat);

  // ---- solvent-system MPNN + GRU + classifier (MFMA GEMMs) ----
  gemm_mfma_kernel<1, 1, 0><<<dim3(64, 4), 128, 0, stream>>>(
      xcat, nullptr, WpTh, WpTl, bp, xp, 4096, 128, 128, 128);
  gemm_mfma_kernel<0, 0, 0><<<dim3(64, 4), 128, 0, stream>>>(
      xp, nullptr, be2Th, be2Tl, nullptr, zb, 4096, 128, 128, 128);
  hipMemsetAsync(aggA, 0, 2 * 262144 * sizeof(float), stream);
  zfold_kernel<<<512, 256, 0, stream>>>(xp, We2, ihb, ia1, ia2, We1, be1, aggA, aggB);
  xin_kernel<<<1024, 256, 0, stream>>>(aggA, aggB, zb, bnn, x_in);
  gemm_mfma_kernel<0, 1, 0><<<dim3(64, 12), 128, 0, stream>>>(
      x_in, nullptr, WihTh, WihTl, bih, gi, 4096, 384, 128, 128);
  gemm_mfma_kernel<0, 1, 0><<<dim3(64, 12), 128, 0, stream>>>(
      xp, nullptr, WhhTh, WhhTl, bhh, gh, 4096, 384, 128, 128);
  gru_kernel<<<2048, 256, 0, stream>>>(gi, gh, xp, xnew);
  gemm_mfma_kernel<1, 1, 1><<<dim3(32, 4), 128, 0, stream>>>(
      xnew, xnew + (long)B2 * 128, Wcl1Th, Wcl1Tl, bcl1, o1, 2048, 128, 256, 128);
  gemm_mfma_kernel<1, 1, 0><<<dim3(32, 4), 128, 0, stream>>>(
      o1, nullptr, Wcl2Th, Wcl2Tl, bcl2, o2, 2048, 128, 128, 128);
  final_kernel<<<16, 256, 0, stream>>>(o2, Wcl3, bcl3, out);
}

// Round 7
// 357.796 us; speedup vs baseline: 2.5665x; 1.0594x over previous
//
#include <hip/hip_runtime.h>
#include <hip/hip_bf16.h>
#include <math.h>

#define B2    2048
#define NPM   30
#define EPM   120

typedef __attribute__((ext_vector_type(8))) short short8;
typedef __attribute__((ext_vector_type(4))) float f32x4;

__device__ __forceinline__ ushort f2bf(float x) {
  unsigned u = __float_as_uint(x);
  return (ushort)((u + 0x7FFFu + ((u >> 16) & 1u)) >> 16);
}
__device__ __forceinline__ float bf2f(ushort h) {
  return __uint_as_float(((unsigned)h) << 16);
}

// ---------------------------------------------------------------------------
// micro-tile FMA helpers (fp32 kernels)
// ---------------------------------------------------------------------------
__device__ __forceinline__ void fma44(float (&acc)[4][4], const float4 a, const float4 w) {
  acc[0][0] = fmaf(a.x, w.x, acc[0][0]); acc[0][1] = fmaf(a.x, w.y, acc[0][1]);
  acc[0][2] = fmaf(a.x, w.z, acc[0][2]); acc[0][3] = fmaf(a.x, w.w, acc[0][3]);
  acc[1][0] = fmaf(a.y, w.x, acc[1][0]); acc[1][1] = fmaf(a.y, w.y, acc[1][1]);
  acc[1][2] = fmaf(a.y, w.z, acc[1][2]); acc[1][3] = fmaf(a.y, w.w, acc[1][3]);
  acc[2][0] = fmaf(a.z, w.x, acc[2][0]); acc[2][1] = fmaf(a.z, w.y, acc[2][1]);
  acc[2][2] = fmaf(a.z, w.z, acc[2][2]); acc[2][3] = fmaf(a.z, w.w, acc[2][3]);
  acc[3][0] = fmaf(a.w, w.x, acc[3][0]); acc[3][1] = fmaf(a.w, w.y, acc[3][1]);
  acc[3][2] = fmaf(a.w, w.z, acc[3][2]); acc[3][3] = fmaf(a.w, w.w, acc[3][3]);
}

__device__ __forceinline__ void fmas4(float (&acc)[4], float s, const float4 w) {
  acc[0] = fmaf(s, w.x, acc[0]); acc[1] = fmaf(s, w.y, acc[1]);
  acc[2] = fmaf(s, w.z, acc[2]); acc[3] = fmaf(s, w.w, acc[3]);
}

// ---------------------------------------------------------------------------
// prep: W[Kreal][N] fp32 -> transposed bf16 split hi/lo[N][Kpad] (zero-pad k).
// ---------------------------------------------------------------------------
__global__ __launch_bounds__(256) void prep_kernel(
    const float* __restrict__ W, ushort* __restrict__ hi, ushort* __restrict__ lo,
    int Kreal, int Kpad, int N)
{
  int idx = blockIdx.x * 256 + threadIdx.x;
  int tot = N * (Kpad >> 3);
  if (idx >= tot) return;
  int n = idx / (Kpad >> 3);
  int k8 = (idx - n * (Kpad >> 3)) << 3;
  #pragma unroll
  for (int j = 0; j < 8; ++j) {
    int k = k8 + j;
    float x = (k < Kreal) ? W[(long)k * N + n] : 0.f;
    ushort h = f2bf(x);
    hi[(long)n * Kpad + k] = h;
    lo[(long)n * Kpad + k] = f2bf(x - bf2f(h));
  }
}

// ---------------------------------------------------------------------------
// MFMA GEMM with full N=128 tile, Kpad=128 (2 chunks of 64), 256 threads
// (4 waves x 16 rows). Split-bf16 (3 mfma). Optional fused mean-pool epilogue
// (POOL: 60-row molecule-aligned blocks -> xcat with solv scaling).
// A selected by blkSplit (h1/h2 concat for y1).
// ---------------------------------------------------------------------------
template<int POOL, int RELU, int BIAS>
__global__ __launch_bounds__(256) void mfma_n128_kernel(
    const float* __restrict__ A, const float* __restrict__ A2, int blkSplit,
    const ushort* __restrict__ Wh, const ushort* __restrict__ Wl,
    const float* __restrict__ bias, float* __restrict__ Cout,
    const float* __restrict__ s1x,
    int rowsPer, int rowsValid, int Kreal, int lda)
{
  __shared__ __align__(16) ushort Ah[64 * 72], Al[64 * 72];
  __shared__ __align__(16) ushort Bh[128 * 72], Bl[128 * 72];
  __shared__ float cs[256];
  const int tid = threadIdx.x;
  const int w = tid >> 6, l = tid & 63;
  const int bid = blockIdx.x;
  const int useA2 = (A2 != nullptr) && (bid >= blkSplit);
  const float* Ab = useA2 ? A2 : A;
  const long rowBase  = (long)(bid - (useA2 ? blkSplit : 0)) * rowsPer;  // A read
  const long crowBase = (long)bid * rowsPer;                             // C write
  if (POOL) cs[tid] = 0.f;

  f32x4 acc[8];
  #pragma unroll
  for (int fc = 0; fc < 8; ++fc) acc[fc] = (f32x4){0.f, 0.f, 0.f, 0.f};

  for (int k0 = 0; k0 < 128; k0 += 64) {
    // stage A (64 rows x 64 k) fp32 -> bf16 hi/lo, guarded
    #pragma unroll
    for (int q = 0; q < 4; ++q) {
      int lin = tid + 256 * q;
      int r = lin >> 4, k4 = (lin & 15) << 2;
      int kg = k0 + k4;
      float4 v = make_float4(0.f, 0.f, 0.f, 0.f);
      if (r < rowsValid) {
        const float* Ar = &Ab[(rowBase + r) * lda];
        if (kg + 4 <= Kreal) {
          float2 a = *(const float2*)&Ar[kg];
          float2 b = *(const float2*)&Ar[kg + 2];
          v = make_float4(a.x, a.y, b.x, b.y);
        } else if (kg + 2 <= Kreal) {
          float2 a = *(const float2*)&Ar[kg];
          v.x = a.x; v.y = a.y;
        }
      }
      ushort4 h4, l4;
      h4.x = f2bf(v.x); l4.x = f2bf(v.x - bf2f(h4.x));
      h4.y = f2bf(v.y); l4.y = f2bf(v.y - bf2f(h4.y));
      h4.z = f2bf(v.z); l4.z = f2bf(v.z - bf2f(h4.z));
      h4.w = f2bf(v.w); l4.w = f2bf(v.w - bf2f(h4.w));
      *(ushort4*)&Ah[r * 72 + k4] = h4;
      *(ushort4*)&Al[r * 72 + k4] = l4;
    }
    // stage B (128 cols x 64 k), pre-split bf16
    #pragma unroll
    for (int q = 0; q < 4; ++q) {
      int lin = tid + 256 * q;
      int n = lin >> 3, k8 = (lin & 7) << 3;
      *(uint4*)&Bh[n * 72 + k8] = *(const uint4*)&Wh[n * 128 + k0 + k8];
      *(uint4*)&Bl[n * 72 + k8] = *(const uint4*)&Wl[n * 128 + k0 + k8];
    }
    __syncthreads();
    #pragma unroll
    for (int ks = 0; ks < 2; ++ks) {
      const int ko = ks * 32 + (l >> 4) * 8;
      const int ar = w * 16 + (l & 15);
      short8 ah  = *(const short8*)&Ah[ar * 72 + ko];
      short8 al8 = *(const short8*)&Al[ar * 72 + ko];
      #pragma unroll
      for (int fc = 0; fc < 8; ++fc) {
        const int c = fc * 16 + (l & 15);
        short8 bh  = *(const short8*)&Bh[c * 72 + ko];
        short8 bl8 = *(const short8*)&Bl[c * 72 + ko];
        acc[fc] = __builtin_amdgcn_mfma_f32_16x16x32_bf16(al8, bh, acc[fc], 0, 0, 0);
        acc[fc] = __builtin_amdgcn_mfma_f32_16x16x32_bf16(ah, bl8, acc[fc], 0, 0, 0);
        acc[fc] = __builtin_amdgcn_mfma_f32_16x16x32_bf16(ah, bh, acc[fc], 0, 0, 0);
      }
    }
    __syncthreads();
  }
  // epilogue: row = w*16 + (l>>4)*4 + i, col = fc*16 + (l&15)
  #pragma unroll
  for (int fc = 0; fc < 8; ++fc) {
    int col = fc * 16 + (l & 15);
    float bv = BIAS ? bias[col] : 0.f;
    if (POOL) {
      float s0 = 0.f, s1 = 0.f;
      #pragma unroll
      for (int i = 0; i < 4; ++i) {
        int lr = w * 16 + ((l >> 4) << 2) + i;
        if (lr < rowsValid) {
          float v = acc[fc][i] + bv;
          if (RELU) v = fmaxf(v, 0.f);
          if (lr < NPM) s0 += v; else s1 += v;
        }
      }
      atomicAdd(&cs[col], s0);
      atomicAdd(&cs[128 + col], s1);
    } else {
      #pragma unroll
      for (int i = 0; i < 4; ++i) {
        int lr = w * 16 + ((l >> 4) << 2) + i;
        if (lr < rowsValid) {
          float v = acc[fc][i] + bv;
          if (RELU) v = fmaxf(v, 0.f);
          Cout[(crowBase + lr) * 128 + col] = v;
        }
      }
    }
  }
  if (POOL) {
    __syncthreads();
    int moll = tid >> 7, c = tid & 127;
    int gm = bid * 2 + moll;
    int gg = gm >> 11, mm = gm & 2047;
    float sf = gg ? (1.f - s1x[mm]) : s1x[mm];
    Cout[(long)gm * 128 + c] = cs[moll * 128 + c] * (1.f / 30.f) * sf;
  }
}

// ---------------------------------------------------------------------------
// MFMA GEMM, split-bf16: C = [relu](A @ W [+ bias]). Tile 64x32, 2 waves.
// (dense chain; unchanged from round 6 — validated)
// ---------------------------------------------------------------------------
template<int RELU, int BIAS, int CAT>
__global__ __launch_bounds__(128) void gemm_mfma_kernel(
    const float* __restrict__ A, const float* __restrict__ A2,
    const ushort* __restrict__ Wh, const ushort* __restrict__ Wl,
    const float* __restrict__ bias, float* __restrict__ C,
    int M, int N, int K, int lda)
{
  __shared__ __align__(16) ushort Ah[64 * 72], Al[64 * 72];
  __shared__ __align__(16) ushort Bh[32 * 72], Bl[32 * 72];
  const int tid = threadIdx.x;
  const int w = tid >> 6, l = tid & 63;
  const long rowBase = (long)blockIdx.x * 64;
  const int colBase = blockIdx.y * 32;

  f32x4 acc[2][2];
  #pragma unroll
  for (int fr = 0; fr < 2; ++fr)
    #pragma unroll
    for (int fc = 0; fc < 2; ++fc)
      acc[fr][fc] = (f32x4){0.f, 0.f, 0.f, 0.f};

  for (int k0 = 0; k0 < K; k0 += 64) {
    const float* Ab = (CAT && k0 >= 128) ? A2 : A;
    const int kc = CAT ? (k0 & 127) : k0;
    #pragma unroll
    for (int q = 0; q < 8; ++q) {
      int lin = tid + 128 * q;
      int r = lin >> 4, k4 = (lin & 15) << 2;
      float4 v = *(const float4*)&Ab[(rowBase + r) * lda + kc + k4];
      ushort4 h4, l4;
      h4.x = f2bf(v.x); l4.x = f2bf(v.x - bf2f(h4.x));
      h4.y = f2bf(v.y); l4.y = f2bf(v.y - bf2f(h4.y));
      h4.z = f2bf(v.z); l4.z = f2bf(v.z - bf2f(h4.z));
      h4.w = f2bf(v.w); l4.w = f2bf(v.w - bf2f(h4.w));
      *(ushort4*)&Ah[r * 72 + k4] = h4;
      *(ushort4*)&Al[r * 72 + k4] = l4;
    }
    #pragma unroll
    for (int q = 0; q < 2; ++q) {
      int lin = tid + 128 * q;
      int n = lin >> 3, k8 = (lin & 7) << 3;
      *(uint4*)&Bh[n * 72 + k8] = *(const uint4*)&Wh[(long)(colBase + n) * K + k0 + k8];
      *(uint4*)&Bl[n * 72 + k8] = *(const uint4*)&Wl[(long)(colBase + n) * K + k0 + k8];
    }
    __syncthreads();
    #pragma unroll
    for (int ks = 0; ks < 2; ++ks) {
      const int ko = ks * 32 + (l >> 4) * 8;
      short8 ah[2], al8[2], bh[2], bl8[2];
      #pragma unroll
      for (int fr = 0; fr < 2; ++fr) {
        int r = w * 32 + fr * 16 + (l & 15);
        ah[fr]  = *(const short8*)&Ah[r * 72 + ko];
        al8[fr] = *(const short8*)&Al[r * 72 + ko];
      }
      #pragma unroll
      for (int fc = 0; fc < 2; ++fc) {
        int c = fc * 16 + (l & 15);
        bh[fc]  = *(const short8*)&Bh[c * 72 + ko];
        bl8[fc] = *(const short8*)&Bl[c * 72 + ko];
      }
      #pragma unroll
      for (int fr = 0; fr < 2; ++fr)
        #pragma unroll
        for (int fc = 0; fc < 2; ++fc) {
          acc[fr][fc] = __builtin_amdgcn_mfma_f32_16x16x32_bf16(al8[fr], bh[fc], acc[fr][fc], 0, 0, 0);
          acc[fr][fc] = __builtin_amdgcn_mfma_f32_16x16x32_bf16(ah[fr], bl8[fc], acc[fr][fc], 0, 0, 0);
          acc[fr][fc] = __builtin_amdgcn_mfma_f32_16x16x32_bf16(ah[fr], bh[fc], acc[fr][fc], 0, 0, 0);
        }
    }
    __syncthreads();
  }
  #pragma unroll
  for (int fc = 0; fc < 2; ++fc) {
    int col = colBase + fc * 16 + (l & 15);
    float bv = BIAS ? bias[col] : 0.f;
    #pragma unroll
    for (int fr = 0; fr < 2; ++fr) {
      #pragma unroll
      for (int i = 0; i < 4; ++i) {
        long row = rowBase + w * 32 + fr * 16 + ((l >> 4) << 2) + i;
        float v = acc[fr][fc][i] + bv;
        if (RELU) v = fmaxf(v, 0.f);
        C[row * N + col] = v;
      }
    }
  }
}

// ---------------------------------------------------------------------------
// adj: normalized dense adjacency Â[d][s] = cnt(s->d)*rsI[d]*rsO[s].
// ---------------------------------------------------------------------------
__global__ __launch_bounds__(256) void adj_kernel(
    const int* __restrict__ src1, const int* __restrict__ dst1,
    const int* __restrict__ src2, const int* __restrict__ dst2,
    float* __restrict__ Abuf)
{
  __shared__ float cnt[4][30 * 33];
  __shared__ float rsOa[4][32], rsIa[4][32];
  const int tid = threadIdx.x, wid = tid >> 6, lane = tid & 63;
  const int gm = blockIdx.x * 4 + wid;
  const int g = gm >> 11, m = gm & 2047;
  const int* src = g ? src2 : src1;
  const int* dst = g ? dst2 : dst1;

  for (int i = lane; i < 30 * 33; i += 64) cnt[wid][i] = 0.f;
  __syncthreads();
  for (int e = lane; e < EPM; e += 64) {
    int s = src[m * EPM + e] - m * NPM;
    int d = dst[m * EPM + e] - m * NPM;
    atomicAdd(&cnt[wid][d * 33 + s], 1.0f);
  }
  __syncthreads();
  if (lane < NPM) {
    float sum = 0.f;
    for (int s = 0; s < NPM; ++s) sum += cnt[wid][lane * 33 + s];
    rsIa[wid][lane] = rsqrtf(fmaxf(sum, 1.f));
  } else if (lane >= 32 && lane < 32 + NPM) {
    int s = lane - 32; float sum = 0.f;
    for (int d = 0; d < NPM; ++d) sum += cnt[wid][d * 33 + s];
    rsOa[wid][s] = rsqrtf(fmaxf(sum, 1.f));
  }
  __syncthreads();
  const long base = (long)gm * 960;
  for (int i = lane; i < 960; i += 64) {
    int d = i >> 5, s = i & 31;
    float v = (d < NPM && s < NPM)
            ? cnt[wid][d * 33 + s] * rsIa[wid][d] * rsOa[wid][s] : 0.f;
    Abuf[base + i] = v;
  }
}

// ---------------------------------------------------------------------------
// aagg2: per 2-molecule block: t1 = relu(Â@y1 + bg1), agg2 = Â@t1 -> global.
// ---------------------------------------------------------------------------
__global__ __launch_bounds__(256, 2) void aagg2_kernel(
    const float* __restrict__ y1, const float* __restrict__ Abuf,
    const float* __restrict__ bg1, float* __restrict__ agg2)
{
  __shared__ float y1s[60 * 128];
  __shared__ float t1s[60 * 128];
  __shared__ float AbL[2 * 990];
  const int tid = threadIdx.x;
  const int p = blockIdx.x;
  const int g = p >> 10;
  const int mloc = (p & 1023) * 2;

  // stage y1 (60 rows x 128)
  for (int t = tid; t < 1920; t += 256) {
    int r = t >> 5, q = (t & 31) << 2;
    *(float4*)&y1s[r * 128 + q] = *(const float4*)&y1[((long)p * 60 + r) * 128 + q];
  }
  // stage Â for both molecules (stride 33)
  {
    const long ab = (long)(g * 2048 + mloc) * 960;
    for (int t = tid; t < 1920; t += 256) {
      int mm = (t >= 960) ? 1 : 0; int j = t - mm * 960;
      int d = j >> 5, s = j & 31;
      AbL[mm * 990 + d * 33 + s] = Abuf[ab + t];
    }
  }
  __syncthreads();

  const int rgrp = tid >> 4, cgrp = tid & 15;
  const int c0 = cgrp * 4;
  const int mol = rgrp >> 3;
  const int d0  = (rgrp & 7) * 4;
  const float* Am = &AbL[mol * 990];
  float4 bv0 = *(const float4*)&bg1[c0];
  float4 bv1 = *(const float4*)&bg1[c0 + 64];
  float accA[4][4], accB[4][4];

  // ---- t1 = relu(Â@y1 + b1) ----
  {
    for (int i = 0; i < 4; ++i)
      for (int j = 0; j < 4; ++j) { accA[i][j] = 0.f; accB[i][j] = 0.f; }
    #pragma unroll 5
    for (int s = 0; s < 30; ++s) {
      float4 ya = *(const float4*)&y1s[(mol * 30 + s) * 128 + c0];
      float4 yb = *(const float4*)&y1s[(mol * 30 + s) * 128 + c0 + 64];
      for (int i = 0; i < 4; ++i) {
        float ab = Am[(d0 + i) * 33 + s];
        fmas4(accA[i], ab, ya);
        fmas4(accB[i], ab, yb);
      }
    }
    for (int i = 0; i < 4; ++i) {
      int d = d0 + i;
      if (d < NPM) {
        int r = mol * 30 + d;
        float4 oa, ob;
        oa.x = fmaxf(accA[i][0] + bv0.x, 0.f); oa.y = fmaxf(accA[i][1] + bv0.y, 0.f);
        oa.z = fmaxf(accA[i][2] + bv0.z, 0.f); oa.w = fmaxf(accA[i][3] + bv0.w, 0.f);
        ob.x = fmaxf(accB[i][0] + bv1.x, 0.f); ob.y = fmaxf(accB[i][1] + bv1.y, 0.f);
        ob.z = fmaxf(accB[i][2] + bv1.z, 0.f); ob.w = fmaxf(accB[i][3] + bv1.w, 0.f);
        *(float4*)&t1s[r * 128 + c0]      = oa;
        *(float4*)&t1s[r * 128 + c0 + 64] = ob;
      }
    }
  }
  __syncthreads();

  // ---- agg2 = Â@t1 -> global ----
  {
    for (int i = 0; i < 4; ++i)
      for (int j = 0; j < 4; ++j) { accA[i][j] = 0.f; accB[i][j] = 0.f; }
    #pragma unroll 5
    for (int s = 0; s < 30; ++s) {
      float4 ta = *(const float4*)&t1s[(mol * 30 + s) * 128 + c0];
      float4 tb = *(const float4*)&t1s[(mol * 30 + s) * 128 + c0 + 64];
      for (int i = 0; i < 4; ++i) {
        float ab = Am[(d0 + i) * 33 + s];
        fmas4(accA[i], ab, ta);
        fmas4(accB[i], ab, tb);
      }
    }
    for (int i = 0; i < 4; ++i) {
      int d = d0 + i;
      if (d < NPM) {
        long row = ((long)p * 60 + mol * 30 + d) * 128;
        *(float4*)&agg2[row + c0]      = make_float4(accA[i][0], accA[i][1], accA[i][2], accA[i][3]);
        *(float4*)&agg2[row + c0 + 64] = make_float4(accB[i][0], accB[i][1], accB[i][2], accB[i][3]);
      }
    }
  }
}

// ---------------------------------------------------------------------------
// Fused z-GEMM + eh-fold. grid = 128 mixture-groups x 4 k-quarters.
// ---------------------------------------------------------------------------
__global__ __launch_bounds__(256) void zfold_kernel(
    const float* __restrict__ xp, const float* __restrict__ We2,
    const float* __restrict__ interhb, const float* __restrict__ ia1,
    const float* __restrict__ ia2, const float* __restrict__ We1,
    const float* __restrict__ be1,
    float* __restrict__ aggA, float* __restrict__ aggB)
{
  __shared__ float xsT[128 * 36];
  __shared__ float Ws[64 * 128];
  __shared__ float ehs[3][16][32];
  __shared__ float accAs[16 * 128], accBs[16 * 128];
  const int tid = threadIdx.x;
  const int mg = blockIdx.x >> 2, kq = blockIdx.x & 3;
  const int i0 = mg * 16;

  for (int t = tid; t < 1024; t += 256) {
    int row = t & 31, d4 = t >> 5;
    int gr = (row < 16) ? (i0 + row) : (B2 + i0 + row - 16);
    float4 v = *(const float4*)&xp[gr * 128 + d4 * 4];
    xsT[(d4 * 4 + 0) * 36 + row] = v.x; xsT[(d4 * 4 + 1) * 36 + row] = v.y;
    xsT[(d4 * 4 + 2) * 36 + row] = v.z; xsT[(d4 * 4 + 3) * 36 + row] = v.w;
  }
  for (int t = tid; t < 512; t += 256) {
    int mm = t >> 5, k = t & 31;
    float a = We1[k], b = be1[k];
    ehs[0][mm][k] = fmaxf(fmaf(interhb[i0 + mm], a, b), 0.f);
    ehs[1][mm][k] = fmaxf(fmaf(ia1[i0 + mm],     a, b), 0.f);
    ehs[2][mm][k] = fmaxf(fmaf(ia2[i0 + mm],     a, b), 0.f);
  }
  for (int t = tid; t < 16 * 128; t += 256) { accAs[t] = 0.f; accBs[t] = 0.f; }

  const int rgrp = tid >> 5, cgrp = tid & 31;
  const int r0 = rgrp * 4, c0 = cgrp * 4;
  const int side = rgrp >> 2;
  float accLo[4][4] = {{0.f}}, accHi[4][4] = {{0.f}};

  for (int kk = 0; kk < 8; ++kk) {
    const int k = kq * 8 + kk;
    float z[4][4] = {{0.f}};
    for (int ch = 0; ch < 2; ++ch) {
      __syncthreads();
      for (int t = tid; t < 2048; t += 256) {
        int d = t >> 5, c4 = (t & 31) << 2;
        *(float4*)&Ws[d * 128 + c4] =
            *(const float4*)&We2[k * 16384 + (ch * 64 + d) * 128 + c4];
      }
      __syncthreads();
      #pragma unroll 4
      for (int d = 0; d < 64; ++d) {
        float4 a = *(const float4*)&xsT[(ch * 64 + d) * 36 + r0];
        float4 w = *(const float4*)&Ws[d * 128 + c0];
        fma44(z, a, w);
      }
    }
    #pragma unroll
    for (int i = 0; i < 4; ++i) {
      int mm = (r0 + i) & 15;
      float uLo = side ? ehs[0][mm][k] : ehs[1][mm][k];
      float uHi = side ? ehs[2][mm][k] : ehs[0][mm][k];
      #pragma unroll
      for (int j = 0; j < 4; ++j) {
        accLo[i][j] = fmaf(uLo, z[i][j], accLo[i][j]);
        accHi[i][j] = fmaf(uHi, z[i][j], accHi[i][j]);
      }
    }
  }
  __syncthreads();
  for (int i = 0; i < 4; ++i) {
    int mm = (r0 + i) & 15;
    for (int j = 0; j < 4; ++j) {
      atomicAdd(&accAs[mm * 128 + c0 + j], accLo[i][j]);
      atomicAdd(&accBs[mm * 128 + c0 + j], accHi[i][j]);
    }
  }
  __syncthreads();
  for (int t = tid; t < 2048; t += 256) {
    int mm = t >> 7, c = t & 127;
    atomicAdd(&aggA[(i0 + mm) * 128 + c], accAs[mm * 128 + c]);
    atomicAdd(&aggB[(i0 + mm) * 128 + c], accBs[mm * 128 + c]);
  }
}

__global__ __launch_bounds__(256) void xin_kernel(
    const float* __restrict__ aggA, const float* __restrict__ aggB,
    const float* __restrict__ zb, const float* __restrict__ bnn,
    float* __restrict__ x_in)
{
  int idx = blockIdx.x * 256 + threadIdx.x;
  int i = idx >> 7, c = idx & 127;
  float zs = zb[i * 128 + c] + zb[(i + B2) * 128 + c] + bnn[c];
  x_in[i * 128 + c]        = fmaxf(aggA[idx] + zs, 0.f);
  x_in[(i + B2) * 128 + c] = fmaxf(aggB[idx] + zs, 0.f);
}

__global__ __launch_bounds__(256) void gru_kernel(
    const float* __restrict__ gi, const float* __restrict__ gh,
    const float* __restrict__ xp, float* __restrict__ xnew)
{
  int idx = blockIdx.x * 256 + threadIdx.x;
  int n = idx >> 7, j = idx & 127;
  float ir = gi[n * 384 + j], iz = gi[n * 384 + 128 + j], ih = gi[n * 384 + 256 + j];
  float hr = gh[n * 384 + j], hz = gh[n * 384 + 128 + j], hn = gh[n * 384 + 256 + j];
  float h  = xp[idx];
  float r  = 1.f / (1.f + expf(-(ir + hr)));
  float zg = 1.f / (1.f + expf(-(iz + hz)));
  float ng = tanhf(ih + r * hn);
  xnew[idx] = (1.f - zg) * ng + zg * h;
}

__global__ __launch_bounds__(256) void final_kernel(
    const float* __restrict__ o2, const float* __restrict__ Wcl3,
    const float* __restrict__ bcl3, float* __restrict__ out)
{
  int idx = blockIdx.x * 256 + threadIdx.x;
  int i = idx >> 1, c = idx & 1;
  float acc = bcl3[c];
  for (int k = 0; k < 128; ++k) acc = fmaf(o2[i * 128 + k], Wcl3[k * 2 + c], acc);
  out[idx] = acc;
}

// ---------------------------------------------------------------------------
extern "C" void kernel_launch(void* const* d_in, const int* in_sizes, int n_in,
                              void* d_out, int out_size, void* d_ws, size_t ws_size,
                              hipStream_t stream)
{
  const float* h1   = (const float*)d_in[0];
  const float* h2   = (const float*)d_in[1];
  const float* s1x  = (const float*)d_in[2];
  const float* ihb  = (const float*)d_in[3];
  const float* ia1  = (const float*)d_in[4];
  const float* ia2  = (const float*)d_in[5];
  const float* Wg1  = (const float*)d_in[6];
  const float* bg1  = (const float*)d_in[7];
  const float* Wg2  = (const float*)d_in[8];
  const float* bg2  = (const float*)d_in[9];
  const float* Wp   = (const float*)d_in[10];
  const float* bp   = (const float*)d_in[11];
  const float* We1  = (const float*)d_in[12];
  const float* be1  = (const float*)d_in[13];
  const float* We2  = (const float*)d_in[14];
  const float* be2  = (const float*)d_in[15];
  const float* bnn  = (const float*)d_in[16];
  const float* Wih  = (const float*)d_in[17];
  const float* bih  = (const float*)d_in[18];
  const float* Whh  = (const float*)d_in[19];
  const float* bhh  = (const float*)d_in[20];
  const float* Wcl1 = (const float*)d_in[21];
  const float* bcl1 = (const float*)d_in[22];
  const float* Wcl2 = (const float*)d_in[23];
  const float* bcl2 = (const float*)d_in[24];
  const float* Wcl3 = (const float*)d_in[25];
  const float* bcl3 = (const float*)d_in[26];
  const int*   src1 = (const int*)d_in[27];
  const int*   dst1 = (const int*)d_in[28];
  const int*   src2 = (const int*)d_in[29];
  const int*   dst2 = (const int*)d_in[30];
  float* out = (float*)d_out;
  float* ws  = (float*)d_ws;

  float* Abuf = ws;                          // 3,932,160
  float* y1   = ws + 3932160;                // 15,728,640
  float* agg2 = ws + 19660800;               // 15,728,640
  float* dwn  = ws + 35389440;

  float* xcat = dwn;
  float* xp   = dwn + 524288;
  float* zb   = dwn + 1048576;
  float* aggA = dwn + 1572864;
  float* aggB = dwn + 1835008;
  float* x_in = dwn + 2097152;
  float* gi   = dwn + 2621440;
  float* gh   = dwn + 4194304;
  float* xnew = dwn + 5767168;
  float* o1   = dwn + 6291456;
  float* o2   = dwn + 6553600;

  // bf16-split transposed weights (ushort arrays)
  ushort* wt     = (ushort*)(dwn + 6815744);
  ushort* WpTh   = wt;               ushort* WpTl   = wt + 16384;
  ushort* be2Th  = wt + 32768;       ushort* be2Tl  = wt + 49152;
  ushort* WihTh  = wt + 65536;       ushort* WihTl  = wt + 114688;
  ushort* WhhTh  = wt + 163840;      ushort* WhhTl  = wt + 212992;
  ushort* Wcl1Th = wt + 262144;      ushort* Wcl1Tl = wt + 294912;
  ushort* Wcl2Th = wt + 327680;      ushort* Wcl2Tl = wt + 344064;
  ushort* Wg1Th  = wt + 360448;      ushort* Wg1Tl  = wt + 376832;
  ushort* Wg2Th  = wt + 393216;      ushort* Wg2Tl  = wt + 409600;

  // ---- weight prep (bf16 split + transpose, K-pad) ----
  prep_kernel<<<8, 256, 0, stream>>>(Wp,   WpTh,   WpTl,   128, 128, 128);
  prep_kernel<<<8, 256, 0, stream>>>(be2,  be2Th,  be2Tl,  128, 128, 128);
  prep_kernel<<<24, 256, 0, stream>>>(Wih,  WihTh,  WihTl,  128, 128, 384);
  prep_kernel<<<24, 256, 0, stream>>>(Whh,  WhhTh,  WhhTl,  128, 128, 384);
  prep_kernel<<<16, 256, 0, stream>>>(Wcl1, Wcl1Th, Wcl1Tl, 256, 256, 128);
  prep_kernel<<<8, 256, 0, stream>>>(Wcl2, Wcl2Th, Wcl2Tl, 128, 128, 128);
  prep_kernel<<<8, 256, 0, stream>>>(Wg1,  Wg1Th,  Wg1Tl,  74,  128, 128);
  prep_kernel<<<8, 256, 0, stream>>>(Wg2,  Wg2Th,  Wg2Tl,  128, 128, 128);

  // ---- GraphConv pipeline (dense per-molecule adjacency, MFMA GEMMs) ----
  adj_kernel<<<1024, 256, 0, stream>>>(src1, dst1, src2, dst2, Abuf);
  // y1 = X @ Wg1 (nodes 0..61439 from h1, rest from h2)
  mfma_n128_kernel<0, 0, 0><<<1920, 256, 0, stream>>>(
      h1, h2, 960, Wg1Th, Wg1Tl, nullptr, y1, nullptr, 64, 64, 74, 74);
  // t1 = relu(Â@y1+b1); agg2 = Â@t1
  aagg2_kernel<<<2048, 256, 0, stream>>>(y1, Abuf, bg1, agg2);
  // t2 = relu(agg2 @ Wg2 + b2) + mean-pool + solv scale -> xcat
  mfma_n128_kernel<1, 1, 1><<<2048, 256, 0, stream>>>(
      agg2, nullptr, 1 << 30, Wg2Th, Wg2Tl, bg2, xcat, s1x, 60, 60, 128, 128);

  // ---- solvent-system MPNN + GRU + classifier (MFMA GEMMs) ----
  gemm_mfma_kernel<1, 1, 0><<<dim3(64, 4), 128, 0, stream>>>(
      xcat, nullptr, WpTh, WpTl, bp, xp, 4096, 128, 128, 128);
  gemm_mfma_kernel<0, 0, 0><<<dim3(64, 4), 128, 0, stream>>>(
      xp, nullptr, be2Th, be2Tl, nullptr, zb, 4096, 128, 128, 128);
  hipMemsetAsync(aggA, 0, 2 * 262144 * sizeof(float), stream);
  zfold_kernel<<<512, 256, 0, stream>>>(xp, We2, ihb, ia1, ia2, We1, be1, aggA, aggB);
  xin_kernel<<<1024, 256, 0, stream>>>(aggA, aggB, zb, bnn, x_in);
  gemm_mfma_kernel<0, 1, 0><<<dim3(64, 12), 128, 0, stream>>>(
      x_in, nullptr, WihTh, WihTl, bih, gi, 4096, 384, 128, 128);
  gemm_mfma_kernel<0, 1, 0><<<dim3(64, 12), 128, 0, stream>>>(
      xp, nullptr, WhhTh, WhhTl, bhh, gh, 4096, 384, 128, 128);
  gru_kernel<<<2048, 256, 0, stream>>>(gi, gh, xp, xnew);
  gemm_mfma_kernel<1, 1, 1><<<dim3(32, 4), 128, 0, stream>>>(
      xnew, xnew + (long)B2 * 128, Wcl1Th, Wcl1Tl, bcl1, o1, 2048, 128, 256, 128);
  gemm_mfma_kernel<1, 1, 0><<<dim3(32, 4), 128, 0, stream>>>(
      o1, nullptr, Wcl2Th, Wcl2Tl, bcl2, o2, 2048, 128, 128, 128);
  final_kernel<<<16, 256, 0, stream>>>(o2, Wcl3, bcl3, out);
}

// Round 8
// 326.067 us; speedup vs baseline: 2.8163x; 1.0973x over previous
//
#include <hip/hip_runtime.h>
#include <hip/hip_bf16.h>
#include <math.h>

#define B2    2048
#define NPM   30
#define EPM   120

typedef __attribute__((ext_vector_type(8))) short short8;
typedef __attribute__((ext_vector_type(4))) float f32x4;

__device__ __forceinline__ ushort f2bf(float x) {
  unsigned u = __float_as_uint(x);
  return (ushort)((u + 0x7FFFu + ((u >> 16) & 1u)) >> 16);
}
__device__ __forceinline__ float bf2f(ushort h) {
  return __uint_as_float(((unsigned)h) << 16);
}

// ---------------------------------------------------------------------------
// micro-tile FMA helpers (fp32 kernels)
// ---------------------------------------------------------------------------
__device__ __forceinline__ void fmas4(float (&acc)[4], float s, const float4 w) {
  acc[0] = fmaf(s, w.x, acc[0]); acc[1] = fmaf(s, w.y, acc[1]);
  acc[2] = fmaf(s, w.z, acc[2]); acc[3] = fmaf(s, w.w, acc[3]);
}

// ---------------------------------------------------------------------------
// prep: W[Kreal][N] fp32 -> transposed bf16 split hi/lo[N][Kpad] (zero-pad k).
// ---------------------------------------------------------------------------
__global__ __launch_bounds__(256) void prep_kernel(
    const float* __restrict__ W, ushort* __restrict__ hi, ushort* __restrict__ lo,
    int Kreal, int Kpad, int N)
{
  int idx = blockIdx.x * 256 + threadIdx.x;
  int tot = N * (Kpad >> 3);
  if (idx >= tot) return;
  int n = idx / (Kpad >> 3);
  int k8 = (idx - n * (Kpad >> 3)) << 3;
  #pragma unroll
  for (int j = 0; j < 8; ++j) {
    int k = k8 + j;
    float x = (k < Kreal) ? W[(long)k * N + n] : 0.f;
    ushort h = f2bf(x);
    hi[(long)n * Kpad + k] = h;
    lo[(long)n * Kpad + k] = f2bf(x - bf2f(h));
  }
}

// We2[32][128][128] -> per-k transposed bf16 split hi/lo[k][n][d]
__global__ __launch_bounds__(256) void prep_we2_kernel(
    const float* __restrict__ We2, ushort* __restrict__ hi, ushort* __restrict__ lo)
{
  int idx = blockIdx.x * 256 + threadIdx.x;   // 32*128*16 = 65536
  int k = idx >> 11;
  int rem = idx & 2047;
  int n = rem >> 4;
  int d8 = (rem & 15) << 3;
  #pragma unroll
  for (int j = 0; j < 8; ++j) {
    int d = d8 + j;
    float x = We2[k * 16384 + d * 128 + n];
    ushort h = f2bf(x);
    hi[k * 16384 + n * 128 + d] = h;
    lo[k * 16384 + n * 128 + d] = f2bf(x - bf2f(h));
  }
}

// ---------------------------------------------------------------------------
// MFMA GEMM with full N=128 tile, Kpad=128 (2 chunks of 64), 256 threads
// (4 waves x 16 rows). Split-bf16 (3 mfma). Optional fused mean-pool epilogue.
// ---------------------------------------------------------------------------
template<int POOL, int RELU, int BIAS>
__global__ __launch_bounds__(256) void mfma_n128_kernel(
    const float* __restrict__ A, const float* __restrict__ A2, int blkSplit,
    const ushort* __restrict__ Wh, const ushort* __restrict__ Wl,
    const float* __restrict__ bias, float* __restrict__ Cout,
    const float* __restrict__ s1x,
    int rowsPer, int rowsValid, int Kreal, int lda)
{
  __shared__ __align__(16) ushort Ah[64 * 72], Al[64 * 72];
  __shared__ __align__(16) ushort Bh[128 * 72], Bl[128 * 72];
  __shared__ float cs[256];
  const int tid = threadIdx.x;
  const int w = tid >> 6, l = tid & 63;
  const int bid = blockIdx.x;
  const int useA2 = (A2 != nullptr) && (bid >= blkSplit);
  const float* Ab = useA2 ? A2 : A;
  const long rowBase  = (long)(bid - (useA2 ? blkSplit : 0)) * rowsPer;
  const long crowBase = (long)bid * rowsPer;
  if (POOL) cs[tid] = 0.f;

  f32x4 acc[8];
  #pragma unroll
  for (int fc = 0; fc < 8; ++fc) acc[fc] = (f32x4){0.f, 0.f, 0.f, 0.f};

  for (int k0 = 0; k0 < 128; k0 += 64) {
    #pragma unroll
    for (int q = 0; q < 4; ++q) {
      int lin = tid + 256 * q;
      int r = lin >> 4, k4 = (lin & 15) << 2;
      int kg = k0 + k4;
      float4 v = make_float4(0.f, 0.f, 0.f, 0.f);
      if (r < rowsValid) {
        const float* Ar = &Ab[(rowBase + r) * lda];
        if (kg + 4 <= Kreal) {
          float2 a = *(const float2*)&Ar[kg];
          float2 b = *(const float2*)&Ar[kg + 2];
          v = make_float4(a.x, a.y, b.x, b.y);
        } else if (kg + 2 <= Kreal) {
          float2 a = *(const float2*)&Ar[kg];
          v.x = a.x; v.y = a.y;
        }
      }
      ushort4 h4, l4;
      h4.x = f2bf(v.x); l4.x = f2bf(v.x - bf2f(h4.x));
      h4.y = f2bf(v.y); l4.y = f2bf(v.y - bf2f(h4.y));
      h4.z = f2bf(v.z); l4.z = f2bf(v.z - bf2f(h4.z));
      h4.w = f2bf(v.w); l4.w = f2bf(v.w - bf2f(h4.w));
      *(ushort4*)&Ah[r * 72 + k4] = h4;
      *(ushort4*)&Al[r * 72 + k4] = l4;
    }
    #pragma unroll
    for (int q = 0; q < 4; ++q) {
      int lin = tid + 256 * q;
      int n = lin >> 3, k8 = (lin & 7) << 3;
      *(uint4*)&Bh[n * 72 + k8] = *(const uint4*)&Wh[n * 128 + k0 + k8];
      *(uint4*)&Bl[n * 72 + k8] = *(const uint4*)&Wl[n * 128 + k0 + k8];
    }
    __syncthreads();
    #pragma unroll
    for (int ks = 0; ks < 2; ++ks) {
      const int ko = ks * 32 + (l >> 4) * 8;
      const int ar = w * 16 + (l & 15);
      short8 ah  = *(const short8*)&Ah[ar * 72 + ko];
      short8 al8 = *(const short8*)&Al[ar * 72 + ko];
      #pragma unroll
      for (int fc = 0; fc < 8; ++fc) {
        const int c = fc * 16 + (l & 15);
        short8 bh  = *(const short8*)&Bh[c * 72 + ko];
        short8 bl8 = *(const short8*)&Bl[c * 72 + ko];
        acc[fc] = __builtin_amdgcn_mfma_f32_16x16x32_bf16(al8, bh, acc[fc], 0, 0, 0);
        acc[fc] = __builtin_amdgcn_mfma_f32_16x16x32_bf16(ah, bl8, acc[fc], 0, 0, 0);
        acc[fc] = __builtin_amdgcn_mfma_f32_16x16x32_bf16(ah, bh, acc[fc], 0, 0, 0);
      }
    }
    __syncthreads();
  }
  #pragma unroll
  for (int fc = 0; fc < 8; ++fc) {
    int col = fc * 16 + (l & 15);
    float bv = BIAS ? bias[col] : 0.f;
    if (POOL) {
      float s0 = 0.f, s1 = 0.f;
      #pragma unroll
      for (int i = 0; i < 4; ++i) {
        int lr = w * 16 + ((l >> 4) << 2) + i;
        if (lr < rowsValid) {
          float v = acc[fc][i] + bv;
          if (RELU) v = fmaxf(v, 0.f);
          if (lr < NPM) s0 += v; else s1 += v;
        }
      }
      atomicAdd(&cs[col], s0);
      atomicAdd(&cs[128 + col], s1);
    } else {
      #pragma unroll
      for (int i = 0; i < 4; ++i) {
        int lr = w * 16 + ((l >> 4) << 2) + i;
        if (lr < rowsValid) {
          float v = acc[fc][i] + bv;
          if (RELU) v = fmaxf(v, 0.f);
          Cout[(crowBase + lr) * 128 + col] = v;
        }
      }
    }
  }
  if (POOL) {
    __syncthreads();
    int moll = tid >> 7, c = tid & 127;
    int gm = bid * 2 + moll;
    int gg = gm >> 11, mm = gm & 2047;
    float sf = gg ? (1.f - s1x[mm]) : s1x[mm];
    Cout[(long)gm * 128 + c] = cs[moll * 128 + c] * (1.f / 30.f) * sf;
  }
}

// ---------------------------------------------------------------------------
// MFMA GEMM, split-bf16: C = [relu](A @ W [+ bias]). Tile 64x32, 2 waves.
// ---------------------------------------------------------------------------
template<int RELU, int BIAS, int CAT>
__global__ __launch_bounds__(128) void gemm_mfma_kernel(
    const float* __restrict__ A, const float* __restrict__ A2,
    const ushort* __restrict__ Wh, const ushort* __restrict__ Wl,
    const float* __restrict__ bias, float* __restrict__ C,
    int M, int N, int K, int lda)
{
  __shared__ __align__(16) ushort Ah[64 * 72], Al[64 * 72];
  __shared__ __align__(16) ushort Bh[32 * 72], Bl[32 * 72];
  const int tid = threadIdx.x;
  const int w = tid >> 6, l = tid & 63;
  const long rowBase = (long)blockIdx.x * 64;
  const int colBase = blockIdx.y * 32;

  f32x4 acc[2][2];
  #pragma unroll
  for (int fr = 0; fr < 2; ++fr)
    #pragma unroll
    for (int fc = 0; fc < 2; ++fc)
      acc[fr][fc] = (f32x4){0.f, 0.f, 0.f, 0.f};

  for (int k0 = 0; k0 < K; k0 += 64) {
    const float* Ab = (CAT && k0 >= 128) ? A2 : A;
    const int kc = CAT ? (k0 & 127) : k0;
    #pragma unroll
    for (int q = 0; q < 8; ++q) {
      int lin = tid + 128 * q;
      int r = lin >> 4, k4 = (lin & 15) << 2;
      float4 v = *(const float4*)&Ab[(rowBase + r) * lda + kc + k4];
      ushort4 h4, l4;
      h4.x = f2bf(v.x); l4.x = f2bf(v.x - bf2f(h4.x));
      h4.y = f2bf(v.y); l4.y = f2bf(v.y - bf2f(h4.y));
      h4.z = f2bf(v.z); l4.z = f2bf(v.z - bf2f(h4.z));
      h4.w = f2bf(v.w); l4.w = f2bf(v.w - bf2f(h4.w));
      *(ushort4*)&Ah[r * 72 + k4] = h4;
      *(ushort4*)&Al[r * 72 + k4] = l4;
    }
    #pragma unroll
    for (int q = 0; q < 2; ++q) {
      int lin = tid + 128 * q;
      int n = lin >> 3, k8 = (lin & 7) << 3;
      *(uint4*)&Bh[n * 72 + k8] = *(const uint4*)&Wh[(long)(colBase + n) * K + k0 + k8];
      *(uint4*)&Bl[n * 72 + k8] = *(const uint4*)&Wl[(long)(colBase + n) * K + k0 + k8];
    }
    __syncthreads();
    #pragma unroll
    for (int ks = 0; ks < 2; ++ks) {
      const int ko = ks * 32 + (l >> 4) * 8;
      short8 ah[2], al8[2], bh[2], bl8[2];
      #pragma unroll
      for (int fr = 0; fr < 2; ++fr) {
        int r = w * 32 + fr * 16 + (l & 15);
        ah[fr]  = *(const short8*)&Ah[r * 72 + ko];
        al8[fr] = *(const short8*)&Al[r * 72 + ko];
      }
      #pragma unroll
      for (int fc = 0; fc < 2; ++fc) {
        int c = fc * 16 + (l & 15);
        bh[fc]  = *(const short8*)&Bh[c * 72 + ko];
        bl8[fc] = *(const short8*)&Bl[c * 72 + ko];
      }
      #pragma unroll
      for (int fr = 0; fr < 2; ++fr)
        #pragma unroll
        for (int fc = 0; fc < 2; ++fc) {
          acc[fr][fc] = __builtin_amdgcn_mfma_f32_16x16x32_bf16(al8[fr], bh[fc], acc[fr][fc], 0, 0, 0);
          acc[fr][fc] = __builtin_amdgcn_mfma_f32_16x16x32_bf16(ah[fr], bl8[fc], acc[fr][fc], 0, 0, 0);
          acc[fr][fc] = __builtin_amdgcn_mfma_f32_16x16x32_bf16(ah[fr], bh[fc], acc[fr][fc], 0, 0, 0);
        }
    }
    __syncthreads();
  }
  #pragma unroll
  for (int fc = 0; fc < 2; ++fc) {
    int col = colBase + fc * 16 + (l & 15);
    float bv = BIAS ? bias[col] : 0.f;
    #pragma unroll
    for (int fr = 0; fr < 2; ++fr) {
      #pragma unroll
      for (int i = 0; i < 4; ++i) {
        long row = rowBase + w * 32 + fr * 16 + ((l >> 4) << 2) + i;
        float v = acc[fr][fc][i] + bv;
        if (RELU) v = fmaxf(v, 0.f);
        C[row * N + col] = v;
      }
    }
  }
}

// ---------------------------------------------------------------------------
// zfold via MFMA: per block, 32 mixtures (64 xp rows: lower+upper) x 8 k's.
// Z_k = XP_tile @ We2_k (split-bf16), folded with eh weights into registers,
// LDS-merged, then global atomics. grid = 64 row-groups x 4 k-octets = 256.
// ---------------------------------------------------------------------------
__global__ __launch_bounds__(256, 1) void zfold_mfma_kernel(
    const float* __restrict__ xp,
    const ushort* __restrict__ We2h, const ushort* __restrict__ We2l,
    const float* __restrict__ interhb, const float* __restrict__ ia1,
    const float* __restrict__ ia2, const float* __restrict__ We1,
    const float* __restrict__ be1,
    float* __restrict__ aggA, float* __restrict__ aggB)
{
  __shared__ __align__(16) ushort Ah[2][64 * 72], Al[2][64 * 72];
  __shared__ __align__(16) ushort Bh[128 * 72], Bl[128 * 72];
  __shared__ float accAs[32 * 128], accBs[32 * 128];
  __shared__ float ehs[3][32][8];
  const int tid = threadIdx.x;
  const int w = tid >> 6, l = tid & 63;
  const int rg = blockIdx.x >> 2, kq = blockIdx.x & 3;
  const int i0 = rg * 32;

  // stage A (64 rows x 128 k) -> bf16 split, both 64-k chunks resident
  for (int t = tid; t < 2048; t += 256) {
    int r = t >> 5, k4 = (t & 31) << 2;
    int gr = (r < 32) ? (i0 + r) : (B2 + i0 + r - 32);
    float4 v = *(const float4*)&xp[(long)gr * 128 + k4];
    int ch = k4 >> 6, ko = k4 & 63;
    ushort4 h4, l4;
    h4.x = f2bf(v.x); l4.x = f2bf(v.x - bf2f(h4.x));
    h4.y = f2bf(v.y); l4.y = f2bf(v.y - bf2f(h4.y));
    h4.z = f2bf(v.z); l4.z = f2bf(v.z - bf2f(h4.z));
    h4.w = f2bf(v.w); l4.w = f2bf(v.w - bf2f(h4.w));
    *(ushort4*)&Ah[ch][r * 72 + ko] = h4;
    *(ushort4*)&Al[ch][r * 72 + ko] = l4;
  }
  // eh weights for this block's 32 mixtures x 8 k's
  for (int t = tid; t < 768; t += 256) {
    int grp = t >> 8, rem = t & 255;
    int mm = rem >> 3, kk = rem & 7;
    int k = kq * 8 + kk;
    float u = (grp == 0) ? interhb[i0 + mm] : (grp == 1) ? ia1[i0 + mm] : ia2[i0 + mm];
    ehs[grp][mm][kk] = fmaxf(fmaf(u, We1[k], be1[k]), 0.f);
  }
  for (int t = tid; t < 4096; t += 256) { accAs[t] = 0.f; accBs[t] = 0.f; }

  float foldA[8][4] = {{0.f}}, foldB[8][4] = {{0.f}};
  const int ar = w * 16 + (l & 15);

  for (int kk = 0; kk < 8; ++kk) {
    const int k = kq * 8 + kk;
    f32x4 acc[8];
    #pragma unroll
    for (int fc = 0; fc < 8; ++fc) acc[fc] = (f32x4){0.f, 0.f, 0.f, 0.f};
    for (int ch = 0; ch < 2; ++ch) {
      __syncthreads();
      #pragma unroll
      for (int q = 0; q < 4; ++q) {
        int lin = tid + 256 * q;
        int n = lin >> 3, k8 = (lin & 7) << 3;
        *(uint4*)&Bh[n * 72 + k8] = *(const uint4*)&We2h[k * 16384 + n * 128 + ch * 64 + k8];
        *(uint4*)&Bl[n * 72 + k8] = *(const uint4*)&We2l[k * 16384 + n * 128 + ch * 64 + k8];
      }
      __syncthreads();
      #pragma unroll
      for (int ks = 0; ks < 2; ++ks) {
        const int ko = ks * 32 + (l >> 4) * 8;
        short8 ah  = *(const short8*)&Ah[ch][ar * 72 + ko];
        short8 al8 = *(const short8*)&Al[ch][ar * 72 + ko];
        #pragma unroll
        for (int fc = 0; fc < 8; ++fc) {
          const int c = fc * 16 + (l & 15);
          short8 bh  = *(const short8*)&Bh[c * 72 + ko];
          short8 bl8 = *(const short8*)&Bl[c * 72 + ko];
          acc[fc] = __builtin_amdgcn_mfma_f32_16x16x32_bf16(al8, bh, acc[fc], 0, 0, 0);
          acc[fc] = __builtin_amdgcn_mfma_f32_16x16x32_bf16(ah, bl8, acc[fc], 0, 0, 0);
          acc[fc] = __builtin_amdgcn_mfma_f32_16x16x32_bf16(ah, bh, acc[fc], 0, 0, 0);
        }
      }
    }
    // fold: rows <32 = lower (z[i]), rows >=32 = upper (z[i+B])
    #pragma unroll
    for (int i = 0; i < 4; ++i) {
      int lr = w * 16 + ((l >> 4) << 2) + i;
      int m = lr & 31, up = lr >> 5;
      float eA = up ? ehs[0][m][kk] : ehs[1][m][kk];
      float eB = up ? ehs[2][m][kk] : ehs[0][m][kk];
      #pragma unroll
      for (int fc = 0; fc < 8; ++fc) {
        foldA[fc][i] = fmaf(eA, acc[fc][i], foldA[fc][i]);
        foldB[fc][i] = fmaf(eB, acc[fc][i], foldB[fc][i]);
      }
    }
  }
  // LDS merge (each (m,col) has 2 contributors: lower & upper row threads)
  #pragma unroll
  for (int i = 0; i < 4; ++i) {
    int lr = w * 16 + ((l >> 4) << 2) + i;
    int m = lr & 31;
    #pragma unroll
    for (int fc = 0; fc < 8; ++fc) {
      int c = fc * 16 + (l & 15);
      atomicAdd(&accAs[m * 128 + c], foldA[fc][i]);
      atomicAdd(&accBs[m * 128 + c], foldB[fc][i]);
    }
  }
  __syncthreads();
  for (int t = tid; t < 4096; t += 256) {
    int mm = t >> 7, c = t & 127;
    atomicAdd(&aggA[(long)(i0 + mm) * 128 + c], accAs[t]);
    atomicAdd(&aggB[(long)(i0 + mm) * 128 + c], accBs[t]);
  }
}

// ---------------------------------------------------------------------------
// adj: normalized dense adjacency Â[d][s] = cnt(s->d)*rsI[d]*rsO[s].
// ---------------------------------------------------------------------------
__global__ __launch_bounds__(256) void adj_kernel(
    const int* __restrict__ src1, const int* __restrict__ dst1,
    const int* __restrict__ src2, const int* __restrict__ dst2,
    float* __restrict__ Abuf)
{
  __shared__ float cnt[4][30 * 33];
  __shared__ float rsOa[4][32], rsIa[4][32];
  const int tid = threadIdx.x, wid = tid >> 6, lane = tid & 63;
  const int gm = blockIdx.x * 4 + wid;
  const int g = gm >> 11, m = gm & 2047;
  const int* src = g ? src2 : src1;
  const int* dst = g ? dst2 : dst1;

  for (int i = lane; i < 30 * 33; i += 64) cnt[wid][i] = 0.f;
  __syncthreads();
  for (int e = lane; e < EPM; e += 64) {
    int s = src[m * EPM + e] - m * NPM;
    int d = dst[m * EPM + e] - m * NPM;
    atomicAdd(&cnt[wid][d * 33 + s], 1.0f);
  }
  __syncthreads();
  if (lane < NPM) {
    float sum = 0.f;
    for (int s = 0; s < NPM; ++s) sum += cnt[wid][lane * 33 + s];
    rsIa[wid][lane] = rsqrtf(fmaxf(sum, 1.f));
  } else if (lane >= 32 && lane < 32 + NPM) {
    int s = lane - 32; float sum = 0.f;
    for (int d = 0; d < NPM; ++d) sum += cnt[wid][d * 33 + s];
    rsOa[wid][s] = rsqrtf(fmaxf(sum, 1.f));
  }
  __syncthreads();
  const long base = (long)gm * 960;
  for (int i = lane; i < 960; i += 64) {
    int d = i >> 5, s = i & 31;
    float v = (d < NPM && s < NPM)
            ? cnt[wid][d * 33 + s] * rsIa[wid][d] * rsOa[wid][s] : 0.f;
    Abuf[base + i] = v;
  }
}

// ---------------------------------------------------------------------------
// aagg2: per 2-molecule block: t1 = relu(Â@y1 + bg1), agg2 = Â@t1 -> global.
// ---------------------------------------------------------------------------
__global__ __launch_bounds__(256, 2) void aagg2_kernel(
    const float* __restrict__ y1, const float* __restrict__ Abuf,
    const float* __restrict__ bg1, float* __restrict__ agg2)
{
  __shared__ float y1s[60 * 128];
  __shared__ float t1s[60 * 128];
  __shared__ float AbL[2 * 990];
  const int tid = threadIdx.x;
  const int p = blockIdx.x;
  const int g = p >> 10;
  const int mloc = (p & 1023) * 2;

  for (int t = tid; t < 1920; t += 256) {
    int r = t >> 5, q = (t & 31) << 2;
    *(float4*)&y1s[r * 128 + q] = *(const float4*)&y1[((long)p * 60 + r) * 128 + q];
  }
  {
    const long ab = (long)(g * 2048 + mloc) * 960;
    for (int t = tid; t < 1920; t += 256) {
      int mm = (t >= 960) ? 1 : 0; int j = t - mm * 960;
      int d = j >> 5, s = j & 31;
      AbL[mm * 990 + d * 33 + s] = Abuf[ab + t];
    }
  }
  __syncthreads();

  const int rgrp = tid >> 4, cgrp = tid & 15;
  const int c0 = cgrp * 4;
  const int mol = rgrp >> 3;
  const int d0  = (rgrp & 7) * 4;
  const float* Am = &AbL[mol * 990];
  float4 bv0 = *(const float4*)&bg1[c0];
  float4 bv1 = *(const float4*)&bg1[c0 + 64];
  float accA[4][4], accB[4][4];

  {
    for (int i = 0; i < 4; ++i)
      for (int j = 0; j < 4; ++j) { accA[i][j] = 0.f; accB[i][j] = 0.f; }
    #pragma unroll 5
    for (int s = 0; s < 30; ++s) {
      float4 ya = *(const float4*)&y1s[(mol * 30 + s) * 128 + c0];
      float4 yb = *(const float4*)&y1s[(mol * 30 + s) * 128 + c0 + 64];
      for (int i = 0; i < 4; ++i) {
        float ab = Am[(d0 + i) * 33 + s];
        fmas4(accA[i], ab, ya);
        fmas4(accB[i], ab, yb);
      }
    }
    for (int i = 0; i < 4; ++i) {
      int d = d0 + i;
      if (d < NPM) {
        int r = mol * 30 + d;
        float4 oa, ob;
        oa.x = fmaxf(accA[i][0] + bv0.x, 0.f); oa.y = fmaxf(accA[i][1] + bv0.y, 0.f);
        oa.z = fmaxf(accA[i][2] + bv0.z, 0.f); oa.w = fmaxf(accA[i][3] + bv0.w, 0.f);
        ob.x = fmaxf(accB[i][0] + bv1.x, 0.f); ob.y = fmaxf(accB[i][1] + bv1.y, 0.f);
        ob.z = fmaxf(accB[i][2] + bv1.z, 0.f); ob.w = fmaxf(accB[i][3] + bv1.w, 0.f);
        *(float4*)&t1s[r * 128 + c0]      = oa;
        *(float4*)&t1s[r * 128 + c0 + 64] = ob;
      }
    }
  }
  __syncthreads();

  {
    for (int i = 0; i < 4; ++i)
      for (int j = 0; j < 4; ++j) { accA[i][j] = 0.f; accB[i][j] = 0.f; }
    #pragma unroll 5
    for (int s = 0; s < 30; ++s) {
      float4 ta = *(const float4*)&t1s[(mol * 30 + s) * 128 + c0];
      float4 tb = *(const float4*)&t1s[(mol * 30 + s) * 128 + c0 + 64];
      for (int i = 0; i < 4; ++i) {
        float ab = Am[(d0 + i) * 33 + s];
        fmas4(accA[i], ab, ta);
        fmas4(accB[i], ab, tb);
      }
    }
    for (int i = 0; i < 4; ++i) {
      int d = d0 + i;
      if (d < NPM) {
        long row = ((long)p * 60 + mol * 30 + d) * 128;
        *(float4*)&agg2[row + c0]      = make_float4(accA[i][0], accA[i][1], accA[i][2], accA[i][3]);
        *(float4*)&agg2[row + c0 + 64] = make_float4(accB[i][0], accB[i][1], accB[i][2], accB[i][3]);
      }
    }
  }
}

__global__ __launch_bounds__(256) void xin_kernel(
    const float* __restrict__ aggA, const float* __restrict__ aggB,
    const float* __restrict__ zb, const float* __restrict__ bnn,
    float* __restrict__ x_in)
{
  int idx = blockIdx.x * 256 + threadIdx.x;
  int i = idx >> 7, c = idx & 127;
  float zs = zb[i * 128 + c] + zb[(i + B2) * 128 + c] + bnn[c];
  x_in[i * 128 + c]        = fmaxf(aggA[idx] + zs, 0.f);
  x_in[(i + B2) * 128 + c] = fmaxf(aggB[idx] + zs, 0.f);
}

__global__ __launch_bounds__(256) void gru_kernel(
    const float* __restrict__ gi, const float* __restrict__ gh,
    const float* __restrict__ xp, float* __restrict__ xnew)
{
  int idx = blockIdx.x * 256 + threadIdx.x;
  int n = idx >> 7, j = idx & 127;
  float ir = gi[n * 384 + j], iz = gi[n * 384 + 128 + j], ih = gi[n * 384 + 256 + j];
  float hr = gh[n * 384 + j], hz = gh[n * 384 + 128 + j], hn = gh[n * 384 + 256 + j];
  float h  = xp[idx];
  float r  = 1.f / (1.f + expf(-(ir + hr)));
  float zg = 1.f / (1.f + expf(-(iz + hz)));
  float ng = tanhf(ih + r * hn);
  xnew[idx] = (1.f - zg) * ng + zg * h;
}

__global__ __launch_bounds__(256) void final_kernel(
    const float* __restrict__ o2, const float* __restrict__ Wcl3,
    const float* __restrict__ bcl3, float* __restrict__ out)
{
  int idx = blockIdx.x * 256 + threadIdx.x;
  int i = idx >> 1, c = idx & 1;
  float acc = bcl3[c];
  for (int k = 0; k < 128; ++k) acc = fmaf(o2[i * 128 + k], Wcl3[k * 2 + c], acc);
  out[idx] = acc;
}

// ---------------------------------------------------------------------------
extern "C" void kernel_launch(void* const* d_in, const int* in_sizes, int n_in,
                              void* d_out, int out_size, void* d_ws, size_t ws_size,
                              hipStream_t stream)
{
  const float* h1   = (const float*)d_in[0];
  const float* h2   = (const float*)d_in[1];
  const float* s1x  = (const float*)d_in[2];
  const float* ihb  = (const float*)d_in[3];
  const float* ia1  = (const float*)d_in[4];
  const float* ia2  = (const float*)d_in[5];
  const float* Wg1  = (const float*)d_in[6];
  const float* bg1  = (const float*)d_in[7];
  const float* Wg2  = (const float*)d_in[8];
  const float* bg2  = (const float*)d_in[9];
  const float* Wp   = (const float*)d_in[10];
  const float* bp   = (const float*)d_in[11];
  const float* We1  = (const float*)d_in[12];
  const float* be1  = (const float*)d_in[13];
  const float* We2  = (const float*)d_in[14];
  const float* be2  = (const float*)d_in[15];
  const float* bnn  = (const float*)d_in[16];
  const float* Wih  = (const float*)d_in[17];
  const float* bih  = (const float*)d_in[18];
  const float* Whh  = (const float*)d_in[19];
  const float* bhh  = (const float*)d_in[20];
  const float* Wcl1 = (const float*)d_in[21];
  const float* bcl1 = (const float*)d_in[22];
  const float* Wcl2 = (const float*)d_in[23];
  const float* bcl2 = (const float*)d_in[24];
  const float* Wcl3 = (const float*)d_in[25];
  const float* bcl3 = (const float*)d_in[26];
  const int*   src1 = (const int*)d_in[27];
  const int*   dst1 = (const int*)d_in[28];
  const int*   src2 = (const int*)d_in[29];
  const int*   dst2 = (const int*)d_in[30];
  float* out = (float*)d_out;
  float* ws  = (float*)d_ws;

  float* Abuf = ws;                          // 3,932,160
  float* y1   = ws + 3932160;                // 15,728,640
  float* agg2 = ws + 19660800;               // 15,728,640
  float* dwn  = ws + 35389440;

  float* xcat = dwn;
  float* xp   = dwn + 524288;
  float* zb   = dwn + 1048576;
  float* aggA = dwn + 1572864;
  float* aggB = dwn + 1835008;
  float* x_in = dwn + 2097152;
  float* gi   = dwn + 2621440;
  float* gh   = dwn + 4194304;
  float* xnew = dwn + 5767168;
  float* o1   = dwn + 6291456;
  float* o2   = dwn + 6553600;

  // bf16-split transposed weights (ushort arrays)
  ushort* wt     = (ushort*)(dwn + 6815744);
  ushort* WpTh   = wt;               ushort* WpTl   = wt + 16384;
  ushort* be2Th  = wt + 32768;       ushort* be2Tl  = wt + 49152;
  ushort* WihTh  = wt + 65536;       ushort* WihTl  = wt + 114688;
  ushort* WhhTh  = wt + 163840;      ushort* WhhTl  = wt + 212992;
  ushort* Wcl1Th = wt + 262144;      ushort* Wcl1Tl = wt + 294912;
  ushort* Wcl2Th = wt + 327680;      ushort* Wcl2Tl = wt + 344064;
  ushort* Wg1Th  = wt + 360448;      ushort* Wg1Tl  = wt + 376832;
  ushort* Wg2Th  = wt + 393216;      ushort* Wg2Tl  = wt + 409600;
  ushort* We2h   = wt + 425984;      ushort* We2l   = wt + 950272;  // 524288 each

  // ---- weight prep (bf16 split + transpose, K-pad) ----
  prep_kernel<<<8, 256, 0, stream>>>(Wp,   WpTh,   WpTl,   128, 128, 128);
  prep_kernel<<<8, 256, 0, stream>>>(be2,  be2Th,  be2Tl,  128, 128, 128);
  prep_kernel<<<24, 256, 0, stream>>>(Wih,  WihTh,  WihTl,  128, 128, 384);
  prep_kernel<<<24, 256, 0, stream>>>(Whh,  WhhTh,  WhhTl,  128, 128, 384);
  prep_kernel<<<16, 256, 0, stream>>>(Wcl1, Wcl1Th, Wcl1Tl, 256, 256, 128);
  prep_kernel<<<8, 256, 0, stream>>>(Wcl2, Wcl2Th, Wcl2Tl, 128, 128, 128);
  prep_kernel<<<8, 256, 0, stream>>>(Wg1,  Wg1Th,  Wg1Tl,  74,  128, 128);
  prep_kernel<<<8, 256, 0, stream>>>(Wg2,  Wg2Th,  Wg2Tl,  128, 128, 128);
  prep_we2_kernel<<<256, 256, 0, stream>>>(We2, We2h, We2l);

  // ---- GraphConv pipeline (dense per-molecule adjacency, MFMA GEMMs) ----
  adj_kernel<<<1024, 256, 0, stream>>>(src1, dst1, src2, dst2, Abuf);
  mfma_n128_kernel<0, 0, 0><<<1920, 256, 0, stream>>>(
      h1, h2, 960, Wg1Th, Wg1Tl, nullptr, y1, nullptr, 64, 64, 74, 74);
  aagg2_kernel<<<2048, 256, 0, stream>>>(y1, Abuf, bg1, agg2);
  mfma_n128_kernel<1, 1, 1><<<2048, 256, 0, stream>>>(
      agg2, nullptr, 1 << 30, Wg2Th, Wg2Tl, bg2, xcat, s1x, 60, 60, 128, 128);

  // ---- solvent-system MPNN + GRU + classifier (MFMA GEMMs) ----
  gemm_mfma_kernel<1, 1, 0><<<dim3(64, 4), 128, 0, stream>>>(
      xcat, nullptr, WpTh, WpTl, bp, xp, 4096, 128, 128, 128);
  gemm_mfma_kernel<0, 0, 0><<<dim3(64, 4), 128, 0, stream>>>(
      xp, nullptr, be2Th, be2Tl, nullptr, zb, 4096, 128, 128, 128);
  hipMemsetAsync(aggA, 0, 2 * 262144 * sizeof(float), stream);
  zfold_mfma_kernel<<<256, 256, 0, stream>>>(xp, We2h, We2l, ihb, ia1, ia2,
                                             We1, be1, aggA, aggB);
  xin_kernel<<<1024, 256, 0, stream>>>(aggA, aggB, zb, bnn, x_in);
  gemm_mfma_kernel<0, 1, 0><<<dim3(64, 12), 128, 0, stream>>>(
      x_in, nullptr, WihTh, WihTl, bih, gi, 4096, 384, 128, 128);
  gemm_mfma_kernel<0, 1, 0><<<dim3(64, 12), 128, 0, stream>>>(
      xp, nullptr, WhhTh, WhhTl, bhh, gh, 4096, 384, 128, 128);
  gru_kernel<<<2048, 256, 0, stream>>>(gi, gh, xp, xnew);
  gemm_mfma_kernel<1, 1, 1><<<dim3(32, 4), 128, 0, stream>>>(
      xnew, xnew + (long)B2 * 128, Wcl1Th, Wcl1Tl, bcl1, o1, 2048, 128, 256, 128);
  gemm_mfma_kernel<1, 1, 0><<<dim3(32, 4), 128, 0, stream>>>(
      o1, nullptr, Wcl2Th, Wcl2Tl, bcl2, o2, 2048, 128, 128, 128);
  final_kernel<<<16, 256, 0, stream>>>(o2, Wcl3, bcl3, out);
}

// Round 9
// 246.081 us; speedup vs baseline: 3.7317x; 1.3250x over previous
//
#include <hip/hip_runtime.h>
#include <hip/hip_bf16.h>
#include <math.h>

#define B2    2048
#define NPM   30
#define EPM   120

typedef __attribute__((ext_vector_type(8))) short short8;
typedef __attribute__((ext_vector_type(4))) float f32x4;

__device__ __forceinline__ ushort f2bf(float x) {
  unsigned u = __float_as_uint(x);
  return (ushort)((u + 0x7FFFu + ((u >> 16) & 1u)) >> 16);
}
__device__ __forceinline__ float bf2f(ushort h) {
  return __uint_as_float(((unsigned)h) << 16);
}

// swizzled byte offsets: 128B rows (per-chunk tiles) and 256B rows (full-K A)
__device__ __forceinline__ int swz128(int r, int kb) { return r * 128 + (kb ^ ((r & 7) << 4)); }
__device__ __forceinline__ int swz256(int r, int kb) { return r * 256 + (kb ^ ((r & 15) << 4)); }

__device__ __forceinline__ void fmas4(float (&acc)[4], float s, const float4 w) {
  acc[0] = fmaf(s, w.x, acc[0]); acc[1] = fmaf(s, w.y, acc[1]);
  acc[2] = fmaf(s, w.z, acc[2]); acc[3] = fmaf(s, w.w, acc[3]);
}

// ---------------------------------------------------------------------------
// prep: W[Kreal][N] fp32 -> transposed bf16 split hi/lo[N][Kpad] (zero-pad k).
// ---------------------------------------------------------------------------
__global__ __launch_bounds__(256) void prep_kernel(
    const float* __restrict__ W, ushort* __restrict__ hi, ushort* __restrict__ lo,
    int Kreal, int Kpad, int N)
{
  int idx = blockIdx.x * 256 + threadIdx.x;
  int tot = N * (Kpad >> 3);
  if (idx >= tot) return;
  int n = idx / (Kpad >> 3);
  int k8 = (idx - n * (Kpad >> 3)) << 3;
  #pragma unroll
  for (int j = 0; j < 8; ++j) {
    int k = k8 + j;
    float x = (k < Kreal) ? W[(long)k * N + n] : 0.f;
    ushort h = f2bf(x);
    hi[(long)n * Kpad + k] = h;
    lo[(long)n * Kpad + k] = f2bf(x - bf2f(h));
  }
}

// We2[32][128][128] -> per-k transposed bf16 split hi/lo[k][n][d]
__global__ __launch_bounds__(256) void prep_we2_kernel(
    const float* __restrict__ We2, ushort* __restrict__ hi, ushort* __restrict__ lo)
{
  int idx = blockIdx.x * 256 + threadIdx.x;   // 32*128*16 = 65536
  int k = idx >> 11;
  int rem = idx & 2047;
  int n = rem >> 4;
  int d8 = (rem & 15) << 3;
  #pragma unroll
  for (int j = 0; j < 8; ++j) {
    int d = d8 + j;
    float x = We2[k * 16384 + d * 128 + n];
    ushort h = f2bf(x);
    hi[k * 16384 + n * 128 + d] = h;
    lo[k * 16384 + n * 128 + d] = f2bf(x - bf2f(h));
  }
}

// ---------------------------------------------------------------------------
// MFMA GEMM, N=128 tile, Kpad=128, 256 threads (4 waves x 16 rows).
// Split-bf16, swizzled stride-64 LDS. (y1 instance)
// ---------------------------------------------------------------------------
template<int RELU, int BIAS>
__global__ __launch_bounds__(256) void mfma_n128_kernel(
    const float* __restrict__ A, const float* __restrict__ A2, int blkSplit,
    const ushort* __restrict__ Wh, const ushort* __restrict__ Wl,
    const float* __restrict__ bias, float* __restrict__ Cout,
    int rowsPer, int rowsValid, int Kreal, int lda)
{
  __shared__ __align__(16) char AhB[8192], AlB[8192];
  __shared__ __align__(16) char BhB[16384], BlB[16384];
  const int tid = threadIdx.x;
  const int w = tid >> 6, l = tid & 63;
  const int bid = blockIdx.x;
  const int useA2 = (A2 != nullptr) && (bid >= blkSplit);
  const float* Ab = useA2 ? A2 : A;
  const long rowBase  = (long)(bid - (useA2 ? blkSplit : 0)) * rowsPer;
  const long crowBase = (long)bid * rowsPer;

  f32x4 acc[8];
  #pragma unroll
  for (int fc = 0; fc < 8; ++fc) acc[fc] = (f32x4){0.f, 0.f, 0.f, 0.f};

  for (int k0 = 0; k0 < 128; k0 += 64) {
    #pragma unroll
    for (int q = 0; q < 4; ++q) {
      int lin = tid + 256 * q;
      int r = lin >> 4, k4 = (lin & 15) << 2;
      int kg = k0 + k4;
      float4 v = make_float4(0.f, 0.f, 0.f, 0.f);
      if (r < rowsValid) {
        const float* Ar = &Ab[(rowBase + r) * lda];
        if (kg + 4 <= Kreal) {
          float2 a = *(const float2*)&Ar[kg];
          float2 b = *(const float2*)&Ar[kg + 2];
          v = make_float4(a.x, a.y, b.x, b.y);
        } else if (kg + 2 <= Kreal) {
          float2 a = *(const float2*)&Ar[kg];
          v.x = a.x; v.y = a.y;
        }
      }
      ushort4 h4, l4;
      h4.x = f2bf(v.x); l4.x = f2bf(v.x - bf2f(h4.x));
      h4.y = f2bf(v.y); l4.y = f2bf(v.y - bf2f(h4.y));
      h4.z = f2bf(v.z); l4.z = f2bf(v.z - bf2f(h4.z));
      h4.w = f2bf(v.w); l4.w = f2bf(v.w - bf2f(h4.w));
      *(ushort4*)(AhB + swz128(r, k4 * 2)) = h4;
      *(ushort4*)(AlB + swz128(r, k4 * 2)) = l4;
    }
    #pragma unroll
    for (int q = 0; q < 4; ++q) {
      int lin = tid + 256 * q;
      int n = lin >> 3, k8 = (lin & 7) << 3;
      *(uint4*)(BhB + swz128(n, k8 * 2)) = *(const uint4*)&Wh[n * 128 + k0 + k8];
      *(uint4*)(BlB + swz128(n, k8 * 2)) = *(const uint4*)&Wl[n * 128 + k0 + k8];
    }
    __syncthreads();
    #pragma unroll
    for (int ks = 0; ks < 2; ++ks) {
      const int ko = ks * 32 + (l >> 4) * 8;
      const int ar = w * 16 + (l & 15);
      short8 ah  = *(const short8*)(AhB + swz128(ar, ko * 2));
      short8 al8 = *(const short8*)(AlB + swz128(ar, ko * 2));
      #pragma unroll
      for (int fc = 0; fc < 8; ++fc) {
        const int c = fc * 16 + (l & 15);
        short8 bh  = *(const short8*)(BhB + swz128(c, ko * 2));
        short8 bl8 = *(const short8*)(BlB + swz128(c, ko * 2));
        acc[fc] = __builtin_amdgcn_mfma_f32_16x16x32_bf16(al8, bh, acc[fc], 0, 0, 0);
        acc[fc] = __builtin_amdgcn_mfma_f32_16x16x32_bf16(ah, bl8, acc[fc], 0, 0, 0);
        acc[fc] = __builtin_amdgcn_mfma_f32_16x16x32_bf16(ah, bh, acc[fc], 0, 0, 0);
      }
    }
    __syncthreads();
  }
  #pragma unroll
  for (int fc = 0; fc < 8; ++fc) {
    int col = fc * 16 + (l & 15);
    float bv = BIAS ? bias[col] : 0.f;
    #pragma unroll
    for (int i = 0; i < 4; ++i) {
      int lr = w * 16 + ((l >> 4) << 2) + i;
      if (lr < rowsValid) {
        float v = acc[fc][i] + bv;
        if (RELU) v = fmaxf(v, 0.f);
        Cout[(crowBase + lr) * 128 + col] = v;
      }
    }
  }
}

// ---------------------------------------------------------------------------
// MFMA GEMM, split-bf16, tile 64x32, 2 waves, swizzled LDS.
// ---------------------------------------------------------------------------
template<int RELU, int BIAS, int CAT>
__global__ __launch_bounds__(128) void gemm_mfma_kernel(
    const float* __restrict__ A, const float* __restrict__ A2,
    const ushort* __restrict__ Wh, const ushort* __restrict__ Wl,
    const float* __restrict__ bias, float* __restrict__ C,
    int M, int N, int K, int lda)
{
  __shared__ __align__(16) char AhB[8192], AlB[8192];
  __shared__ __align__(16) char BhB[4096], BlB[4096];
  const int tid = threadIdx.x;
  const int w = tid >> 6, l = tid & 63;
  const long rowBase = (long)blockIdx.x * 64;
  const int colBase = blockIdx.y * 32;

  f32x4 acc[2][2];
  #pragma unroll
  for (int fr = 0; fr < 2; ++fr)
    #pragma unroll
    for (int fc = 0; fc < 2; ++fc)
      acc[fr][fc] = (f32x4){0.f, 0.f, 0.f, 0.f};

  for (int k0 = 0; k0 < K; k0 += 64) {
    const float* Ab = (CAT && k0 >= 128) ? A2 : A;
    const int kc = CAT ? (k0 & 127) : k0;
    #pragma unroll
    for (int q = 0; q < 8; ++q) {
      int lin = tid + 128 * q;
      int r = lin >> 4, k4 = (lin & 15) << 2;
      float4 v = *(const float4*)&Ab[(rowBase + r) * lda + kc + k4];
      ushort4 h4, l4;
      h4.x = f2bf(v.x); l4.x = f2bf(v.x - bf2f(h4.x));
      h4.y = f2bf(v.y); l4.y = f2bf(v.y - bf2f(h4.y));
      h4.z = f2bf(v.z); l4.z = f2bf(v.z - bf2f(h4.z));
      h4.w = f2bf(v.w); l4.w = f2bf(v.w - bf2f(h4.w));
      *(ushort4*)(AhB + swz128(r, k4 * 2)) = h4;
      *(ushort4*)(AlB + swz128(r, k4 * 2)) = l4;
    }
    #pragma unroll
    for (int q = 0; q < 2; ++q) {
      int lin = tid + 128 * q;
      int n = lin >> 3, k8 = (lin & 7) << 3;
      *(uint4*)(BhB + swz128(n, k8 * 2)) = *(const uint4*)&Wh[(long)(colBase + n) * K + k0 + k8];
      *(uint4*)(BlB + swz128(n, k8 * 2)) = *(const uint4*)&Wl[(long)(colBase + n) * K + k0 + k8];
    }
    __syncthreads();
    #pragma unroll
    for (int ks = 0; ks < 2; ++ks) {
      const int ko = ks * 32 + (l >> 4) * 8;
      short8 ah[2], al8[2], bh[2], bl8[2];
      #pragma unroll
      for (int fr = 0; fr < 2; ++fr) {
        int r = w * 32 + fr * 16 + (l & 15);
        ah[fr]  = *(const short8*)(AhB + swz128(r, ko * 2));
        al8[fr] = *(const short8*)(AlB + swz128(r, ko * 2));
      }
      #pragma unroll
      for (int fc = 0; fc < 2; ++fc) {
        int c = fc * 16 + (l & 15);
        bh[fc]  = *(const short8*)(BhB + swz128(c, ko * 2));
        bl8[fc] = *(const short8*)(BlB + swz128(c, ko * 2));
      }
      #pragma unroll
      for (int fr = 0; fr < 2; ++fr)
        #pragma unroll
        for (int fc = 0; fc < 2; ++fc) {
          acc[fr][fc] = __builtin_amdgcn_mfma_f32_16x16x32_bf16(al8[fr], bh[fc], acc[fr][fc], 0, 0, 0);
          acc[fr][fc] = __builtin_amdgcn_mfma_f32_16x16x32_bf16(ah[fr], bl8[fc], acc[fr][fc], 0, 0, 0);
          acc[fr][fc] = __builtin_amdgcn_mfma_f32_16x16x32_bf16(ah[fr], bh[fc], acc[fr][fc], 0, 0, 0);
        }
    }
    __syncthreads();
  }
  #pragma unroll
  for (int fc = 0; fc < 2; ++fc) {
    int col = colBase + fc * 16 + (l & 15);
    float bv = BIAS ? bias[col] : 0.f;
    #pragma unroll
    for (int fr = 0; fr < 2; ++fr) {
      #pragma unroll
      for (int i = 0; i < 4; ++i) {
        long row = rowBase + w * 32 + fr * 16 + ((l >> 4) << 2) + i;
        float v = acc[fr][fc][i] + bv;
        if (RELU) v = fmaxf(v, 0.f);
        C[row * N + col] = v;
      }
    }
  }
}

// ---------------------------------------------------------------------------
// zfold via MFMA (validated round 8, unchanged).
// ---------------------------------------------------------------------------
__global__ __launch_bounds__(256, 1) void zfold_mfma_kernel(
    const float* __restrict__ xp,
    const ushort* __restrict__ We2h, const ushort* __restrict__ We2l,
    const float* __restrict__ interhb, const float* __restrict__ ia1,
    const float* __restrict__ ia2, const float* __restrict__ We1,
    const float* __restrict__ be1,
    float* __restrict__ aggA, float* __restrict__ aggB)
{
  __shared__ __align__(16) ushort Ah[2][64 * 72], Al[2][64 * 72];
  __shared__ __align__(16) ushort Bh[128 * 72], Bl[128 * 72];
  __shared__ float accAs[32 * 128], accBs[32 * 128];
  __shared__ float ehs[3][32][8];
  const int tid = threadIdx.x;
  const int w = tid >> 6, l = tid & 63;
  const int rg = blockIdx.x >> 2, kq = blockIdx.x & 3;
  const int i0 = rg * 32;

  for (int t = tid; t < 2048; t += 256) {
    int r = t >> 5, k4 = (t & 31) << 2;
    int gr = (r < 32) ? (i0 + r) : (B2 + i0 + r - 32);
    float4 v = *(const float4*)&xp[(long)gr * 128 + k4];
    int ch = k4 >> 6, ko = k4 & 63;
    ushort4 h4, l4;
    h4.x = f2bf(v.x); l4.x = f2bf(v.x - bf2f(h4.x));
    h4.y = f2bf(v.y); l4.y = f2bf(v.y - bf2f(h4.y));
    h4.z = f2bf(v.z); l4.z = f2bf(v.z - bf2f(h4.z));
    h4.w = f2bf(v.w); l4.w = f2bf(v.w - bf2f(h4.w));
    *(ushort4*)&Ah[ch][r * 72 + ko] = h4;
    *(ushort4*)&Al[ch][r * 72 + ko] = l4;
  }
  for (int t = tid; t < 768; t += 256) {
    int grp = t >> 8, rem = t & 255;
    int mm = rem >> 3, kk = rem & 7;
    int k = kq * 8 + kk;
    float u = (grp == 0) ? interhb[i0 + mm] : (grp == 1) ? ia1[i0 + mm] : ia2[i0 + mm];
    ehs[grp][mm][kk] = fmaxf(fmaf(u, We1[k], be1[k]), 0.f);
  }
  for (int t = tid; t < 4096; t += 256) { accAs[t] = 0.f; accBs[t] = 0.f; }

  float foldA[8][4] = {{0.f}}, foldB[8][4] = {{0.f}};
  const int ar = w * 16 + (l & 15);

  for (int kk = 0; kk < 8; ++kk) {
    const int k = kq * 8 + kk;
    f32x4 acc[8];
    #pragma unroll
    for (int fc = 0; fc < 8; ++fc) acc[fc] = (f32x4){0.f, 0.f, 0.f, 0.f};
    for (int ch = 0; ch < 2; ++ch) {
      __syncthreads();
      #pragma unroll
      for (int q = 0; q < 4; ++q) {
        int lin = tid + 256 * q;
        int n = lin >> 3, k8 = (lin & 7) << 3;
        *(uint4*)&Bh[n * 72 + k8] = *(const uint4*)&We2h[k * 16384 + n * 128 + ch * 64 + k8];
        *(uint4*)&Bl[n * 72 + k8] = *(const uint4*)&We2l[k * 16384 + n * 128 + ch * 64 + k8];
      }
      __syncthreads();
      #pragma unroll
      for (int ks = 0; ks < 2; ++ks) {
        const int ko = ks * 32 + (l >> 4) * 8;
        short8 ah  = *(const short8*)&Ah[ch][ar * 72 + ko];
        short8 al8 = *(const short8*)&Al[ch][ar * 72 + ko];
        #pragma unroll
        for (int fc = 0; fc < 8; ++fc) {
          const int c = fc * 16 + (l & 15);
          short8 bh  = *(const short8*)&Bh[c * 72 + ko];
          short8 bl8 = *(const short8*)&Bl[c * 72 + ko];
          acc[fc] = __builtin_amdgcn_mfma_f32_16x16x32_bf16(al8, bh, acc[fc], 0, 0, 0);
          acc[fc] = __builtin_amdgcn_mfma_f32_16x16x32_bf16(ah, bl8, acc[fc], 0, 0, 0);
          acc[fc] = __builtin_amdgcn_mfma_f32_16x16x32_bf16(ah, bh, acc[fc], 0, 0, 0);
        }
      }
    }
    #pragma unroll
    for (int i = 0; i < 4; ++i) {
      int lr = w * 16 + ((l >> 4) << 2) + i;
      int m = lr & 31, up = lr >> 5;
      float eA = up ? ehs[0][m][kk] : ehs[1][m][kk];
      float eB = up ? ehs[2][m][kk] : ehs[0][m][kk];
      #pragma unroll
      for (int fc = 0; fc < 8; ++fc) {
        foldA[fc][i] = fmaf(eA, acc[fc][i], foldA[fc][i]);
        foldB[fc][i] = fmaf(eB, acc[fc][i], foldB[fc][i]);
      }
    }
  }
  #pragma unroll
  for (int i = 0; i < 4; ++i) {
    int lr = w * 16 + ((l >> 4) << 2) + i;
    int m = lr & 31;
    #pragma unroll
    for (int fc = 0; fc < 8; ++fc) {
      int c = fc * 16 + (l & 15);
      atomicAdd(&accAs[m * 128 + c], foldA[fc][i]);
      atomicAdd(&accBs[m * 128 + c], foldB[fc][i]);
    }
  }
  __syncthreads();
  for (int t = tid; t < 4096; t += 256) {
    int mm = t >> 7, c = t & 127;
    atomicAdd(&aggA[(long)(i0 + mm) * 128 + c], accAs[t]);
    atomicAdd(&aggB[(long)(i0 + mm) * 128 + c], accBs[t]);
  }
}

// ---------------------------------------------------------------------------
// adj: normalized dense adjacency Â[d][s] = cnt(s->d)*rsI[d]*rsO[s].
// ---------------------------------------------------------------------------
__global__ __launch_bounds__(256) void adj_kernel(
    const int* __restrict__ src1, const int* __restrict__ dst1,
    const int* __restrict__ src2, const int* __restrict__ dst2,
    float* __restrict__ Abuf)
{
  __shared__ float cnt[4][30 * 33];
  __shared__ float rsOa[4][32], rsIa[4][32];
  const int tid = threadIdx.x, wid = tid >> 6, lane = tid & 63;
  const int gm = blockIdx.x * 4 + wid;
  const int g = gm >> 11, m = gm & 2047;
  const int* src = g ? src2 : src1;
  const int* dst = g ? dst2 : dst1;

  for (int i = lane; i < 30 * 33; i += 64) cnt[wid][i] = 0.f;
  __syncthreads();
  for (int e = lane; e < EPM; e += 64) {
    int s = src[m * EPM + e] - m * NPM;
    int d = dst[m * EPM + e] - m * NPM;
    atomicAdd(&cnt[wid][d * 33 + s], 1.0f);
  }
  __syncthreads();
  if (lane < NPM) {
    float sum = 0.f;
    for (int s = 0; s < NPM; ++s) sum += cnt[wid][lane * 33 + s];
    rsIa[wid][lane] = rsqrtf(fmaxf(sum, 1.f));
  } else if (lane >= 32 && lane < 32 + NPM) {
    int s = lane - 32; float sum = 0.f;
    for (int d = 0; d < NPM; ++d) sum += cnt[wid][d * 33 + s];
    rsOa[wid][s] = rsqrtf(fmaxf(sum, 1.f));
  }
  __syncthreads();
  const long base = (long)gm * 960;
  for (int i = lane; i < 960; i += 64) {
    int d = i >> 5, s = i & 31;
    float v = (d < NPM && s < NPM)
            ? cnt[wid][d * 33 + s] * rsIa[wid][d] * rsOa[wid][s] : 0.f;
    Abuf[base + i] = v;
  }
}

// ---------------------------------------------------------------------------
// FUSED aagg2 + g2pool: per 2-molecule block:
//   t1 = relu(Â@y1+b1) [VALU], agg2 = Â@t1 [VALU, in regs]
//   -> bf16-split into swizzled LDS A-tile -> t2 = relu(agg2@Wg2+b2) [MFMA]
//   -> mean-pool * solv -> xcat.  agg2 never touches HBM.
// LDS pool (70.4KB, phase-aliased): y1s/Ah+Al, t1s+AbL/Bh+Bl, cs.
// ---------------------------------------------------------------------------
__global__ __launch_bounds__(256, 2) void aagg2pool_kernel(
    const float* __restrict__ y1, const float* __restrict__ Abuf,
    const float* __restrict__ bg1,
    const ushort* __restrict__ Wh, const ushort* __restrict__ Wl,
    const float* __restrict__ bias2, const float* __restrict__ s1x,
    float* __restrict__ xcat)
{
  __shared__ __align__(16) char pool[70400];
  float* y1s = (float*)pool;               // [60*128]  bytes [0,30720)
  float* t1s = (float*)(pool + 30720);     // [60*128]  bytes [30720,61440)
  float* AbL = (float*)(pool + 61440);     // [2*990]   bytes [61440,69360)
  float* cs  = (float*)(pool + 69376);     // [256]     bytes [69376,70400)
  char* AhB = pool;                        // A hi, 64 rows x 256B swz [0,16384)
  char* AlB = pool + 16384;                // A lo [16384,32768)
  char* BhB = pool + 32768;                // B hi chunk, 128 rows x 128B swz
  char* BlB = pool + 49152;                // B lo chunk

  const int tid = threadIdx.x;
  const int p = blockIdx.x;
  const int g = p >> 10;
  const int mloc = (p & 1023) * 2;
  cs[tid] = 0.f;

  // ---- phase 1: stage y1 tile + Â ----
  for (int t = tid; t < 1920; t += 256) {
    int r = t >> 5, q = (t & 31) << 2;
    *(float4*)&y1s[r * 128 + q] = *(const float4*)&y1[((long)p * 60 + r) * 128 + q];
  }
  {
    const long ab = (long)(g * 2048 + mloc) * 960;
    for (int t = tid; t < 1920; t += 256) {
      int mm = (t >= 960) ? 1 : 0; int j = t - mm * 960;
      int d = j >> 5, s = j & 31;
      AbL[mm * 990 + d * 33 + s] = Abuf[ab + t];
    }
  }
  __syncthreads();

  const int rgrp = tid >> 4, cgrp = tid & 15;
  const int c0 = cgrp * 4;
  const int mol = rgrp >> 3;
  const int d0  = (rgrp & 7) * 4;
  const float* Am = &AbL[mol * 990];
  float accA[4][4], accB[4][4];

  // ---- phase 2: t1 = relu(Â@y1 + b1) ----
  {
    float4 bv0 = *(const float4*)&bg1[c0];
    float4 bv1 = *(const float4*)&bg1[c0 + 64];
    for (int i = 0; i < 4; ++i)
      for (int j = 0; j < 4; ++j) { accA[i][j] = 0.f; accB[i][j] = 0.f; }
    #pragma unroll 5
    for (int s = 0; s < 30; ++s) {
      float4 ya = *(const float4*)&y1s[(mol * 30 + s) * 128 + c0];
      float4 yb = *(const float4*)&y1s[(mol * 30 + s) * 128 + c0 + 64];
      for (int i = 0; i < 4; ++i) {
        float ab = Am[(d0 + i) * 33 + s];
        fmas4(accA[i], ab, ya);
        fmas4(accB[i], ab, yb);
      }
    }
    __syncthreads();   // y1s reads done everywhere? (reads above; t1s writes below disjoint region)
    for (int i = 0; i < 4; ++i) {
      int d = d0 + i;
      if (d < NPM) {
        int r = mol * 30 + d;
        float4 oa, ob;
        oa.x = fmaxf(accA[i][0] + bv0.x, 0.f); oa.y = fmaxf(accA[i][1] + bv0.y, 0.f);
        oa.z = fmaxf(accA[i][2] + bv0.z, 0.f); oa.w = fmaxf(accA[i][3] + bv0.w, 0.f);
        ob.x = fmaxf(accB[i][0] + bv1.x, 0.f); ob.y = fmaxf(accB[i][1] + bv1.y, 0.f);
        ob.z = fmaxf(accB[i][2] + bv1.z, 0.f); ob.w = fmaxf(accB[i][3] + bv1.w, 0.f);
        *(float4*)&t1s[r * 128 + c0]      = oa;
        *(float4*)&t1s[r * 128 + c0 + 64] = ob;
      }
    }
  }
  __syncthreads();

  // ---- phase 3: agg2 = Â@t1 (registers) ----
  {
    for (int i = 0; i < 4; ++i)
      for (int j = 0; j < 4; ++j) { accA[i][j] = 0.f; accB[i][j] = 0.f; }
    #pragma unroll 5
    for (int s = 0; s < 30; ++s) {
      float4 ta = *(const float4*)&t1s[(mol * 30 + s) * 128 + c0];
      float4 tb = *(const float4*)&t1s[(mol * 30 + s) * 128 + c0 + 64];
      for (int i = 0; i < 4; ++i) {
        float ab = Am[(d0 + i) * 33 + s];
        fmas4(accA[i], ab, ta);
        fmas4(accB[i], ab, tb);
      }
    }
  }
  __syncthreads();   // all t1s/AbL reads complete before A-tile overwrites

  // ---- phase 4: regs -> bf16 split swizzled A-tile (rows 60-63 zeroed) ----
  if (tid < 128) {     // zero rows 60..63 of Ah/Al (16 uint4 per row)
    int arr = tid >> 6, rr = 60 + ((tid >> 4) & 3), q16 = (tid & 15) << 4;
    uint4 z = {0u, 0u, 0u, 0u};
    *(uint4*)((arr ? AlB : AhB) + rr * 256 + q16) = z;
  }
  for (int i = 0; i < 4; ++i) {
    int d = d0 + i;
    if (d < NPM) {
      int r = mol * 30 + d;
      ushort4 h4, l4;
      h4.x = f2bf(accA[i][0]); l4.x = f2bf(accA[i][0] - bf2f(h4.x));
      h4.y = f2bf(accA[i][1]); l4.y = f2bf(accA[i][1] - bf2f(h4.y));
      h4.z = f2bf(accA[i][2]); l4.z = f2bf(accA[i][2] - bf2f(h4.z));
      h4.w = f2bf(accA[i][3]); l4.w = f2bf(accA[i][3] - bf2f(h4.w));
      *(ushort4*)(AhB + swz256(r, c0 * 2)) = h4;
      *(ushort4*)(AlB + swz256(r, c0 * 2)) = l4;
      h4.x = f2bf(accB[i][0]); l4.x = f2bf(accB[i][0] - bf2f(h4.x));
      h4.y = f2bf(accB[i][1]); l4.y = f2bf(accB[i][1] - bf2f(h4.y));
      h4.z = f2bf(accB[i][2]); l4.z = f2bf(accB[i][2] - bf2f(h4.z));
      h4.w = f2bf(accB[i][3]); l4.w = f2bf(accB[i][3] - bf2f(h4.w));
      *(ushort4*)(AhB + swz256(r, (c0 + 64) * 2)) = h4;
      *(ushort4*)(AlB + swz256(r, (c0 + 64) * 2)) = l4;
    }
  }

  // ---- phase 5: MFMA t2 = relu(A@Wg2 + b2) + pool ----
  const int w = tid >> 6, l = tid & 63;
  const int ar = w * 16 + (l & 15);
  f32x4 acc[8];
  #pragma unroll
  for (int fc = 0; fc < 8; ++fc) acc[fc] = (f32x4){0.f, 0.f, 0.f, 0.f};

  for (int k0 = 0; k0 < 128; k0 += 64) {
    __syncthreads();   // A writes visible (first iter) / previous B reads done
    #pragma unroll
    for (int q = 0; q < 4; ++q) {
      int lin = tid + 256 * q;
      int n = lin >> 3, k8 = (lin & 7) << 3;
      *(uint4*)(BhB + swz128(n, k8 * 2)) = *(const uint4*)&Wh[n * 128 + k0 + k8];
      *(uint4*)(BlB + swz128(n, k8 * 2)) = *(const uint4*)&Wl[n * 128 + k0 + k8];
    }
    __syncthreads();
    #pragma unroll
    for (int ks = 0; ks < 2; ++ks) {
      const int ko = ks * 32 + (l >> 4) * 8;
      short8 ah  = *(const short8*)(AhB + swz256(ar, (k0 + ko) * 2));
      short8 al8 = *(const short8*)(AlB + swz256(ar, (k0 + ko) * 2));
      #pragma unroll
      for (int fc = 0; fc < 8; ++fc) {
        const int c = fc * 16 + (l & 15);
        short8 bh  = *(const short8*)(BhB + swz128(c, ko * 2));
        short8 bl8 = *(const short8*)(BlB + swz128(c, ko * 2));
        acc[fc] = __builtin_amdgcn_mfma_f32_16x16x32_bf16(al8, bh, acc[fc], 0, 0, 0);
        acc[fc] = __builtin_amdgcn_mfma_f32_16x16x32_bf16(ah, bl8, acc[fc], 0, 0, 0);
        acc[fc] = __builtin_amdgcn_mfma_f32_16x16x32_bf16(ah, bh, acc[fc], 0, 0, 0);
      }
    }
  }
  __syncthreads();

  // pool epilogue: bias+relu, per-thread row sums, wave shfl-reduce, cs atomics
  #pragma unroll
  for (int fc = 0; fc < 8; ++fc) {
    int col = fc * 16 + (l & 15);
    float bv = bias2[col];
    float s0 = 0.f, s1 = 0.f;
    #pragma unroll
    for (int i = 0; i < 4; ++i) {
      int lr = w * 16 + ((l >> 4) << 2) + i;
      if (lr < 60) {
        float v = fmaxf(acc[fc][i] + bv, 0.f);
        if (lr < NPM) s0 += v; else s1 += v;
      }
    }
    s0 += __shfl_down(s0, 32); s0 += __shfl_down(s0, 16);
    s1 += __shfl_down(s1, 32); s1 += __shfl_down(s1, 16);
    if ((l >> 4) == 0) {
      atomicAdd(&cs[col], s0);
      atomicAdd(&cs[128 + col], s1);
    }
  }
  __syncthreads();
  {
    int moll = tid >> 7, c = tid & 127;
    int gm = p * 2 + moll;
    int gg = gm >> 11, mm = gm & 2047;
    float sf = gg ? (1.f - s1x[mm]) : s1x[mm];
    xcat[(long)gm * 128 + c] = cs[moll * 128 + c] * (1.f / 30.f) * sf;
  }
}

__global__ __launch_bounds__(256) void xin_kernel(
    const float* __restrict__ aggA, const float* __restrict__ aggB,
    const float* __restrict__ zb, const float* __restrict__ bnn,
    float* __restrict__ x_in)
{
  int idx = blockIdx.x * 256 + threadIdx.x;
  int i = idx >> 7, c = idx & 127;
  float zs = zb[i * 128 + c] + zb[(i + B2) * 128 + c] + bnn[c];
  x_in[i * 128 + c]        = fmaxf(aggA[idx] + zs, 0.f);
  x_in[(i + B2) * 128 + c] = fmaxf(aggB[idx] + zs, 0.f);
}

__global__ __launch_bounds__(256) void gru_kernel(
    const float* __restrict__ gi, const float* __restrict__ gh,
    const float* __restrict__ xp, float* __restrict__ xnew)
{
  int idx = blockIdx.x * 256 + threadIdx.x;
  int n = idx >> 7, j = idx & 127;
  float ir = gi[n * 384 + j], iz = gi[n * 384 + 128 + j], ih = gi[n * 384 + 256 + j];
  float hr = gh[n * 384 + j], hz = gh[n * 384 + 128 + j], hn = gh[n * 384 + 256 + j];
  float h  = xp[idx];
  float r  = 1.f / (1.f + expf(-(ir + hr)));
  float zg = 1.f / (1.f + expf(-(iz + hz)));
  float ng = tanhf(ih + r * hn);
  xnew[idx] = (1.f - zg) * ng + zg * h;
}

__global__ __launch_bounds__(256) void final_kernel(
    const float* __restrict__ o2, const float* __restrict__ Wcl3,
    const float* __restrict__ bcl3, float* __restrict__ out)
{
  int idx = blockIdx.x * 256 + threadIdx.x;
  int i = idx >> 1, c = idx & 1;
  float acc = bcl3[c];
  for (int k = 0; k < 128; ++k) acc = fmaf(o2[i * 128 + k], Wcl3[k * 2 + c], acc);
  out[idx] = acc;
}

// ---------------------------------------------------------------------------
extern "C" void kernel_launch(void* const* d_in, const int* in_sizes, int n_in,
                              void* d_out, int out_size, void* d_ws, size_t ws_size,
                              hipStream_t stream)
{
  const float* h1   = (const float*)d_in[0];
  const float* h2   = (const float*)d_in[1];
  const float* s1x  = (const float*)d_in[2];
  const float* ihb  = (const float*)d_in[3];
  const float* ia1  = (const float*)d_in[4];
  const float* ia2  = (const float*)d_in[5];
  const float* Wg1  = (const float*)d_in[6];
  const float* bg1  = (const float*)d_in[7];
  const float* Wg2  = (const float*)d_in[8];
  const float* bg2  = (const float*)d_in[9];
  const float* Wp   = (const float*)d_in[10];
  const float* bp   = (const float*)d_in[11];
  const float* We1  = (const float*)d_in[12];
  const float* be1  = (const float*)d_in[13];
  const float* We2  = (const float*)d_in[14];
  const float* be2  = (const float*)d_in[15];
  const float* bnn  = (const float*)d_in[16];
  const float* Wih  = (const float*)d_in[17];
  const float* bih  = (const float*)d_in[18];
  const float* Whh  = (const float*)d_in[19];
  const float* bhh  = (const float*)d_in[20];
  const float* Wcl1 = (const float*)d_in[21];
  const float* bcl1 = (const float*)d_in[22];
  const float* Wcl2 = (const float*)d_in[23];
  const float* bcl2 = (const float*)d_in[24];
  const float* Wcl3 = (const float*)d_in[25];
  const float* bcl3 = (const float*)d_in[26];
  const int*   src1 = (const int*)d_in[27];
  const int*   dst1 = (const int*)d_in[28];
  const int*   src2 = (const int*)d_in[29];
  const int*   dst2 = (const int*)d_in[30];
  float* out = (float*)d_out;
  float* ws  = (float*)d_ws;

  float* Abuf = ws;                          // 3,932,160
  float* y1   = ws + 3932160;                // 15,728,640
  float* dwn  = ws + 35389440;

  float* xcat = dwn;
  float* xp   = dwn + 524288;
  float* zb   = dwn + 1048576;
  float* aggA = dwn + 1572864;
  float* aggB = dwn + 1835008;
  float* x_in = dwn + 2097152;
  float* gi   = dwn + 2621440;
  float* gh   = dwn + 4194304;
  float* xnew = dwn + 5767168;
  float* o1   = dwn + 6291456;
  float* o2   = dwn + 6553600;

  ushort* wt     = (ushort*)(dwn + 6815744);
  ushort* WpTh   = wt;               ushort* WpTl   = wt + 16384;
  ushort* be2Th  = wt + 32768;       ushort* be2Tl  = wt + 49152;
  ushort* WihTh  = wt + 65536;       ushort* WihTl  = wt + 114688;
  ushort* WhhTh  = wt + 163840;      ushort* WhhTl  = wt + 212992;
  ushort* Wcl1Th = wt + 262144;      ushort* Wcl1Tl = wt + 294912;
  ushort* Wcl2Th = wt + 327680;      ushort* Wcl2Tl = wt + 344064;
  ushort* Wg1Th  = wt + 360448;      ushort* Wg1Tl  = wt + 376832;
  ushort* Wg2Th  = wt + 393216;      ushort* Wg2Tl  = wt + 409600;
  ushort* We2h   = wt + 425984;      ushort* We2l   = wt + 950272;

  // ---- weight prep ----
  prep_kernel<<<8, 256, 0, stream>>>(Wp,   WpTh,   WpTl,   128, 128, 128);
  prep_kernel<<<8, 256, 0, stream>>>(be2,  be2Th,  be2Tl,  128, 128, 128);
  prep_kernel<<<24, 256, 0, stream>>>(Wih,  WihTh,  WihTl,  128, 128, 384);
  prep_kernel<<<24, 256, 0, stream>>>(Whh,  WhhTh,  WhhTl,  128, 128, 384);
  prep_kernel<<<16, 256, 0, stream>>>(Wcl1, Wcl1Th, Wcl1Tl, 256, 256, 128);
  prep_kernel<<<8, 256, 0, stream>>>(Wcl2, Wcl2Th, Wcl2Tl, 128, 128, 128);
  prep_kernel<<<8, 256, 0, stream>>>(Wg1,  Wg1Th,  Wg1Tl,  74,  128, 128);
  prep_kernel<<<8, 256, 0, stream>>>(Wg2,  Wg2Th,  Wg2Tl,  128, 128, 128);
  prep_we2_kernel<<<256, 256, 0, stream>>>(We2, We2h, We2l);

  // ---- GraphConv pipeline ----
  adj_kernel<<<1024, 256, 0, stream>>>(src1, dst1, src2, dst2, Abuf);
  mfma_n128_kernel<0, 0><<<1920, 256, 0, stream>>>(
      h1, h2, 960, Wg1Th, Wg1Tl, nullptr, y1, 64, 64, 74, 74);
  aagg2pool_kernel<<<2048, 256, 0, stream>>>(y1, Abuf, bg1, Wg2Th, Wg2Tl,
                                             bg2, s1x, xcat);

  // ---- solvent-system MPNN + GRU + classifier ----
  gemm_mfma_kernel<1, 1, 0><<<dim3(64, 4), 128, 0, stream>>>(
      xcat, nullptr, WpTh, WpTl, bp, xp, 4096, 128, 128, 128);
  gemm_mfma_kernel<0, 0, 0><<<dim3(64, 4), 128, 0, stream>>>(
      xp, nullptr, be2Th, be2Tl, nullptr, zb, 4096, 128, 128, 128);
  hipMemsetAsync(aggA, 0, 2 * 262144 * sizeof(float), stream);
  zfold_mfma_kernel<<<256, 256, 0, stream>>>(xp, We2h, We2l, ihb, ia1, ia2,
                                             We1, be1, aggA, aggB);
  xin_kernel<<<1024, 256, 0, stream>>>(aggA, aggB, zb, bnn, x_in);
  gemm_mfma_kernel<0, 1, 0><<<dim3(64, 12), 128, 0, stream>>>(
      x_in, nullptr, WihTh, WihTl, bih, gi, 4096, 384, 128, 128);
  gemm_mfma_kernel<0, 1, 0><<<dim3(64, 12), 128, 0, stream>>>(
      xp, nullptr, WhhTh, WhhTl, bhh, gh, 4096, 384, 128, 128);
  gru_kernel<<<2048, 256, 0, stream>>>(gi, gh, xp, xnew);
  gemm_mfma_kernel<1, 1, 1><<<dim3(32, 4), 128, 0, stream>>>(
      xnew, xnew + (long)B2 * 128, Wcl1Th, Wcl1Tl, bcl1, o1, 2048, 128, 256, 128);
  gemm_mfma_kernel<1, 1, 0><<<dim3(32, 4), 128, 0, stream>>>(
      o1, nullptr, Wcl2Th, Wcl2Tl, bcl2, o2, 2048, 128, 128, 128);
  final_kernel<<<16, 256, 0, stream>>>(o2, Wcl3, bcl3, out);
}

// Round 10
// 245.117 us; speedup vs baseline: 3.7464x; 1.0039x over previous
//
#include <hip/hip_runtime.h>
#include <hip/hip_bf16.h>
#include <math.h>

#define B2    2048
#define NPM   30
#define EPM   120

typedef __attribute__((ext_vector_type(8))) short short8;
typedef __attribute__((ext_vector_type(4))) float f32x4;

__device__ __forceinline__ ushort f2bf(float x) {
  unsigned u = __float_as_uint(x);
  return (ushort)((u + 0x7FFFu + ((u >> 16) & 1u)) >> 16);
}
__device__ __forceinline__ float bf2f(ushort h) {
  return __uint_as_float(((unsigned)h) << 16);
}

// swizzled byte offsets: 128B rows (per-chunk tiles) and 256B rows (full-K A)
__device__ __forceinline__ int swz128(int r, int kb) { return r * 128 + (kb ^ ((r & 7) << 4)); }
__device__ __forceinline__ int swz256(int r, int kb) { return r * 256 + (kb ^ ((r & 15) << 4)); }

__device__ __forceinline__ void fmas4(float (&acc)[4], float s, const float4 w) {
  acc[0] = fmaf(s, w.x, acc[0]); acc[1] = fmaf(s, w.y, acc[1]);
  acc[2] = fmaf(s, w.z, acc[2]); acc[3] = fmaf(s, w.w, acc[3]);
}

// ---------------------------------------------------------------------------
// prep: W[Kreal][N] fp32 -> transposed bf16 split hi/lo[N][Kpad] (zero-pad k).
// ---------------------------------------------------------------------------
__global__ __launch_bounds__(256) void prep_kernel(
    const float* __restrict__ W, ushort* __restrict__ hi, ushort* __restrict__ lo,
    int Kreal, int Kpad, int N)
{
  int idx = blockIdx.x * 256 + threadIdx.x;
  int tot = N * (Kpad >> 3);
  if (idx >= tot) return;
  int n = idx / (Kpad >> 3);
  int k8 = (idx - n * (Kpad >> 3)) << 3;
  #pragma unroll
  for (int j = 0; j < 8; ++j) {
    int k = k8 + j;
    float x = (k < Kreal) ? W[(long)k * N + n] : 0.f;
    ushort h = f2bf(x);
    hi[(long)n * Kpad + k] = h;
    lo[(long)n * Kpad + k] = f2bf(x - bf2f(h));
  }
}

// We2[32][128][128] -> per-k transposed bf16 split hi/lo[k][n][d]
__global__ __launch_bounds__(256) void prep_we2_kernel(
    const float* __restrict__ We2, ushort* __restrict__ hi, ushort* __restrict__ lo)
{
  int idx = blockIdx.x * 256 + threadIdx.x;   // 32*128*16 = 65536
  int k = idx >> 11;
  int rem = idx & 2047;
  int n = rem >> 4;
  int d8 = (rem & 15) << 3;
  #pragma unroll
  for (int j = 0; j < 8; ++j) {
    int d = d8 + j;
    float x = We2[k * 16384 + d * 128 + n];
    ushort h = f2bf(x);
    hi[k * 16384 + n * 128 + d] = h;
    lo[k * 16384 + n * 128 + d] = f2bf(x - bf2f(h));
  }
}

// ---------------------------------------------------------------------------
// MFMA GEMM, split-bf16, tile 64x32, 2 waves, swizzled LDS. (dense chain)
// ---------------------------------------------------------------------------
template<int RELU, int BIAS, int CAT>
__global__ __launch_bounds__(128) void gemm_mfma_kernel(
    const float* __restrict__ A, const float* __restrict__ A2,
    const ushort* __restrict__ Wh, const ushort* __restrict__ Wl,
    const float* __restrict__ bias, float* __restrict__ C,
    int M, int N, int K, int lda)
{
  __shared__ __align__(16) char AhB[8192], AlB[8192];
  __shared__ __align__(16) char BhB[4096], BlB[4096];
  const int tid = threadIdx.x;
  const int w = tid >> 6, l = tid & 63;
  const long rowBase = (long)blockIdx.x * 64;
  const int colBase = blockIdx.y * 32;

  f32x4 acc[2][2];
  #pragma unroll
  for (int fr = 0; fr < 2; ++fr)
    #pragma unroll
    for (int fc = 0; fc < 2; ++fc)
      acc[fr][fc] = (f32x4){0.f, 0.f, 0.f, 0.f};

  for (int k0 = 0; k0 < K; k0 += 64) {
    const float* Ab = (CAT && k0 >= 128) ? A2 : A;
    const int kc = CAT ? (k0 & 127) : k0;
    #pragma unroll
    for (int q = 0; q < 8; ++q) {
      int lin = tid + 128 * q;
      int r = lin >> 4, k4 = (lin & 15) << 2;
      float4 v = *(const float4*)&Ab[(rowBase + r) * lda + kc + k4];
      ushort4 h4, l4;
      h4.x = f2bf(v.x); l4.x = f2bf(v.x - bf2f(h4.x));
      h4.y = f2bf(v.y); l4.y = f2bf(v.y - bf2f(h4.y));
      h4.z = f2bf(v.z); l4.z = f2bf(v.z - bf2f(h4.z));
      h4.w = f2bf(v.w); l4.w = f2bf(v.w - bf2f(h4.w));
      *(ushort4*)(AhB + swz128(r, k4 * 2)) = h4;
      *(ushort4*)(AlB + swz128(r, k4 * 2)) = l4;
    }
    #pragma unroll
    for (int q = 0; q < 2; ++q) {
      int lin = tid + 128 * q;
      int n = lin >> 3, k8 = (lin & 7) << 3;
      *(uint4*)(BhB + swz128(n, k8 * 2)) = *(const uint4*)&Wh[(long)(colBase + n) * K + k0 + k8];
      *(uint4*)(BlB + swz128(n, k8 * 2)) = *(const uint4*)&Wl[(long)(colBase + n) * K + k0 + k8];
    }
    __syncthreads();
    #pragma unroll
    for (int ks = 0; ks < 2; ++ks) {
      const int ko = ks * 32 + (l >> 4) * 8;
      short8 ah[2], al8[2], bh[2], bl8[2];
      #pragma unroll
      for (int fr = 0; fr < 2; ++fr) {
        int r = w * 32 + fr * 16 + (l & 15);
        ah[fr]  = *(const short8*)(AhB + swz128(r, ko * 2));
        al8[fr] = *(const short8*)(AlB + swz128(r, ko * 2));
      }
      #pragma unroll
      for (int fc = 0; fc < 2; ++fc) {
        int c = fc * 16 + (l & 15);
        bh[fc]  = *(const short8*)(BhB + swz128(c, ko * 2));
        bl8[fc] = *(const short8*)(BlB + swz128(c, ko * 2));
      }
      #pragma unroll
      for (int fr = 0; fr < 2; ++fr)
        #pragma unroll
        for (int fc = 0; fc < 2; ++fc) {
          acc[fr][fc] = __builtin_amdgcn_mfma_f32_16x16x32_bf16(al8[fr], bh[fc], acc[fr][fc], 0, 0, 0);
          acc[fr][fc] = __builtin_amdgcn_mfma_f32_16x16x32_bf16(ah[fr], bl8[fc], acc[fr][fc], 0, 0, 0);
          acc[fr][fc] = __builtin_amdgcn_mfma_f32_16x16x32_bf16(ah[fr], bh[fc], acc[fr][fc], 0, 0, 0);
        }
    }
    __syncthreads();
  }
  #pragma unroll
  for (int fc = 0; fc < 2; ++fc) {
    int col = colBase + fc * 16 + (l & 15);
    float bv = BIAS ? bias[col] : 0.f;
    #pragma unroll
    for (int fr = 0; fr < 2; ++fr) {
      #pragma unroll
      for (int i = 0; i < 4; ++i) {
        long row = rowBase + w * 32 + fr * 16 + ((l >> 4) << 2) + i;
        float v = acc[fr][fc][i] + bv;
        if (RELU) v = fmaxf(v, 0.f);
        C[row * N + col] = v;
      }
    }
  }
}

// ---------------------------------------------------------------------------
// zfold via MFMA (validated round 8, unchanged).
// ---------------------------------------------------------------------------
__global__ __launch_bounds__(256, 1) void zfold_mfma_kernel(
    const float* __restrict__ xp,
    const ushort* __restrict__ We2h, const ushort* __restrict__ We2l,
    const float* __restrict__ interhb, const float* __restrict__ ia1,
    const float* __restrict__ ia2, const float* __restrict__ We1,
    const float* __restrict__ be1,
    float* __restrict__ aggA, float* __restrict__ aggB)
{
  __shared__ __align__(16) ushort Ah[2][64 * 72], Al[2][64 * 72];
  __shared__ __align__(16) ushort Bh[128 * 72], Bl[128 * 72];
  __shared__ float accAs[32 * 128], accBs[32 * 128];
  __shared__ float ehs[3][32][8];
  const int tid = threadIdx.x;
  const int w = tid >> 6, l = tid & 63;
  const int rg = blockIdx.x >> 2, kq = blockIdx.x & 3;
  const int i0 = rg * 32;

  for (int t = tid; t < 2048; t += 256) {
    int r = t >> 5, k4 = (t & 31) << 2;
    int gr = (r < 32) ? (i0 + r) : (B2 + i0 + r - 32);
    float4 v = *(const float4*)&xp[(long)gr * 128 + k4];
    int ch = k4 >> 6, ko = k4 & 63;
    ushort4 h4, l4;
    h4.x = f2bf(v.x); l4.x = f2bf(v.x - bf2f(h4.x));
    h4.y = f2bf(v.y); l4.y = f2bf(v.y - bf2f(h4.y));
    h4.z = f2bf(v.z); l4.z = f2bf(v.z - bf2f(h4.z));
    h4.w = f2bf(v.w); l4.w = f2bf(v.w - bf2f(h4.w));
    *(ushort4*)&Ah[ch][r * 72 + ko] = h4;
    *(ushort4*)&Al[ch][r * 72 + ko] = l4;
  }
  for (int t = tid; t < 768; t += 256) {
    int grp = t >> 8, rem = t & 255;
    int mm = rem >> 3, kk = rem & 7;
    int k = kq * 8 + kk;
    float u = (grp == 0) ? interhb[i0 + mm] : (grp == 1) ? ia1[i0 + mm] : ia2[i0 + mm];
    ehs[grp][mm][kk] = fmaxf(fmaf(u, We1[k], be1[k]), 0.f);
  }
  for (int t = tid; t < 4096; t += 256) { accAs[t] = 0.f; accBs[t] = 0.f; }

  float foldA[8][4] = {{0.f}}, foldB[8][4] = {{0.f}};
  const int ar = w * 16 + (l & 15);

  for (int kk = 0; kk < 8; ++kk) {
    const int k = kq * 8 + kk;
    f32x4 acc[8];
    #pragma unroll
    for (int fc = 0; fc < 8; ++fc) acc[fc] = (f32x4){0.f, 0.f, 0.f, 0.f};
    for (int ch = 0; ch < 2; ++ch) {
      __syncthreads();
      #pragma unroll
      for (int q = 0; q < 4; ++q) {
        int lin = tid + 256 * q;
        int n = lin >> 3, k8 = (lin & 7) << 3;
        *(uint4*)&Bh[n * 72 + k8] = *(const uint4*)&We2h[k * 16384 + n * 128 + ch * 64 + k8];
        *(uint4*)&Bl[n * 72 + k8] = *(const uint4*)&We2l[k * 16384 + n * 128 + ch * 64 + k8];
      }
      __syncthreads();
      #pragma unroll
      for (int ks = 0; ks < 2; ++ks) {
        const int ko = ks * 32 + (l >> 4) * 8;
        short8 ah  = *(const short8*)&Ah[ch][ar * 72 + ko];
        short8 al8 = *(const short8*)&Al[ch][ar * 72 + ko];
        #pragma unroll
        for (int fc = 0; fc < 8; ++fc) {
          const int c = fc * 16 + (l & 15);
          short8 bh  = *(const short8*)&Bh[c * 72 + ko];
          short8 bl8 = *(const short8*)&Bl[c * 72 + ko];
          acc[fc] = __builtin_amdgcn_mfma_f32_16x16x32_bf16(al8, bh, acc[fc], 0, 0, 0);
          acc[fc] = __builtin_amdgcn_mfma_f32_16x16x32_bf16(ah, bl8, acc[fc], 0, 0, 0);
          acc[fc] = __builtin_amdgcn_mfma_f32_16x16x32_bf16(ah, bh, acc[fc], 0, 0, 0);
        }
      }
    }
    #pragma unroll
    for (int i = 0; i < 4; ++i) {
      int lr = w * 16 + ((l >> 4) << 2) + i;
      int m = lr & 31, up = lr >> 5;
      float eA = up ? ehs[0][m][kk] : ehs[1][m][kk];
      float eB = up ? ehs[2][m][kk] : ehs[0][m][kk];
      #pragma unroll
      for (int fc = 0; fc < 8; ++fc) {
        foldA[fc][i] = fmaf(eA, acc[fc][i], foldA[fc][i]);
        foldB[fc][i] = fmaf(eB, acc[fc][i], foldB[fc][i]);
      }
    }
  }
  #pragma unroll
  for (int i = 0; i < 4; ++i) {
    int lr = w * 16 + ((l >> 4) << 2) + i;
    int m = lr & 31;
    #pragma unroll
    for (int fc = 0; fc < 8; ++fc) {
      int c = fc * 16 + (l & 15);
      atomicAdd(&accAs[m * 128 + c], foldA[fc][i]);
      atomicAdd(&accBs[m * 128 + c], foldB[fc][i]);
    }
  }
  __syncthreads();
  for (int t = tid; t < 4096; t += 256) {
    int mm = t >> 7, c = t & 127;
    atomicAdd(&aggA[(long)(i0 + mm) * 128 + c], accAs[t]);
    atomicAdd(&aggB[(long)(i0 + mm) * 128 + c], accBs[t]);
  }
}

// ---------------------------------------------------------------------------
// adj: normalized dense adjacency Â[d][s] = cnt(s->d)*rsI[d]*rsO[s].
// ---------------------------------------------------------------------------
__global__ __launch_bounds__(256) void adj_kernel(
    const int* __restrict__ src1, const int* __restrict__ dst1,
    const int* __restrict__ src2, const int* __restrict__ dst2,
    float* __restrict__ Abuf)
{
  __shared__ float cnt[4][30 * 33];
  __shared__ float rsOa[4][32], rsIa[4][32];
  const int tid = threadIdx.x, wid = tid >> 6, lane = tid & 63;
  const int gm = blockIdx.x * 4 + wid;
  const int g = gm >> 11, m = gm & 2047;
  const int* src = g ? src2 : src1;
  const int* dst = g ? dst2 : dst1;

  for (int i = lane; i < 30 * 33; i += 64) cnt[wid][i] = 0.f;
  __syncthreads();
  for (int e = lane; e < EPM; e += 64) {
    int s = src[m * EPM + e] - m * NPM;
    int d = dst[m * EPM + e] - m * NPM;
    atomicAdd(&cnt[wid][d * 33 + s], 1.0f);
  }
  __syncthreads();
  if (lane < NPM) {
    float sum = 0.f;
    for (int s = 0; s < NPM; ++s) sum += cnt[wid][lane * 33 + s];
    rsIa[wid][lane] = rsqrtf(fmaxf(sum, 1.f));
  } else if (lane >= 32 && lane < 32 + NPM) {
    int s = lane - 32; float sum = 0.f;
    for (int d = 0; d < NPM; ++d) sum += cnt[wid][d * 33 + s];
    rsOa[wid][s] = rsqrtf(fmaxf(sum, 1.f));
  }
  __syncthreads();
  const long base = (long)gm * 960;
  for (int i = lane; i < 960; i += 64) {
    int d = i >> 5, s = i & 31;
    float v = (d < NPM && s < NPM)
            ? cnt[wid][d * 33 + s] * rsIa[wid][d] * rsOa[wid][s] : 0.f;
    Abuf[base + i] = v;
  }
}

// ---------------------------------------------------------------------------
// FULLY-FUSED GraphConv: per 2-molecule block:
//   phase 0: stage X -> bf16-split swz A-tile; y1 = X@Wg1 [MFMA] -> y1s LDS
//   phase 2: t1 = relu(Â@y1+b1) [VALU]; phase 3: agg2 = Â@t1 [VALU, regs]
//   phase 4: regs -> bf16 A-tile; phase 5: t2 = relu(agg2@Wg2+b2) [MFMA]
//   + mean-pool * solv -> xcat.  y1/agg2 never touch HBM.
// ---------------------------------------------------------------------------
__global__ __launch_bounds__(256, 2) void gconv_kernel(
    const float* __restrict__ h1, const float* __restrict__ h2,
    const float* __restrict__ Abuf, const float* __restrict__ bg1,
    const ushort* __restrict__ W1h, const ushort* __restrict__ W1l,
    const ushort* __restrict__ W2h, const ushort* __restrict__ W2l,
    const float* __restrict__ bias2, const float* __restrict__ s1x,
    float* __restrict__ xcat)
{
  __shared__ __align__(16) char pool[70400];
  float* y1s = (float*)pool;               // [60*128]  [0,30720)
  float* t1s = (float*)(pool + 30720);     // [60*128]  [30720,61440)
  float* AbL = (float*)(pool + 61440);     // [2*990]   [61440,69360)
  float* cs  = (float*)(pool + 69376);     // [256]     [69376,70400)
  char* AhB = pool;                        // A hi, 64 rows x 256B swz
  char* AlB = pool + 16384;                // A lo
  char* BhB = pool + 32768;                // B hi chunk, 128 rows x 128B swz
  char* BlB = pool + 49152;                // B lo chunk

  const int tid = threadIdx.x;
  const int p = blockIdx.x;
  const int g = p >> 10;
  const int mloc = (p & 1023) * 2;
  const float* hsrc = g ? h2 : h1;
  cs[tid] = 0.f;

  const int w = tid >> 6, l = tid & 63;
  const int ar = w * 16 + (l & 15);

  // ---- phase 0a: stage X (60x74 -> 64x128 pad) into swz256 bf16-split A ----
  #pragma unroll
  for (int q = 0; q < 8; ++q) {
    int lin = tid + 256 * q;                 // 0..2047
    int r = lin >> 5, k4 = (lin & 31) << 2;
    float4 v = make_float4(0.f, 0.f, 0.f, 0.f);
    if (r < 60) {
      const float* Ar = &hsrc[(long)(mloc * 30 + r) * 74];
      if (k4 + 4 <= 74) {
        float2 a = *(const float2*)&Ar[k4];
        float2 b = *(const float2*)&Ar[k4 + 2];
        v = make_float4(a.x, a.y, b.x, b.y);
      } else if (k4 + 2 <= 74) {
        float2 a = *(const float2*)&Ar[k4];
        v.x = a.x; v.y = a.y;
      }
    }
    ushort4 h4, l4;
    h4.x = f2bf(v.x); l4.x = f2bf(v.x - bf2f(h4.x));
    h4.y = f2bf(v.y); l4.y = f2bf(v.y - bf2f(h4.y));
    h4.z = f2bf(v.z); l4.z = f2bf(v.z - bf2f(h4.z));
    h4.w = f2bf(v.w); l4.w = f2bf(v.w - bf2f(h4.w));
    *(ushort4*)(AhB + swz256(r, k4 * 2)) = h4;
    *(ushort4*)(AlB + swz256(r, k4 * 2)) = l4;
  }
  __syncthreads();

  // ---- phase 0b: y1 = X @ Wg1 (MFMA, split-bf16) ----
  f32x4 acc[8];
  #pragma unroll
  for (int fc = 0; fc < 8; ++fc) acc[fc] = (f32x4){0.f, 0.f, 0.f, 0.f};
  for (int k0 = 0; k0 < 128; k0 += 64) {
    #pragma unroll
    for (int q = 0; q < 4; ++q) {
      int lin = tid + 256 * q;
      int n = lin >> 3, k8 = (lin & 7) << 3;
      *(uint4*)(BhB + swz128(n, k8 * 2)) = *(const uint4*)&W1h[n * 128 + k0 + k8];
      *(uint4*)(BlB + swz128(n, k8 * 2)) = *(const uint4*)&W1l[n * 128 + k0 + k8];
    }
    __syncthreads();
    #pragma unroll
    for (int ks = 0; ks < 2; ++ks) {
      const int ko = ks * 32 + (l >> 4) * 8;
      short8 ah  = *(const short8*)(AhB + swz256(ar, (k0 + ko) * 2));
      short8 al8 = *(const short8*)(AlB + swz256(ar, (k0 + ko) * 2));
      #pragma unroll
      for (int fc = 0; fc < 8; ++fc) {
        const int c = fc * 16 + (l & 15);
        short8 bh  = *(const short8*)(BhB + swz128(c, ko * 2));
        short8 bl8 = *(const short8*)(BlB + swz128(c, ko * 2));
        acc[fc] = __builtin_amdgcn_mfma_f32_16x16x32_bf16(al8, bh, acc[fc], 0, 0, 0);
        acc[fc] = __builtin_amdgcn_mfma_f32_16x16x32_bf16(ah, bl8, acc[fc], 0, 0, 0);
        acc[fc] = __builtin_amdgcn_mfma_f32_16x16x32_bf16(ah, bh, acc[fc], 0, 0, 0);
      }
    }
    __syncthreads();
  }

  // ---- phase 1: y1 acc -> y1s (fp32, aliases dead A-tile); stage Â ----
  #pragma unroll
  for (int fc = 0; fc < 8; ++fc) {
    int col = fc * 16 + (l & 15);
    #pragma unroll
    for (int i = 0; i < 4; ++i) {
      int lr = w * 16 + ((l >> 4) << 2) + i;
      if (lr < 60) y1s[lr * 128 + col] = acc[fc][i];
    }
  }
  {
    const long ab = (long)(g * 2048 + mloc) * 960;
    for (int t = tid; t < 1920; t += 256) {
      int mm = (t >= 960) ? 1 : 0; int j = t - mm * 960;
      int d = j >> 5, s = j & 31;
      AbL[mm * 990 + d * 33 + s] = Abuf[ab + t];
    }
  }
  __syncthreads();

  const int rgrp = tid >> 4, cgrp = tid & 15;
  const int c0 = cgrp * 4;
  const int mol = rgrp >> 3;
  const int d0  = (rgrp & 7) * 4;
  const float* Am = &AbL[mol * 990];
  float accA[4][4], accB[4][4];

  // ---- phase 2: t1 = relu(Â@y1 + b1) ----
  {
    float4 bv0 = *(const float4*)&bg1[c0];
    float4 bv1 = *(const float4*)&bg1[c0 + 64];
    for (int i = 0; i < 4; ++i)
      for (int j = 0; j < 4; ++j) { accA[i][j] = 0.f; accB[i][j] = 0.f; }
    #pragma unroll 5
    for (int s = 0; s < 30; ++s) {
      float4 ya = *(const float4*)&y1s[(mol * 30 + s) * 128 + c0];
      float4 yb = *(const float4*)&y1s[(mol * 30 + s) * 128 + c0 + 64];
      for (int i = 0; i < 4; ++i) {
        float ab = Am[(d0 + i) * 33 + s];
        fmas4(accA[i], ab, ya);
        fmas4(accB[i], ab, yb);
      }
    }
    __syncthreads();
    for (int i = 0; i < 4; ++i) {
      int d = d0 + i;
      if (d < NPM) {
        int r = mol * 30 + d;
        float4 oa, ob;
        oa.x = fmaxf(accA[i][0] + bv0.x, 0.f); oa.y = fmaxf(accA[i][1] + bv0.y, 0.f);
        oa.z = fmaxf(accA[i][2] + bv0.z, 0.f); oa.w = fmaxf(accA[i][3] + bv0.w, 0.f);
        ob.x = fmaxf(accB[i][0] + bv1.x, 0.f); ob.y = fmaxf(accB[i][1] + bv1.y, 0.f);
        ob.z = fmaxf(accB[i][2] + bv1.z, 0.f); ob.w = fmaxf(accB[i][3] + bv1.w, 0.f);
        *(float4*)&t1s[r * 128 + c0]      = oa;
        *(float4*)&t1s[r * 128 + c0 + 64] = ob;
      }
    }
  }
  __syncthreads();

  // ---- phase 3: agg2 = Â@t1 (registers) ----
  {
    for (int i = 0; i < 4; ++i)
      for (int j = 0; j < 4; ++j) { accA[i][j] = 0.f; accB[i][j] = 0.f; }
    #pragma unroll 5
    for (int s = 0; s < 30; ++s) {
      float4 ta = *(const float4*)&t1s[(mol * 30 + s) * 128 + c0];
      float4 tb = *(const float4*)&t1s[(mol * 30 + s) * 128 + c0 + 64];
      for (int i = 0; i < 4; ++i) {
        float ab = Am[(d0 + i) * 33 + s];
        fmas4(accA[i], ab, ta);
        fmas4(accB[i], ab, tb);
      }
    }
  }
  __syncthreads();   // all t1s/AbL reads complete before A-tile overwrites

  // ---- phase 4: regs -> bf16 split swizzled A-tile (rows 60-63 zeroed) ----
  if (tid < 128) {
    int arr = tid >> 6, rr = 60 + ((tid >> 4) & 3), q16 = (tid & 15) << 4;
    uint4 z = {0u, 0u, 0u, 0u};
    *(uint4*)((arr ? AlB : AhB) + rr * 256 + q16) = z;
  }
  for (int i = 0; i < 4; ++i) {
    int d = d0 + i;
    if (d < NPM) {
      int r = mol * 30 + d;
      ushort4 h4, l4;
      h4.x = f2bf(accA[i][0]); l4.x = f2bf(accA[i][0] - bf2f(h4.x));
      h4.y = f2bf(accA[i][1]); l4.y = f2bf(accA[i][1] - bf2f(h4.y));
      h4.z = f2bf(accA[i][2]); l4.z = f2bf(accA[i][2] - bf2f(h4.z));
      h4.w = f2bf(accA[i][3]); l4.w = f2bf(accA[i][3] - bf2f(h4.w));
      *(ushort4*)(AhB + swz256(r, c0 * 2)) = h4;
      *(ushort4*)(AlB + swz256(r, c0 * 2)) = l4;
      h4.x = f2bf(accB[i][0]); l4.x = f2bf(accB[i][0] - bf2f(h4.x));
      h4.y = f2bf(accB[i][1]); l4.y = f2bf(accB[i][1] - bf2f(h4.y));
      h4.z = f2bf(accB[i][2]); l4.z = f2bf(accB[i][2] - bf2f(h4.z));
      h4.w = f2bf(accB[i][3]); l4.w = f2bf(accB[i][3] - bf2f(h4.w));
      *(ushort4*)(AhB + swz256(r, (c0 + 64) * 2)) = h4;
      *(ushort4*)(AlB + swz256(r, (c0 + 64) * 2)) = l4;
    }
  }

  // ---- phase 5: MFMA t2 = relu(A@Wg2 + b2) + pool ----
  #pragma unroll
  for (int fc = 0; fc < 8; ++fc) acc[fc] = (f32x4){0.f, 0.f, 0.f, 0.f};

  for (int k0 = 0; k0 < 128; k0 += 64) {
    __syncthreads();   // A writes visible (first iter) / previous B reads done
    #pragma unroll
    for (int q = 0; q < 4; ++q) {
      int lin = tid + 256 * q;
      int n = lin >> 3, k8 = (lin & 7) << 3;
      *(uint4*)(BhB + swz128(n, k8 * 2)) = *(const uint4*)&W2h[n * 128 + k0 + k8];
      *(uint4*)(BlB + swz128(n, k8 * 2)) = *(const uint4*)&W2l[n * 128 + k0 + k8];
    }
    __syncthreads();
    #pragma unroll
    for (int ks = 0; ks < 2; ++ks) {
      const int ko = ks * 32 + (l >> 4) * 8;
      short8 ah  = *(const short8*)(AhB + swz256(ar, (k0 + ko) * 2));
      short8 al8 = *(const short8*)(AlB + swz256(ar, (k0 + ko) * 2));
      #pragma unroll
      for (int fc = 0; fc < 8; ++fc) {
        const int c = fc * 16 + (l & 15);
        short8 bh  = *(const short8*)(BhB + swz128(c, ko * 2));
        short8 bl8 = *(const short8*)(BlB + swz128(c, ko * 2));
        acc[fc] = __builtin_amdgcn_mfma_f32_16x16x32_bf16(al8, bh, acc[fc], 0, 0, 0);
        acc[fc] = __builtin_amdgcn_mfma_f32_16x16x32_bf16(ah, bl8, acc[fc], 0, 0, 0);
        acc[fc] = __builtin_amdgcn_mfma_f32_16x16x32_bf16(ah, bh, acc[fc], 0, 0, 0);
      }
    }
  }
  __syncthreads();

  // pool epilogue: bias+relu, per-thread row sums, wave shfl-reduce, cs atomics
  #pragma unroll
  for (int fc = 0; fc < 8; ++fc) {
    int col = fc * 16 + (l & 15);
    float bv = bias2[col];
    float s0 = 0.f, s1 = 0.f;
    #pragma unroll
    for (int i = 0; i < 4; ++i) {
      int lr = w * 16 + ((l >> 4) << 2) + i;
      if (lr < 60) {
        float v = fmaxf(acc[fc][i] + bv, 0.f);
        if (lr < NPM) s0 += v; else s1 += v;
      }
    }
    s0 += __shfl_down(s0, 32); s0 += __shfl_down(s0, 16);
    s1 += __shfl_down(s1, 32); s1 += __shfl_down(s1, 16);
    if ((l >> 4) == 0) {
      atomicAdd(&cs[col], s0);
      atomicAdd(&cs[128 + col], s1);
    }
  }
  __syncthreads();
  {
    int moll = tid >> 7, c = tid & 127;
    int gm = p * 2 + moll;
    int gg = gm >> 11, mm = gm & 2047;
    float sf = gg ? (1.f - s1x[mm]) : s1x[mm];
    xcat[(long)gm * 128 + c] = cs[moll * 128 + c] * (1.f / 30.f) * sf;
  }
}

__global__ __launch_bounds__(256) void xin_kernel(
    const float* __restrict__ aggA, const float* __restrict__ aggB,
    const float* __restrict__ zb, const float* __restrict__ bnn,
    float* __restrict__ x_in)
{
  int idx = blockIdx.x * 256 + threadIdx.x;
  int i = idx >> 7, c = idx & 127;
  float zs = zb[i * 128 + c] + zb[(i + B2) * 128 + c] + bnn[c];
  x_in[i * 128 + c]        = fmaxf(aggA[idx] + zs, 0.f);
  x_in[(i + B2) * 128 + c] = fmaxf(aggB[idx] + zs, 0.f);
}

__global__ __launch_bounds__(256) void gru_kernel(
    const float* __restrict__ gi, const float* __restrict__ gh,
    const float* __restrict__ xp, float* __restrict__ xnew)
{
  int idx = blockIdx.x * 256 + threadIdx.x;
  int n = idx >> 7, j = idx & 127;
  float ir = gi[n * 384 + j], iz = gi[n * 384 + 128 + j], ih = gi[n * 384 + 256 + j];
  float hr = gh[n * 384 + j], hz = gh[n * 384 + 128 + j], hn = gh[n * 384 + 256 + j];
  float h  = xp[idx];
  float r  = 1.f / (1.f + expf(-(ir + hr)));
  float zg = 1.f / (1.f + expf(-(iz + hz)));
  float ng = tanhf(ih + r * hn);
  xnew[idx] = (1.f - zg) * ng + zg * h;
}

__global__ __launch_bounds__(256) void final_kernel(
    const float* __restrict__ o2, const float* __restrict__ Wcl3,
    const float* __restrict__ bcl3, float* __restrict__ out)
{
  int idx = blockIdx.x * 256 + threadIdx.x;
  int i = idx >> 1, c = idx & 1;
  float acc = bcl3[c];
  for (int k = 0; k < 128; ++k) acc = fmaf(o2[i * 128 + k], Wcl3[k * 2 + c], acc);
  out[idx] = acc;
}

// ---------------------------------------------------------------------------
extern "C" void kernel_launch(void* const* d_in, const int* in_sizes, int n_in,
                              void* d_out, int out_size, void* d_ws, size_t ws_size,
                              hipStream_t stream)
{
  const float* h1   = (const float*)d_in[0];
  const float* h2   = (const float*)d_in[1];
  const float* s1x  = (const float*)d_in[2];
  const float* ihb  = (const float*)d_in[3];
  const float* ia1  = (const float*)d_in[4];
  const float* ia2  = (const float*)d_in[5];
  const float* Wg1  = (const float*)d_in[6];
  const float* bg1  = (const float*)d_in[7];
  const float* Wg2  = (const float*)d_in[8];
  const float* bg2  = (const float*)d_in[9];
  const float* Wp   = (const float*)d_in[10];
  const float* bp   = (const float*)d_in[11];
  const float* We1  = (const float*)d_in[12];
  const float* be1  = (const float*)d_in[13];
  const float* We2  = (const float*)d_in[14];
  const float* be2  = (const float*)d_in[15];
  const float* bnn  = (const float*)d_in[16];
  const float* Wih  = (const float*)d_in[17];
  const float* bih  = (const float*)d_in[18];
  const float* Whh  = (const float*)d_in[19];
  const float* bhh  = (const float*)d_in[20];
  const float* Wcl1 = (const float*)d_in[21];
  const float* bcl1 = (const float*)d_in[22];
  const float* Wcl2 = (const float*)d_in[23];
  const float* bcl2 = (const float*)d_in[24];
  const float* Wcl3 = (const float*)d_in[25];
  const float* bcl3 = (const float*)d_in[26];
  const int*   src1 = (const int*)d_in[27];
  const int*   dst1 = (const int*)d_in[28];
  const int*   src2 = (const int*)d_in[29];
  const int*   dst2 = (const int*)d_in[30];
  float* out = (float*)d_out;
  float* ws  = (float*)d_ws;

  float* Abuf = ws;                          // 3,932,160
  float* dwn  = ws + 35389440;

  float* xcat = dwn;
  float* xp   = dwn + 524288;
  float* zb   = dwn + 1048576;
  float* aggA = dwn + 1572864;
  float* aggB = dwn + 1835008;
  float* x_in = dwn + 2097152;
  float* gi   = dwn + 2621440;
  float* gh   = dwn + 4194304;
  float* xnew = dwn + 5767168;
  float* o1   = dwn + 6291456;
  float* o2   = dwn + 6553600;

  ushort* wt     = (ushort*)(dwn + 6815744);
  ushort* WpTh   = wt;               ushort* WpTl   = wt + 16384;
  ushort* be2Th  = wt + 32768;       ushort* be2Tl  = wt + 49152;
  ushort* WihTh  = wt + 65536;       ushort* WihTl  = wt + 114688;
  ushort* WhhTh  = wt + 163840;      ushort* WhhTl  = wt + 212992;
  ushort* Wcl1Th = wt + 262144;      ushort* Wcl1Tl = wt + 294912;
  ushort* Wcl2Th = wt + 327680;      ushort* Wcl2Tl = wt + 344064;
  ushort* Wg1Th  = wt + 360448;      ushort* Wg1Tl  = wt + 376832;
  ushort* Wg2Th  = wt + 393216;      ushort* Wg2Tl  = wt + 409600;
  ushort* We2h   = wt + 425984;      ushort* We2l   = wt + 950272;

  // ---- weight prep ----
  prep_kernel<<<8, 256, 0, stream>>>(Wp,   WpTh,   WpTl,   128, 128, 128);
  prep_kernel<<<8, 256, 0, stream>>>(be2,  be2Th,  be2Tl,  128, 128, 128);
  prep_kernel<<<24, 256, 0, stream>>>(Wih,  WihTh,  WihTl,  128, 128, 384);
  prep_kernel<<<24, 256, 0, stream>>>(Whh,  WhhTh,  WhhTl,  128, 128, 384);
  prep_kernel<<<16, 256, 0, stream>>>(Wcl1, Wcl1Th, Wcl1Tl, 256, 256, 128);
  prep_kernel<<<8, 256, 0, stream>>>(Wcl2, Wcl2Th, Wcl2Tl, 128, 128, 128);
  prep_kernel<<<8, 256, 0, stream>>>(Wg1,  Wg1Th,  Wg1Tl,  74,  128, 128);
  prep_kernel<<<8, 256, 0, stream>>>(Wg2,  Wg2Th,  Wg2Tl,  128, 128, 128);
  prep_we2_kernel<<<256, 256, 0, stream>>>(We2, We2h, We2l);

  // ---- fully-fused GraphConv ----
  adj_kernel<<<1024, 256, 0, stream>>>(src1, dst1, src2, dst2, Abuf);
  gconv_kernel<<<2048, 256, 0, stream>>>(h1, h2, Abuf, bg1, Wg1Th, Wg1Tl,
                                         Wg2Th, Wg2Tl, bg2, s1x, xcat);

  // ---- solvent-system MPNN + GRU + classifier ----
  gemm_mfma_kernel<1, 1, 0><<<dim3(64, 4), 128, 0, stream>>>(
      xcat, nullptr, WpTh, WpTl, bp, xp, 4096, 128, 128, 128);
  gemm_mfma_kernel<0, 0, 0><<<dim3(64, 4), 128, 0, stream>>>(
      xp, nullptr, be2Th, be2Tl, nullptr, zb, 4096, 128, 128, 128);
  hipMemsetAsync(aggA, 0, 2 * 262144 * sizeof(float), stream);
  zfold_mfma_kernel<<<256, 256, 0, stream>>>(xp, We2h, We2l, ihb, ia1, ia2,
                                             We1, be1, aggA, aggB);
  xin_kernel<<<1024, 256, 0, stream>>>(aggA, aggB, zb, bnn, x_in);
  gemm_mfma_kernel<0, 1, 0><<<dim3(64, 12), 128, 0, stream>>>(
      x_in, nullptr, WihTh, WihTl, bih, gi, 4096, 384, 128, 128);
  gemm_mfma_kernel<0, 1, 0><<<dim3(64, 12), 128, 0, stream>>>(
      xp, nullptr, WhhTh, WhhTl, bhh, gh, 4096, 384, 128, 128);
  gru_kernel<<<2048, 256, 0, stream>>>(gi, gh, xp, xnew);
  gemm_mfma_kernel<1, 1, 1><<<dim3(32, 4), 128, 0, stream>>>(
      xnew, xnew + (long)B2 * 128, Wcl1Th, Wcl1Tl, bcl1, o1, 2048, 128, 256, 128);
  gemm_mfma_kernel<1, 1, 0><<<dim3(32, 4), 128, 0, stream>>>(
      o1, nullptr, Wcl2Th, Wcl2Tl, bcl2, o2, 2048, 128, 128, 128);
  final_kernel<<<16, 256, 0, stream>>>(o2, Wcl3, bcl3, out);
}

// Round 11
// 230.307 us; speedup vs baseline: 3.9873x; 1.0643x over previous
//
#include <hip/hip_runtime.h>
#include <hip/hip_bf16.h>
#include <math.h>

#define B2    2048
#define NPM   30
#define EPM   120

typedef __attribute__((ext_vector_type(8))) short short8;
typedef __attribute__((ext_vector_type(4))) float f32x4;

__device__ __forceinline__ ushort f2bf(float x) {
  unsigned u = __float_as_uint(x);
  return (ushort)((u + 0x7FFFu + ((u >> 16) & 1u)) >> 16);
}
__device__ __forceinline__ float bf2f(ushort h) {
  return __uint_as_float(((unsigned)h) << 16);
}

// swizzled byte offsets: 128B rows (per-chunk tiles) and 256B rows (full-K A)
__device__ __forceinline__ int swz128(int r, int kb) { return r * 128 + (kb ^ ((r & 7) << 4)); }
__device__ __forceinline__ int swz256(int r, int kb) { return r * 256 + (kb ^ ((r & 15) << 4)); }

__device__ __forceinline__ void fmas4(float (&acc)[4], float s, const float4 w) {
  acc[0] = fmaf(s, w.x, acc[0]); acc[1] = fmaf(s, w.y, acc[1]);
  acc[2] = fmaf(s, w.z, acc[2]); acc[3] = fmaf(s, w.w, acc[3]);
}

// ---------------------------------------------------------------------------
// prep: W[Kreal][N] fp32 -> transposed bf16 split hi/lo[N][Kpad] (zero-pad k).
// ---------------------------------------------------------------------------
__global__ __launch_bounds__(256) void prep_kernel(
    const float* __restrict__ W, ushort* __restrict__ hi, ushort* __restrict__ lo,
    int Kreal, int Kpad, int N)
{
  int idx = blockIdx.x * 256 + threadIdx.x;
  int tot = N * (Kpad >> 3);
  if (idx >= tot) return;
  int n = idx / (Kpad >> 3);
  int k8 = (idx - n * (Kpad >> 3)) << 3;
  #pragma unroll
  for (int j = 0; j < 8; ++j) {
    int k = k8 + j;
    float x = (k < Kreal) ? W[(long)k * N + n] : 0.f;
    ushort h = f2bf(x);
    hi[(long)n * Kpad + k] = h;
    lo[(long)n * Kpad + k] = f2bf(x - bf2f(h));
  }
}

// We2[32][128][128] -> per-k transposed bf16 split hi/lo[k][n][d]
__global__ __launch_bounds__(256) void prep_we2_kernel(
    const float* __restrict__ We2, ushort* __restrict__ hi, ushort* __restrict__ lo)
{
  int idx = blockIdx.x * 256 + threadIdx.x;   // 32*128*16 = 65536
  int k = idx >> 11;
  int rem = idx & 2047;
  int n = rem >> 4;
  int d8 = (rem & 15) << 3;
  #pragma unroll
  for (int j = 0; j < 8; ++j) {
    int d = d8 + j;
    float x = We2[k * 16384 + d * 128 + n];
    ushort h = f2bf(x);
    hi[k * 16384 + n * 128 + d] = h;
    lo[k * 16384 + n * 128 + d] = f2bf(x - bf2f(h));
  }
}

// ---------------------------------------------------------------------------
// MFMA GEMM, split-bf16, tile 64x32, 2 waves, swizzled LDS. (dense chain)
// ---------------------------------------------------------------------------
template<int RELU, int BIAS, int CAT>
__global__ __launch_bounds__(128) void gemm_mfma_kernel(
    const float* __restrict__ A, const float* __restrict__ A2,
    const ushort* __restrict__ Wh, const ushort* __restrict__ Wl,
    const float* __restrict__ bias, float* __restrict__ C,
    int M, int N, int K, int lda)
{
  __shared__ __align__(16) char AhB[8192], AlB[8192];
  __shared__ __align__(16) char BhB[4096], BlB[4096];
  const int tid = threadIdx.x;
  const int w = tid >> 6, l = tid & 63;
  const long rowBase = (long)blockIdx.x * 64;
  const int colBase = blockIdx.y * 32;

  f32x4 acc[2][2];
  #pragma unroll
  for (int fr = 0; fr < 2; ++fr)
    #pragma unroll
    for (int fc = 0; fc < 2; ++fc)
      acc[fr][fc] = (f32x4){0.f, 0.f, 0.f, 0.f};

  for (int k0 = 0; k0 < K; k0 += 64) {
    const float* Ab = (CAT && k0 >= 128) ? A2 : A;
    const int kc = CAT ? (k0 & 127) : k0;
    #pragma unroll
    for (int q = 0; q < 8; ++q) {
      int lin = tid + 128 * q;
      int r = lin >> 4, k4 = (lin & 15) << 2;
      float4 v = *(const float4*)&Ab[(rowBase + r) * lda + kc + k4];
      ushort4 h4, l4;
      h4.x = f2bf(v.x); l4.x = f2bf(v.x - bf2f(h4.x));
      h4.y = f2bf(v.y); l4.y = f2bf(v.y - bf2f(h4.y));
      h4.z = f2bf(v.z); l4.z = f2bf(v.z - bf2f(h4.z));
      h4.w = f2bf(v.w); l4.w = f2bf(v.w - bf2f(h4.w));
      *(ushort4*)(AhB + swz128(r, k4 * 2)) = h4;
      *(ushort4*)(AlB + swz128(r, k4 * 2)) = l4;
    }
    #pragma unroll
    for (int q = 0; q < 2; ++q) {
      int lin = tid + 128 * q;
      int n = lin >> 3, k8 = (lin & 7) << 3;
      *(uint4*)(BhB + swz128(n, k8 * 2)) = *(const uint4*)&Wh[(long)(colBase + n) * K + k0 + k8];
      *(uint4*)(BlB + swz128(n, k8 * 2)) = *(const uint4*)&Wl[(long)(colBase + n) * K + k0 + k8];
    }
    __syncthreads();
    #pragma unroll
    for (int ks = 0; ks < 2; ++ks) {
      const int ko = ks * 32 + (l >> 4) * 8;
      short8 ah[2], al8[2], bh[2], bl8[2];
      #pragma unroll
      for (int fr = 0; fr < 2; ++fr) {
        int r = w * 32 + fr * 16 + (l & 15);
        ah[fr]  = *(const short8*)(AhB + swz128(r, ko * 2));
        al8[fr] = *(const short8*)(AlB + swz128(r, ko * 2));
      }
      #pragma unroll
      for (int fc = 0; fc < 2; ++fc) {
        int c = fc * 16 + (l & 15);
        bh[fc]  = *(const short8*)(BhB + swz128(c, ko * 2));
        bl8[fc] = *(const short8*)(BlB + swz128(c, ko * 2));
      }
      #pragma unroll
      for (int fr = 0; fr < 2; ++fr)
        #pragma unroll
        for (int fc = 0; fc < 2; ++fc) {
          acc[fr][fc] = __builtin_amdgcn_mfma_f32_16x16x32_bf16(al8[fr], bh[fc], acc[fr][fc], 0, 0, 0);
          acc[fr][fc] = __builtin_amdgcn_mfma_f32_16x16x32_bf16(ah[fr], bl8[fc], acc[fr][fc], 0, 0, 0);
          acc[fr][fc] = __builtin_amdgcn_mfma_f32_16x16x32_bf16(ah[fr], bh[fc], acc[fr][fc], 0, 0, 0);
        }
    }
    __syncthreads();
  }
  #pragma unroll
  for (int fc = 0; fc < 2; ++fc) {
    int col = colBase + fc * 16 + (l & 15);
    float bv = BIAS ? bias[col] : 0.f;
    #pragma unroll
    for (int fr = 0; fr < 2; ++fr) {
      #pragma unroll
      for (int i = 0; i < 4; ++i) {
        long row = rowBase + w * 32 + fr * 16 + ((l >> 4) << 2) + i;
        float v = acc[fr][fc][i] + bv;
        if (RELU) v = fmaxf(v, 0.f);
        C[row * N + col] = v;
      }
    }
  }
}

// ---------------------------------------------------------------------------
// zfold via MFMA (validated round 8, unchanged).
// ---------------------------------------------------------------------------
__global__ __launch_bounds__(256, 1) void zfold_mfma_kernel(
    const float* __restrict__ xp,
    const ushort* __restrict__ We2h, const ushort* __restrict__ We2l,
    const float* __restrict__ interhb, const float* __restrict__ ia1,
    const float* __restrict__ ia2, const float* __restrict__ We1,
    const float* __restrict__ be1,
    float* __restrict__ aggA, float* __restrict__ aggB)
{
  __shared__ __align__(16) ushort Ah[2][64 * 72], Al[2][64 * 72];
  __shared__ __align__(16) ushort Bh[128 * 72], Bl[128 * 72];
  __shared__ float accAs[32 * 128], accBs[32 * 128];
  __shared__ float ehs[3][32][8];
  const int tid = threadIdx.x;
  const int w = tid >> 6, l = tid & 63;
  const int rg = blockIdx.x >> 2, kq = blockIdx.x & 3;
  const int i0 = rg * 32;

  for (int t = tid; t < 2048; t += 256) {
    int r = t >> 5, k4 = (t & 31) << 2;
    int gr = (r < 32) ? (i0 + r) : (B2 + i0 + r - 32);
    float4 v = *(const float4*)&xp[(long)gr * 128 + k4];
    int ch = k4 >> 6, ko = k4 & 63;
    ushort4 h4, l4;
    h4.x = f2bf(v.x); l4.x = f2bf(v.x - bf2f(h4.x));
    h4.y = f2bf(v.y); l4.y = f2bf(v.y - bf2f(h4.y));
    h4.z = f2bf(v.z); l4.z = f2bf(v.z - bf2f(h4.z));
    h4.w = f2bf(v.w); l4.w = f2bf(v.w - bf2f(h4.w));
    *(ushort4*)&Ah[ch][r * 72 + ko] = h4;
    *(ushort4*)&Al[ch][r * 72 + ko] = l4;
  }
  for (int t = tid; t < 768; t += 256) {
    int grp = t >> 8, rem = t & 255;
    int mm = rem >> 3, kk = rem & 7;
    int k = kq * 8 + kk;
    float u = (grp == 0) ? interhb[i0 + mm] : (grp == 1) ? ia1[i0 + mm] : ia2[i0 + mm];
    ehs[grp][mm][kk] = fmaxf(fmaf(u, We1[k], be1[k]), 0.f);
  }
  for (int t = tid; t < 4096; t += 256) { accAs[t] = 0.f; accBs[t] = 0.f; }

  float foldA[8][4] = {{0.f}}, foldB[8][4] = {{0.f}};
  const int ar = w * 16 + (l & 15);

  for (int kk = 0; kk < 8; ++kk) {
    const int k = kq * 8 + kk;
    f32x4 acc[8];
    #pragma unroll
    for (int fc = 0; fc < 8; ++fc) acc[fc] = (f32x4){0.f, 0.f, 0.f, 0.f};
    for (int ch = 0; ch < 2; ++ch) {
      __syncthreads();
      #pragma unroll
      for (int q = 0; q < 4; ++q) {
        int lin = tid + 256 * q;
        int n = lin >> 3, k8 = (lin & 7) << 3;
        *(uint4*)&Bh[n * 72 + k8] = *(const uint4*)&We2h[k * 16384 + n * 128 + ch * 64 + k8];
        *(uint4*)&Bl[n * 72 + k8] = *(const uint4*)&We2l[k * 16384 + n * 128 + ch * 64 + k8];
      }
      __syncthreads();
      #pragma unroll
      for (int ks = 0; ks < 2; ++ks) {
        const int ko = ks * 32 + (l >> 4) * 8;
        short8 ah  = *(const short8*)&Ah[ch][ar * 72 + ko];
        short8 al8 = *(const short8*)&Al[ch][ar * 72 + ko];
        #pragma unroll
        for (int fc = 0; fc < 8; ++fc) {
          const int c = fc * 16 + (l & 15);
          short8 bh  = *(const short8*)&Bh[c * 72 + ko];
          short8 bl8 = *(const short8*)&Bl[c * 72 + ko];
          acc[fc] = __builtin_amdgcn_mfma_f32_16x16x32_bf16(al8, bh, acc[fc], 0, 0, 0);
          acc[fc] = __builtin_amdgcn_mfma_f32_16x16x32_bf16(ah, bl8, acc[fc], 0, 0, 0);
          acc[fc] = __builtin_amdgcn_mfma_f32_16x16x32_bf16(ah, bh, acc[fc], 0, 0, 0);
        }
      }
    }
    #pragma unroll
    for (int i = 0; i < 4; ++i) {
      int lr = w * 16 + ((l >> 4) << 2) + i;
      int m = lr & 31, up = lr >> 5;
      float eA = up ? ehs[0][m][kk] : ehs[1][m][kk];
      float eB = up ? ehs[2][m][kk] : ehs[0][m][kk];
      #pragma unroll
      for (int fc = 0; fc < 8; ++fc) {
        foldA[fc][i] = fmaf(eA, acc[fc][i], foldA[fc][i]);
        foldB[fc][i] = fmaf(eB, acc[fc][i], foldB[fc][i]);
      }
    }
  }
  #pragma unroll
  for (int i = 0; i < 4; ++i) {
    int lr = w * 16 + ((l >> 4) << 2) + i;
    int m = lr & 31;
    #pragma unroll
    for (int fc = 0; fc < 8; ++fc) {
      int c = fc * 16 + (l & 15);
      atomicAdd(&accAs[m * 128 + c], foldA[fc][i]);
      atomicAdd(&accBs[m * 128 + c], foldB[fc][i]);
    }
  }
  __syncthreads();
  for (int t = tid; t < 4096; t += 256) {
    int mm = t >> 7, c = t & 127;
    atomicAdd(&aggA[(long)(i0 + mm) * 128 + c], accAs[t]);
    atomicAdd(&aggB[(long)(i0 + mm) * 128 + c], accBs[t]);
  }
}

// ---------------------------------------------------------------------------
// adj: normalized dense adjacency Â[d][s] = cnt(s->d)*rsI[d]*rsO[s].
// ---------------------------------------------------------------------------
__global__ __launch_bounds__(256) void adj_kernel(
    const int* __restrict__ src1, const int* __restrict__ dst1,
    const int* __restrict__ src2, const int* __restrict__ dst2,
    float* __restrict__ Abuf)
{
  __shared__ float cnt[4][30 * 33];
  __shared__ float rsOa[4][32], rsIa[4][32];
  const int tid = threadIdx.x, wid = tid >> 6, lane = tid & 63;
  const int gm = blockIdx.x * 4 + wid;
  const int g = gm >> 11, m = gm & 2047;
  const int* src = g ? src2 : src1;
  const int* dst = g ? dst2 : dst1;

  for (int i = lane; i < 30 * 33; i += 64) cnt[wid][i] = 0.f;
  __syncthreads();
  for (int e = lane; e < EPM; e += 64) {
    int s = src[m * EPM + e] - m * NPM;
    int d = dst[m * EPM + e] - m * NPM;
    atomicAdd(&cnt[wid][d * 33 + s], 1.0f);
  }
  __syncthreads();
  if (lane < NPM) {
    float sum = 0.f;
    for (int s = 0; s < NPM; ++s) sum += cnt[wid][lane * 33 + s];
    rsIa[wid][lane] = rsqrtf(fmaxf(sum, 1.f));
  } else if (lane >= 32 && lane < 32 + NPM) {
    int s = lane - 32; float sum = 0.f;
    for (int d = 0; d < NPM; ++d) sum += cnt[wid][d * 33 + s];
    rsOa[wid][s] = rsqrtf(fmaxf(sum, 1.f));
  }
  __syncthreads();
  const long base = (long)gm * 960;
  for (int i = lane; i < 960; i += 64) {
    int d = i >> 5, s = i & 31;
    float v = (d < NPM && s < NPM)
            ? cnt[wid][d * 33 + s] * rsIa[wid][d] * rsOa[wid][s] : 0.f;
    Abuf[base + i] = v;
  }
}

// ---------------------------------------------------------------------------
// FULLY-FUSED GraphConv, 512 threads (8 waves = 4 row-waves x 2 col-halves):
//   phase 0: stage X -> bf16-split swz A-tile; y1 = X@Wg1 [MFMA] -> y1s LDS
//   phase 2: t1 = relu(Â@y1+b1) [VALU]; phase 3: agg2 = Â@t1 [VALU, regs]
//   phase 4: regs -> bf16 A-tile; phase 5: t2 = relu(agg2@Wg2+b2) [MFMA]
//   + mean-pool * solv -> xcat.  y1/agg2 never touch HBM.
// ---------------------------------------------------------------------------
__global__ __launch_bounds__(512, 4) void gconv_kernel(
    const float* __restrict__ h1, const float* __restrict__ h2,
    const float* __restrict__ Abuf, const float* __restrict__ bg1,
    const ushort* __restrict__ W1h, const ushort* __restrict__ W1l,
    const ushort* __restrict__ W2h, const ushort* __restrict__ W2l,
    const float* __restrict__ bias2, const float* __restrict__ s1x,
    float* __restrict__ xcat)
{
  __shared__ __align__(16) char pool[70400];
  float* y1s = (float*)pool;               // [60*128]  [0,30720)
  float* t1s = (float*)(pool + 30720);     // [60*128]  [30720,61440)
  float* AbL = (float*)(pool + 61440);     // [2*990]   [61440,69360)
  float* cs  = (float*)(pool + 69376);     // [256]     [69376,70400)
  char* AhB = pool;                        // A hi, 64 rows x 256B swz
  char* AlB = pool + 16384;                // A lo
  char* BhB = pool + 32768;                // B hi chunk, 128 rows x 128B swz
  char* BlB = pool + 49152;                // B lo chunk

  const int tid = threadIdx.x;
  const int p = blockIdx.x;
  const int g = p >> 10;
  const int mloc = (p & 1023) * 2;
  const float* hsrc = g ? h2 : h1;
  if (tid < 256) cs[tid] = 0.f;

  const int w8 = tid >> 6, l = tid & 63;
  const int rw = w8 & 3;                   // row-wave 0..3 (16 rows each)
  const int ch2 = w8 >> 2;                 // col-half 0/1 (64 cols each)
  const int ar = rw * 16 + (l & 15);

  // ---- phase 0a: stage X (60x74 -> 64x128 pad) into swz256 bf16-split A ----
  #pragma unroll
  for (int q = 0; q < 4; ++q) {
    int lin = tid + 512 * q;                 // 0..2047
    int r = lin >> 5, k4 = (lin & 31) << 2;
    float4 v = make_float4(0.f, 0.f, 0.f, 0.f);
    if (r < 60) {
      const float* Ar = &hsrc[(long)(mloc * 30 + r) * 74];
      if (k4 + 4 <= 74) {
        float2 a = *(const float2*)&Ar[k4];
        float2 b = *(const float2*)&Ar[k4 + 2];
        v = make_float4(a.x, a.y, b.x, b.y);
      } else if (k4 + 2 <= 74) {
        float2 a = *(const float2*)&Ar[k4];
        v.x = a.x; v.y = a.y;
      }
    }
    ushort4 h4, l4;
    h4.x = f2bf(v.x); l4.x = f2bf(v.x - bf2f(h4.x));
    h4.y = f2bf(v.y); l4.y = f2bf(v.y - bf2f(h4.y));
    h4.z = f2bf(v.z); l4.z = f2bf(v.z - bf2f(h4.z));
    h4.w = f2bf(v.w); l4.w = f2bf(v.w - bf2f(h4.w));
    *(ushort4*)(AhB + swz256(r, k4 * 2)) = h4;
    *(ushort4*)(AlB + swz256(r, k4 * 2)) = l4;
  }
  __syncthreads();

  // ---- phase 0b: y1 = X @ Wg1 (MFMA, split-bf16), 4 fc per wave ----
  f32x4 acc[4];
  #pragma unroll
  for (int fc = 0; fc < 4; ++fc) acc[fc] = (f32x4){0.f, 0.f, 0.f, 0.f};
  for (int k0 = 0; k0 < 128; k0 += 64) {
    #pragma unroll
    for (int q = 0; q < 2; ++q) {
      int lin = tid + 512 * q;               // 0..1023
      int n = lin >> 3, k8 = (lin & 7) << 3;
      *(uint4*)(BhB + swz128(n, k8 * 2)) = *(const uint4*)&W1h[n * 128 + k0 + k8];
      *(uint4*)(BlB + swz128(n, k8 * 2)) = *(const uint4*)&W1l[n * 128 + k0 + k8];
    }
    __syncthreads();
    #pragma unroll
    for (int ks = 0; ks < 2; ++ks) {
      const int ko = ks * 32 + (l >> 4) * 8;
      short8 ah  = *(const short8*)(AhB + swz256(ar, (k0 + ko) * 2));
      short8 al8 = *(const short8*)(AlB + swz256(ar, (k0 + ko) * 2));
      #pragma unroll
      for (int fc = 0; fc < 4; ++fc) {
        const int c = ch2 * 64 + fc * 16 + (l & 15);
        short8 bh  = *(const short8*)(BhB + swz128(c, ko * 2));
        short8 bl8 = *(const short8*)(BlB + swz128(c, ko * 2));
        acc[fc] = __builtin_amdgcn_mfma_f32_16x16x32_bf16(al8, bh, acc[fc], 0, 0, 0);
        acc[fc] = __builtin_amdgcn_mfma_f32_16x16x32_bf16(ah, bl8, acc[fc], 0, 0, 0);
        acc[fc] = __builtin_amdgcn_mfma_f32_16x16x32_bf16(ah, bh, acc[fc], 0, 0, 0);
      }
    }
    __syncthreads();
  }

  // ---- phase 1: y1 acc -> y1s (fp32, aliases dead A-tile); stage Â ----
  #pragma unroll
  for (int fc = 0; fc < 4; ++fc) {
    int col = ch2 * 64 + fc * 16 + (l & 15);
    #pragma unroll
    for (int i = 0; i < 4; ++i) {
      int lr = rw * 16 + ((l >> 4) << 2) + i;
      if (lr < 60) y1s[lr * 128 + col] = acc[fc][i];
    }
  }
  {
    const long ab = (long)(g * 2048 + mloc) * 960;
    for (int t = tid; t < 1920; t += 512) {
      int mm = (t >= 960) ? 1 : 0; int j = t - mm * 960;
      int d = j >> 5, s = j & 31;
      AbL[mm * 990 + d * 33 + s] = Abuf[ab + t];
    }
  }
  __syncthreads();

  const int rgrp = tid >> 5, cgrp = tid & 31;  // 16 row-groups x 32 col-groups
  const int c0 = cgrp * 4;
  const int mol = rgrp >> 3;
  const int d0  = (rgrp & 7) * 4;
  const float* Am = &AbL[mol * 990];
  float accA[4][4];

  // ---- phase 2: t1 = relu(Â@y1 + b1) ----
  {
    float4 bv0 = *(const float4*)&bg1[c0];
    for (int i = 0; i < 4; ++i)
      for (int j = 0; j < 4; ++j) accA[i][j] = 0.f;
    #pragma unroll 5
    for (int s = 0; s < 30; ++s) {
      float4 ya = *(const float4*)&y1s[(mol * 30 + s) * 128 + c0];
      for (int i = 0; i < 4; ++i) {
        float ab = Am[(d0 + i) * 33 + s];
        fmas4(accA[i], ab, ya);
      }
    }
    __syncthreads();
    for (int i = 0; i < 4; ++i) {
      int d = d0 + i;
      if (d < NPM) {
        int r = mol * 30 + d;
        float4 oa;
        oa.x = fmaxf(accA[i][0] + bv0.x, 0.f); oa.y = fmaxf(accA[i][1] + bv0.y, 0.f);
        oa.z = fmaxf(accA[i][2] + bv0.z, 0.f); oa.w = fmaxf(accA[i][3] + bv0.w, 0.f);
        *(float4*)&t1s[r * 128 + c0] = oa;
      }
    }
  }
  __syncthreads();

  // ---- phase 3: agg2 = Â@t1 (registers) ----
  {
    for (int i = 0; i < 4; ++i)
      for (int j = 0; j < 4; ++j) accA[i][j] = 0.f;
    #pragma unroll 5
    for (int s = 0; s < 30; ++s) {
      float4 ta = *(const float4*)&t1s[(mol * 30 + s) * 128 + c0];
      for (int i = 0; i < 4; ++i) {
        float ab = Am[(d0 + i) * 33 + s];
        fmas4(accA[i], ab, ta);
      }
    }
  }
  __syncthreads();   // all t1s/AbL reads complete before A-tile overwrites

  // ---- phase 4: regs -> bf16 split swizzled A-tile (rows 60-63 zeroed) ----
  if (tid < 128) {
    int arr = tid >> 6, rr = 60 + ((tid >> 4) & 3), q16 = (tid & 15) << 4;
    uint4 z = {0u, 0u, 0u, 0u};
    *(uint4*)((arr ? AlB : AhB) + rr * 256 + q16) = z;
  }
  for (int i = 0; i < 4; ++i) {
    int d = d0 + i;
    if (d < NPM) {
      int r = mol * 30 + d;
      ushort4 h4, l4;
      h4.x = f2bf(accA[i][0]); l4.x = f2bf(accA[i][0] - bf2f(h4.x));
      h4.y = f2bf(accA[i][1]); l4.y = f2bf(accA[i][1] - bf2f(h4.y));
      h4.z = f2bf(accA[i][2]); l4.z = f2bf(accA[i][2] - bf2f(h4.z));
      h4.w = f2bf(accA[i][3]); l4.w = f2bf(accA[i][3] - bf2f(h4.w));
      *(ushort4*)(AhB + swz256(r, c0 * 2)) = h4;
      *(ushort4*)(AlB + swz256(r, c0 * 2)) = l4;
    }
  }

  // ---- phase 5: MFMA t2 = relu(A@Wg2 + b2) + pool ----
  #pragma unroll
  for (int fc = 0; fc < 4; ++fc) acc[fc] = (f32x4){0.f, 0.f, 0.f, 0.f};

  for (int k0 = 0; k0 < 128; k0 += 64) {
    __syncthreads();   // A writes visible (first iter) / previous B reads done
    #pragma unroll
    for (int q = 0; q < 2; ++q) {
      int lin = tid + 512 * q;
      int n = lin >> 3, k8 = (lin & 7) << 3;
      *(uint4*)(BhB + swz128(n, k8 * 2)) = *(const uint4*)&W2h[n * 128 + k0 + k8];
      *(uint4*)(BlB + swz128(n, k8 * 2)) = *(const uint4*)&W2l[n * 128 + k0 + k8];
    }
    __syncthreads();
    #pragma unroll
    for (int ks = 0; ks < 2; ++ks) {
      const int ko = ks * 32 + (l >> 4) * 8;
      short8 ah  = *(const short8*)(AhB + swz256(ar, (k0 + ko) * 2));
      short8 al8 = *(const short8*)(AlB + swz256(ar, (k0 + ko) * 2));
      #pragma unroll
      for (int fc = 0; fc < 4; ++fc) {
        const int c = ch2 * 64 + fc * 16 + (l & 15);
        short8 bh  = *(const short8*)(BhB + swz128(c, ko * 2));
        short8 bl8 = *(const short8*)(BlB + swz128(c, ko * 2));
        acc[fc] = __builtin_amdgcn_mfma_f32_16x16x32_bf16(al8, bh, acc[fc], 0, 0, 0);
        acc[fc] = __builtin_amdgcn_mfma_f32_16x16x32_bf16(ah, bl8, acc[fc], 0, 0, 0);
        acc[fc] = __builtin_amdgcn_mfma_f32_16x16x32_bf16(ah, bh, acc[fc], 0, 0, 0);
      }
    }
  }
  __syncthreads();

  // pool epilogue: bias+relu, per-thread row sums, wave shfl-reduce, cs atomics
  #pragma unroll
  for (int fc = 0; fc < 4; ++fc) {
    int col = ch2 * 64 + fc * 16 + (l & 15);
    float bv = bias2[col];
    float s0 = 0.f, s1 = 0.f;
    #pragma unroll
    for (int i = 0; i < 4; ++i) {
      int lr = rw * 16 + ((l >> 4) << 2) + i;
      if (lr < 60) {
        float v = fmaxf(acc[fc][i] + bv, 0.f);
        if (lr < NPM) s0 += v; else s1 += v;
      }
    }
    s0 += __shfl_down(s0, 32); s0 += __shfl_down(s0, 16);
    s1 += __shfl_down(s1, 32); s1 += __shfl_down(s1, 16);
    if ((l >> 4) == 0) {
      atomicAdd(&cs[col], s0);
      atomicAdd(&cs[128 + col], s1);
    }
  }
  __syncthreads();
  if (tid < 256) {
    int moll = tid >> 7, c = tid & 127;
    int gm = p * 2 + moll;
    int gg = gm >> 11, mm = gm & 2047;
    float sf = gg ? (1.f - s1x[mm]) : s1x[mm];
    xcat[(long)gm * 128 + c] = cs[moll * 128 + c] * (1.f / 30.f) * sf;
  }
}

__global__ __launch_bounds__(256) void xin_kernel(
    const float* __restrict__ aggA, const float* __restrict__ aggB,
    const float* __restrict__ zb, const float* __restrict__ bnn,
    float* __restrict__ x_in)
{
  int idx = blockIdx.x * 256 + threadIdx.x;
  int i = idx >> 7, c = idx & 127;
  float zs = zb[i * 128 + c] + zb[(i + B2) * 128 + c] + bnn[c];
  x_in[i * 128 + c]        = fmaxf(aggA[idx] + zs, 0.f);
  x_in[(i + B2) * 128 + c] = fmaxf(aggB[idx] + zs, 0.f);
}

__global__ __launch_bounds__(256) void gru_kernel(
    const float* __restrict__ gi, const float* __restrict__ gh,
    const float* __restrict__ xp, float* __restrict__ xnew)
{
  int idx = blockIdx.x * 256 + threadIdx.x;
  int n = idx >> 7, j = idx & 127;
  float ir = gi[n * 384 + j], iz = gi[n * 384 + 128 + j], ih = gi[n * 384 + 256 + j];
  float hr = gh[n * 384 + j], hz = gh[n * 384 + 128 + j], hn = gh[n * 384 + 256 + j];
  float h  = xp[idx];
  float r  = 1.f / (1.f + expf(-(ir + hr)));
  float zg = 1.f / (1.f + expf(-(iz + hz)));
  float ng = tanhf(ih + r * hn);
  xnew[idx] = (1.f - zg) * ng + zg * h;
}

__global__ __launch_bounds__(256) void final_kernel(
    const float* __restrict__ o2, const float* __restrict__ Wcl3,
    const float* __restrict__ bcl3, float* __restrict__ out)
{
  int idx = blockIdx.x * 256 + threadIdx.x;
  int i = idx >> 1, c = idx & 1;
  float acc = bcl3[c];
  for (int k = 0; k < 128; ++k) acc = fmaf(o2[i * 128 + k], Wcl3[k * 2 + c], acc);
  out[idx] = acc;
}

// ---------------------------------------------------------------------------
extern "C" void kernel_launch(void* const* d_in, const int* in_sizes, int n_in,
                              void* d_out, int out_size, void* d_ws, size_t ws_size,
                              hipStream_t stream)
{
  const float* h1   = (const float*)d_in[0];
  const float* h2   = (const float*)d_in[1];
  const float* s1x  = (const float*)d_in[2];
  const float* ihb  = (const float*)d_in[3];
  const float* ia1  = (const float*)d_in[4];
  const float* ia2  = (const float*)d_in[5];
  const float* Wg1  = (const float*)d_in[6];
  const float* bg1  = (const float*)d_in[7];
  const float* Wg2  = (const float*)d_in[8];
  const float* bg2  = (const float*)d_in[9];
  const float* Wp   = (const float*)d_in[10];
  const float* bp   = (const float*)d_in[11];
  const float* We1  = (const float*)d_in[12];
  const float* be1  = (const float*)d_in[13];
  const float* We2  = (const float*)d_in[14];
  const float* be2  = (const float*)d_in[15];
  const float* bnn  = (const float*)d_in[16];
  const float* Wih  = (const float*)d_in[17];
  const float* bih  = (const float*)d_in[18];
  const float* Whh  = (const float*)d_in[19];
  const float* bhh  = (const float*)d_in[20];
  const float* Wcl1 = (const float*)d_in[21];
  const float* bcl1 = (const float*)d_in[22];
  const float* Wcl2 = (const float*)d_in[23];
  const float* bcl2 = (const float*)d_in[24];
  const float* Wcl3 = (const float*)d_in[25];
  const float* bcl3 = (const float*)d_in[26];
  const int*   src1 = (const int*)d_in[27];
  const int*   dst1 = (const int*)d_in[28];
  const int*   src2 = (const int*)d_in[29];
  const int*   dst2 = (const int*)d_in[30];
  float* out = (float*)d_out;
  float* ws  = (float*)d_ws;

  float* Abuf = ws;                          // 3,932,160
  float* dwn  = ws + 35389440;

  float* xcat = dwn;
  float* xp   = dwn + 524288;
  float* zb   = dwn + 1048576;
  float* aggA = dwn + 1572864;
  float* aggB = dwn + 1835008;
  float* x_in = dwn + 2097152;
  float* gi   = dwn + 2621440;
  float* gh   = dwn + 4194304;
  float* xnew = dwn + 5767168;
  float* o1   = dwn + 6291456;
  float* o2   = dwn + 6553600;

  ushort* wt     = (ushort*)(dwn + 6815744);
  ushort* WpTh   = wt;               ushort* WpTl   = wt + 16384;
  ushort* be2Th  = wt + 32768;       ushort* be2Tl  = wt + 49152;
  ushort* WihTh  = wt + 65536;       ushort* WihTl  = wt + 114688;
  ushort* WhhTh  = wt + 163840;      ushort* WhhTl  = wt + 212992;
  ushort* Wcl1Th = wt + 262144;      ushort* Wcl1Tl = wt + 294912;
  ushort* Wcl2Th = wt + 327680;      ushort* Wcl2Tl = wt + 344064;
  ushort* Wg1Th  = wt + 360448;      ushort* Wg1Tl  = wt + 376832;
  ushort* Wg2Th  = wt + 393216;      ushort* Wg2Tl  = wt + 409600;
  ushort* We2h   = wt + 425984;      ushort* We2l   = wt + 950272;

  // ---- weight prep ----
  prep_kernel<<<8, 256, 0, stream>>>(Wp,   WpTh,   WpTl,   128, 128, 128);
  prep_kernel<<<8, 256, 0, stream>>>(be2,  be2Th,  be2Tl,  128, 128, 128);
  prep_kernel<<<24, 256, 0, stream>>>(Wih,  WihTh,  WihTl,  128, 128, 384);
  prep_kernel<<<24, 256, 0, stream>>>(Whh,  WhhTh,  WhhTl,  128, 128, 384);
  prep_kernel<<<16, 256, 0, stream>>>(Wcl1, Wcl1Th, Wcl1Tl, 256, 256, 128);
  prep_kernel<<<8, 256, 0, stream>>>(Wcl2, Wcl2Th, Wcl2Tl, 128, 128, 128);
  prep_kernel<<<8, 256, 0, stream>>>(Wg1,  Wg1Th,  Wg1Tl,  74,  128, 128);
  prep_kernel<<<8, 256, 0, stream>>>(Wg2,  Wg2Th,  Wg2Tl,  128, 128, 128);
  prep_we2_kernel<<<256, 256, 0, stream>>>(We2, We2h, We2l);

  // ---- fully-fused GraphConv ----
  adj_kernel<<<1024, 256, 0, stream>>>(src1, dst1, src2, dst2, Abuf);
  gconv_kernel<<<2048, 512, 0, stream>>>(h1, h2, Abuf, bg1, Wg1Th, Wg1Tl,
                                         Wg2Th, Wg2Tl, bg2, s1x, xcat);

  // ---- solvent-system MPNN + GRU + classifier ----
  gemm_mfma_kernel<1, 1, 0><<<dim3(64, 4), 128, 0, stream>>>(
      xcat, nullptr, WpTh, WpTl, bp, xp, 4096, 128, 128, 128);
  gemm_mfma_kernel<0, 0, 0><<<dim3(64, 4), 128, 0, stream>>>(
      xp, nullptr, be2Th, be2Tl, nullptr, zb, 4096, 128, 128, 128);
  hipMemsetAsync(aggA, 0, 2 * 262144 * sizeof(float), stream);
  zfold_mfma_kernel<<<256, 256, 0, stream>>>(xp, We2h, We2l, ihb, ia1, ia2,
                                             We1, be1, aggA, aggB);
  xin_kernel<<<1024, 256, 0, stream>>>(aggA, aggB, zb, bnn, x_in);
  gemm_mfma_kernel<0, 1, 0><<<dim3(64, 12), 128, 0, stream>>>(
      x_in, nullptr, WihTh, WihTl, bih, gi, 4096, 384, 128, 128);
  gemm_mfma_kernel<0, 1, 0><<<dim3(64, 12), 128, 0, stream>>>(
      xp, nullptr, WhhTh, WhhTl, bhh, gh, 4096, 384, 128, 128);
  gru_kernel<<<2048, 256, 0, stream>>>(gi, gh, xp, xnew);
  gemm_mfma_kernel<1, 1, 1><<<dim3(32, 4), 128, 0, stream>>>(
      xnew, xnew + (long)B2 * 128, Wcl1Th, Wcl1Tl, bcl1, o1, 2048, 128, 256, 128);
  gemm_mfma_kernel<1, 1, 0><<<dim3(32, 4), 128, 0, stream>>>(
      o1, nullptr, Wcl2Th, Wcl2Tl, bcl2, o2, 2048, 128, 128, 128);
  final_kernel<<<16, 256, 0, stream>>>(o2, Wcl3, bcl3, out);
}

// Round 12
// 225.657 us; speedup vs baseline: 4.0694x; 1.0206x over previous
//
#include <hip/hip_runtime.h>
#include <hip/hip_bf16.h>
#include <math.h>

#define B2    2048
#define NPM   30
#define EPM   120

typedef __attribute__((ext_vector_type(8))) short short8;
typedef __attribute__((ext_vector_type(4))) float f32x4;

__device__ __forceinline__ ushort f2bf(float x) {
  unsigned u = __float_as_uint(x);
  return (ushort)((u + 0x7FFFu + ((u >> 16) & 1u)) >> 16);
}
__device__ __forceinline__ float bf2f(ushort h) {
  return __uint_as_float(((unsigned)h) << 16);
}

// swizzled byte offsets: 128B rows (per-chunk tiles) and 256B rows (full-K A)
__device__ __forceinline__ int swz128(int r, int kb) { return r * 128 + (kb ^ ((r & 7) << 4)); }
__device__ __forceinline__ int swz256(int r, int kb) { return r * 256 + (kb ^ ((r & 15) << 4)); }

// ---------------------------------------------------------------------------
// prep: W[Kreal][N] fp32 -> transposed bf16 split hi/lo[N][Kpad] (zero-pad k).
// ---------------------------------------------------------------------------
__global__ __launch_bounds__(256) void prep_kernel(
    const float* __restrict__ W, ushort* __restrict__ hi, ushort* __restrict__ lo,
    int Kreal, int Kpad, int N)
{
  int idx = blockIdx.x * 256 + threadIdx.x;
  int tot = N * (Kpad >> 3);
  if (idx >= tot) return;
  int n = idx / (Kpad >> 3);
  int k8 = (idx - n * (Kpad >> 3)) << 3;
  #pragma unroll
  for (int j = 0; j < 8; ++j) {
    int k = k8 + j;
    float x = (k < Kreal) ? W[(long)k * N + n] : 0.f;
    ushort h = f2bf(x);
    hi[(long)n * Kpad + k] = h;
    lo[(long)n * Kpad + k] = f2bf(x - bf2f(h));
  }
}

// We2[32][128][128] -> per-k transposed bf16 split hi/lo[k][n][d]
__global__ __launch_bounds__(256) void prep_we2_kernel(
    const float* __restrict__ We2, ushort* __restrict__ hi, ushort* __restrict__ lo)
{
  int idx = blockIdx.x * 256 + threadIdx.x;   // 32*128*16 = 65536
  int k = idx >> 11;
  int rem = idx & 2047;
  int n = rem >> 4;
  int d8 = (rem & 15) << 3;
  #pragma unroll
  for (int j = 0; j < 8; ++j) {
    int d = d8 + j;
    float x = We2[k * 16384 + d * 128 + n];
    ushort h = f2bf(x);
    hi[k * 16384 + n * 128 + d] = h;
    lo[k * 16384 + n * 128 + d] = f2bf(x - bf2f(h));
  }
}

// ---------------------------------------------------------------------------
// MFMA GEMM, split-bf16, tile 64x32, 2 waves, swizzled LDS. (dense chain)
// ---------------------------------------------------------------------------
template<int RELU, int BIAS, int CAT>
__global__ __launch_bounds__(128) void gemm_mfma_kernel(
    const float* __restrict__ A, const float* __restrict__ A2,
    const ushort* __restrict__ Wh, const ushort* __restrict__ Wl,
    const float* __restrict__ bias, float* __restrict__ C,
    int M, int N, int K, int lda)
{
  __shared__ __align__(16) char AhB[8192], AlB[8192];
  __shared__ __align__(16) char BhB[4096], BlB[4096];
  const int tid = threadIdx.x;
  const int w = tid >> 6, l = tid & 63;
  const long rowBase = (long)blockIdx.x * 64;
  const int colBase = blockIdx.y * 32;

  f32x4 acc[2][2];
  #pragma unroll
  for (int fr = 0; fr < 2; ++fr)
    #pragma unroll
    for (int fc = 0; fc < 2; ++fc)
      acc[fr][fc] = (f32x4){0.f, 0.f, 0.f, 0.f};

  for (int k0 = 0; k0 < K; k0 += 64) {
    const float* Ab = (CAT && k0 >= 128) ? A2 : A;
    const int kc = CAT ? (k0 & 127) : k0;
    #pragma unroll
    for (int q = 0; q < 8; ++q) {
      int lin = tid + 128 * q;
      int r = lin >> 4, k4 = (lin & 15) << 2;
      float4 v = *(const float4*)&Ab[(rowBase + r) * lda + kc + k4];
      ushort4 h4, l4;
      h4.x = f2bf(v.x); l4.x = f2bf(v.x - bf2f(h4.x));
      h4.y = f2bf(v.y); l4.y = f2bf(v.y - bf2f(h4.y));
      h4.z = f2bf(v.z); l4.z = f2bf(v.z - bf2f(h4.z));
      h4.w = f2bf(v.w); l4.w = f2bf(v.w - bf2f(h4.w));
      *(ushort4*)(AhB + swz128(r, k4 * 2)) = h4;
      *(ushort4*)(AlB + swz128(r, k4 * 2)) = l4;
    }
    #pragma unroll
    for (int q = 0; q < 2; ++q) {
      int lin = tid + 128 * q;
      int n = lin >> 3, k8 = (lin & 7) << 3;
      *(uint4*)(BhB + swz128(n, k8 * 2)) = *(const uint4*)&Wh[(long)(colBase + n) * K + k0 + k8];
      *(uint4*)(BlB + swz128(n, k8 * 2)) = *(const uint4*)&Wl[(long)(colBase + n) * K + k0 + k8];
    }
    __syncthreads();
    #pragma unroll
    for (int ks = 0; ks < 2; ++ks) {
      const int ko = ks * 32 + (l >> 4) * 8;
      short8 ah[2], al8[2], bh[2], bl8[2];
      #pragma unroll
      for (int fr = 0; fr < 2; ++fr) {
        int r = w * 32 + fr * 16 + (l & 15);
        ah[fr]  = *(const short8*)(AhB + swz128(r, ko * 2));
        al8[fr] = *(const short8*)(AlB + swz128(r, ko * 2));
      }
      #pragma unroll
      for (int fc = 0; fc < 2; ++fc) {
        int c = fc * 16 + (l & 15);
        bh[fc]  = *(const short8*)(BhB + swz128(c, ko * 2));
        bl8[fc] = *(const short8*)(BlB + swz128(c, ko * 2));
      }
      #pragma unroll
      for (int fr = 0; fr < 2; ++fr)
        #pragma unroll
        for (int fc = 0; fc < 2; ++fc) {
          acc[fr][fc] = __builtin_amdgcn_mfma_f32_16x16x32_bf16(al8[fr], bh[fc], acc[fr][fc], 0, 0, 0);
          acc[fr][fc] = __builtin_amdgcn_mfma_f32_16x16x32_bf16(ah[fr], bl8[fc], acc[fr][fc], 0, 0, 0);
          acc[fr][fc] = __builtin_amdgcn_mfma_f32_16x16x32_bf16(ah[fr], bh[fc], acc[fr][fc], 0, 0, 0);
        }
    }
    __syncthreads();
  }
  #pragma unroll
  for (int fc = 0; fc < 2; ++fc) {
    int col = colBase + fc * 16 + (l & 15);
    float bv = BIAS ? bias[col] : 0.f;
    #pragma unroll
    for (int fr = 0; fr < 2; ++fr) {
      #pragma unroll
      for (int i = 0; i < 4; ++i) {
        long row = rowBase + w * 32 + fr * 16 + ((l >> 4) << 2) + i;
        float v = acc[fr][fc][i] + bv;
        if (RELU) v = fmaxf(v, 0.f);
        C[row * N + col] = v;
      }
    }
  }
}

// ---------------------------------------------------------------------------
// zfold via MFMA (validated round 8, unchanged).
// ---------------------------------------------------------------------------
__global__ __launch_bounds__(256, 1) void zfold_mfma_kernel(
    const float* __restrict__ xp,
    const ushort* __restrict__ We2h, const ushort* __restrict__ We2l,
    const float* __restrict__ interhb, const float* __restrict__ ia1,
    const float* __restrict__ ia2, const float* __restrict__ We1,
    const float* __restrict__ be1,
    float* __restrict__ aggA, float* __restrict__ aggB)
{
  __shared__ __align__(16) ushort Ah[2][64 * 72], Al[2][64 * 72];
  __shared__ __align__(16) ushort Bh[128 * 72], Bl[128 * 72];
  __shared__ float accAs[32 * 128], accBs[32 * 128];
  __shared__ float ehs[3][32][8];
  const int tid = threadIdx.x;
  const int w = tid >> 6, l = tid & 63;
  const int rg = blockIdx.x >> 2, kq = blockIdx.x & 3;
  const int i0 = rg * 32;

  for (int t = tid; t < 2048; t += 256) {
    int r = t >> 5, k4 = (t & 31) << 2;
    int gr = (r < 32) ? (i0 + r) : (B2 + i0 + r - 32);
    float4 v = *(const float4*)&xp[(long)gr * 128 + k4];
    int ch = k4 >> 6, ko = k4 & 63;
    ushort4 h4, l4;
    h4.x = f2bf(v.x); l4.x = f2bf(v.x - bf2f(h4.x));
    h4.y = f2bf(v.y); l4.y = f2bf(v.y - bf2f(h4.y));
    h4.z = f2bf(v.z); l4.z = f2bf(v.z - bf2f(h4.z));
    h4.w = f2bf(v.w); l4.w = f2bf(v.w - bf2f(h4.w));
    *(ushort4*)&Ah[ch][r * 72 + ko] = h4;
    *(ushort4*)&Al[ch][r * 72 + ko] = l4;
  }
  for (int t = tid; t < 768; t += 256) {
    int grp = t >> 8, rem = t & 255;
    int mm = rem >> 3, kk = rem & 7;
    int k = kq * 8 + kk;
    float u = (grp == 0) ? interhb[i0 + mm] : (grp == 1) ? ia1[i0 + mm] : ia2[i0 + mm];
    ehs[grp][mm][kk] = fmaxf(fmaf(u, We1[k], be1[k]), 0.f);
  }
  for (int t = tid; t < 4096; t += 256) { accAs[t] = 0.f; accBs[t] = 0.f; }

  float foldA[8][4] = {{0.f}}, foldB[8][4] = {{0.f}};
  const int ar = w * 16 + (l & 15);

  for (int kk = 0; kk < 8; ++kk) {
    const int k = kq * 8 + kk;
    f32x4 acc[8];
    #pragma unroll
    for (int fc = 0; fc < 8; ++fc) acc[fc] = (f32x4){0.f, 0.f, 0.f, 0.f};
    for (int ch = 0; ch < 2; ++ch) {
      __syncthreads();
      #pragma unroll
      for (int q = 0; q < 4; ++q) {
        int lin = tid + 256 * q;
        int n = lin >> 3, k8 = (lin & 7) << 3;
        *(uint4*)&Bh[n * 72 + k8] = *(const uint4*)&We2h[k * 16384 + n * 128 + ch * 64 + k8];
        *(uint4*)&Bl[n * 72 + k8] = *(const uint4*)&We2l[k * 16384 + n * 128 + ch * 64 + k8];
      }
      __syncthreads();
      #pragma unroll
      for (int ks = 0; ks < 2; ++ks) {
        const int ko = ks * 32 + (l >> 4) * 8;
        short8 ah  = *(const short8*)&Ah[ch][ar * 72 + ko];
        short8 al8 = *(const short8*)&Al[ch][ar * 72 + ko];
        #pragma unroll
        for (int fc = 0; fc < 8; ++fc) {
          const int c = fc * 16 + (l & 15);
          short8 bh  = *(const short8*)&Bh[c * 72 + ko];
          short8 bl8 = *(const short8*)&Bl[c * 72 + ko];
          acc[fc] = __builtin_amdgcn_mfma_f32_16x16x32_bf16(al8, bh, acc[fc], 0, 0, 0);
          acc[fc] = __builtin_amdgcn_mfma_f32_16x16x32_bf16(ah, bl8, acc[fc], 0, 0, 0);
          acc[fc] = __builtin_amdgcn_mfma_f32_16x16x32_bf16(ah, bh, acc[fc], 0, 0, 0);
        }
      }
    }
    #pragma unroll
    for (int i = 0; i < 4; ++i) {
      int lr = w * 16 + ((l >> 4) << 2) + i;
      int m = lr & 31, up = lr >> 5;
      float eA = up ? ehs[0][m][kk] : ehs[1][m][kk];
      float eB = up ? ehs[2][m][kk] : ehs[0][m][kk];
      #pragma unroll
      for (int fc = 0; fc < 8; ++fc) {
        foldA[fc][i] = fmaf(eA, acc[fc][i], foldA[fc][i]);
        foldB[fc][i] = fmaf(eB, acc[fc][i], foldB[fc][i]);
      }
    }
  }
  #pragma unroll
  for (int i = 0; i < 4; ++i) {
    int lr = w * 16 + ((l >> 4) << 2) + i;
    int m = lr & 31;
    #pragma unroll
    for (int fc = 0; fc < 8; ++fc) {
      int c = fc * 16 + (l & 15);
      atomicAdd(&accAs[m * 128 + c], foldA[fc][i]);
      atomicAdd(&accBs[m * 128 + c], foldB[fc][i]);
    }
  }
  __syncthreads();
  for (int t = tid; t < 4096; t += 256) {
    int mm = t >> 7, c = t & 127;
    atomicAdd(&aggA[(long)(i0 + mm) * 128 + c], accAs[t]);
    atomicAdd(&aggB[(long)(i0 + mm) * 128 + c], accBs[t]);
  }
}

// ---------------------------------------------------------------------------
// adj: normalized dense adjacency Â[d][s] = cnt(s->d)*rsI[d]*rsO[s].
// ---------------------------------------------------------------------------
__global__ __launch_bounds__(256) void adj_kernel(
    const int* __restrict__ src1, const int* __restrict__ dst1,
    const int* __restrict__ src2, const int* __restrict__ dst2,
    float* __restrict__ Abuf)
{
  __shared__ float cnt[4][30 * 33];
  __shared__ float rsOa[4][32], rsIa[4][32];
  const int tid = threadIdx.x, wid = tid >> 6, lane = tid & 63;
  const int gm = blockIdx.x * 4 + wid;
  const int g = gm >> 11, m = gm & 2047;
  const int* src = g ? src2 : src1;
  const int* dst = g ? dst2 : dst1;

  for (int i = lane; i < 30 * 33; i += 64) cnt[wid][i] = 0.f;
  __syncthreads();
  for (int e = lane; e < EPM; e += 64) {
    int s = src[m * EPM + e] - m * NPM;
    int d = dst[m * EPM + e] - m * NPM;
    atomicAdd(&cnt[wid][d * 33 + s], 1.0f);
  }
  __syncthreads();
  if (lane < NPM) {
    float sum = 0.f;
    for (int s = 0; s < NPM; ++s) sum += cnt[wid][lane * 33 + s];
    rsIa[wid][lane] = rsqrtf(fmaxf(sum, 1.f));
  } else if (lane >= 32 && lane < 32 + NPM) {
    int s = lane - 32; float sum = 0.f;
    for (int d = 0; d < NPM; ++d) sum += cnt[wid][d * 33 + s];
    rsOa[wid][s] = rsqrtf(fmaxf(sum, 1.f));
  }
  __syncthreads();
  const long base = (long)gm * 960;
  for (int i = lane; i < 960; i += 64) {
    int d = i >> 5, s = i & 31;
    float v = (d < NPM && s < NPM)
            ? cnt[wid][d * 33 + s] * rsIa[wid][d] * rsOa[wid][s] : 0.f;
    Abuf[base + i] = v;
  }
}

// ---------------------------------------------------------------------------
// FULLY-FUSED ALL-MFMA GraphConv, 512 threads (4 row-waves x 2 col-halves):
//   ph0: X -> swz A-tile; y1 = X@W1 [MFMA]
//   ph1: build Abig (64x64 block-diag bf16 split); y1 acc -> By B-tile
//   ph2: t1 = relu(Abig@By + b1) [MFMA] -> By
//   ph3: agg2 = Abig@By [MFMA]
//   ph4: acc -> A-tile; ph5: t2 = relu(A@W2+b2) [MFMA] + pool -> xcat
// ---------------------------------------------------------------------------
__global__ __launch_bounds__(512, 4) void gconv_kernel(
    const float* __restrict__ h1, const float* __restrict__ h2,
    const float* __restrict__ Abuf, const float* __restrict__ bg1,
    const ushort* __restrict__ W1h, const ushort* __restrict__ W1l,
    const ushort* __restrict__ W2h, const ushort* __restrict__ W2l,
    const float* __restrict__ bias2, const float* __restrict__ s1x,
    float* __restrict__ xcat)
{
  __shared__ __align__(16) char pool[66560];
  char* AhB = pool;              // A-tile hi (64 x 256B swz)  [ph0, ph4-5]
  char* AlB = pool + 16384;      // A-tile lo
  char* BhB = pool + 32768;      // B-tile hi (128 x 128B swz) [W1 ph0, W2 ph5]
  char* BlB = pool + 49152;      // B-tile lo
  char* A2h = pool;              // Abig hi (64 x 128B swz)    [ph1-3, alias AhB]
  char* A2l = pool + 8192;       // Abig lo
  char* Byh = pool + 32768;      // y1/t1 B-operand hi (128 x 128B) [ph1-3]
  char* Byl = pool + 49152;      // y1/t1 B-operand lo
  float* cs = (float*)(pool + 65536);  // [256]

  const int tid = threadIdx.x;
  const int p = blockIdx.x;
  const int g = p >> 10;
  const int mloc = (p & 1023) * 2;
  const float* hsrc = g ? h2 : h1;
  if (tid < 256) cs[tid] = 0.f;

  const int w8 = tid >> 6, l = tid & 63;
  const int rw = w8 & 3;                   // row-wave 0..3
  const int ch2 = w8 >> 2;                 // col-half 0/1
  const int ar = rw * 16 + (l & 15);
  const int crow = rw * 16 + ((l >> 4) << 2);   // C-row base (+i)

  // ---- ph0a: stage X (60x74 -> 64x128 pad) into swz256 bf16-split A ----
  #pragma unroll
  for (int q = 0; q < 4; ++q) {
    int lin = tid + 512 * q;
    int r = lin >> 5, k4 = (lin & 31) << 2;
    float4 v = make_float4(0.f, 0.f, 0.f, 0.f);
    if (r < 60) {
      const float* Ar = &hsrc[(long)(mloc * 30 + r) * 74];
      if (k4 + 4 <= 74) {
        float2 a = *(const float2*)&Ar[k4];
        float2 b = *(const float2*)&Ar[k4 + 2];
        v = make_float4(a.x, a.y, b.x, b.y);
      } else if (k4 + 2 <= 74) {
        float2 a = *(const float2*)&Ar[k4];
        v.x = a.x; v.y = a.y;
      }
    }
    ushort4 h4, l4;
    h4.x = f2bf(v.x); l4.x = f2bf(v.x - bf2f(h4.x));
    h4.y = f2bf(v.y); l4.y = f2bf(v.y - bf2f(h4.y));
    h4.z = f2bf(v.z); l4.z = f2bf(v.z - bf2f(h4.z));
    h4.w = f2bf(v.w); l4.w = f2bf(v.w - bf2f(h4.w));
    *(ushort4*)(AhB + swz256(r, k4 * 2)) = h4;
    *(ushort4*)(AlB + swz256(r, k4 * 2)) = l4;
  }
  __syncthreads();

  // ---- ph0b: y1 = X @ Wg1 (MFMA) ----
  f32x4 acc[4];
  #pragma unroll
  for (int fc = 0; fc < 4; ++fc) acc[fc] = (f32x4){0.f, 0.f, 0.f, 0.f};
  for (int k0 = 0; k0 < 128; k0 += 64) {
    #pragma unroll
    for (int q = 0; q < 2; ++q) {
      int lin = tid + 512 * q;
      int n = lin >> 3, k8 = (lin & 7) << 3;
      *(uint4*)(BhB + swz128(n, k8 * 2)) = *(const uint4*)&W1h[n * 128 + k0 + k8];
      *(uint4*)(BlB + swz128(n, k8 * 2)) = *(const uint4*)&W1l[n * 128 + k0 + k8];
    }
    __syncthreads();
    #pragma unroll
    for (int ks = 0; ks < 2; ++ks) {
      const int ko = ks * 32 + (l >> 4) * 8;
      short8 ah  = *(const short8*)(AhB + swz256(ar, (k0 + ko) * 2));
      short8 al8 = *(const short8*)(AlB + swz256(ar, (k0 + ko) * 2));
      #pragma unroll
      for (int fc = 0; fc < 4; ++fc) {
        const int c = ch2 * 64 + fc * 16 + (l & 15);
        short8 bh  = *(const short8*)(BhB + swz128(c, ko * 2));
        short8 bl8 = *(const short8*)(BlB + swz128(c, ko * 2));
        acc[fc] = __builtin_amdgcn_mfma_f32_16x16x32_bf16(al8, bh, acc[fc], 0, 0, 0);
        acc[fc] = __builtin_amdgcn_mfma_f32_16x16x32_bf16(ah, bl8, acc[fc], 0, 0, 0);
        acc[fc] = __builtin_amdgcn_mfma_f32_16x16x32_bf16(ah, bh, acc[fc], 0, 0, 0);
      }
    }
    __syncthreads();
  }

  // ---- ph1: build Abig bf16-split; y1 acc -> By B-tile [n][k=node] ----
  {
    const long ab0 = (long)(g * 2048 + mloc) * 960;
    for (int t = tid; t < 4096; t += 512) {
      int row = t >> 6, k = t & 63;
      float v = 0.f;
      if (row < 30) { if (k < 30) v = Abuf[ab0 + row * 32 + k]; }
      else if (row < 60) { if (k >= 30 && k < 60) v = Abuf[ab0 + 960 + (row - 30) * 32 + (k - 30)]; }
      ushort h = f2bf(v);
      *(ushort*)(A2h + swz128(row, k * 2)) = h;
      *(ushort*)(A2l + swz128(row, k * 2)) = f2bf(v - bf2f(h));
    }
  }
  #pragma unroll
  for (int fc = 0; fc < 4; ++fc) {
    int n = ch2 * 64 + fc * 16 + (l & 15);
    ushort4 h4, l4;
    h4.x = f2bf(acc[fc][0]); l4.x = f2bf(acc[fc][0] - bf2f(h4.x));
    h4.y = f2bf(acc[fc][1]); l4.y = f2bf(acc[fc][1] - bf2f(h4.y));
    h4.z = f2bf(acc[fc][2]); l4.z = f2bf(acc[fc][2] - bf2f(h4.z));
    h4.w = f2bf(acc[fc][3]); l4.w = f2bf(acc[fc][3] - bf2f(h4.w));
    *(ushort4*)(Byh + swz128(n, crow * 2)) = h4;
    *(ushort4*)(Byl + swz128(n, crow * 2)) = l4;
  }
  __syncthreads();

  // ---- ph2: t1 = relu(Abig@By + b1) (MFMA, K=64) ----
  f32x4 acc2[4];
  #pragma unroll
  for (int fc = 0; fc < 4; ++fc) acc2[fc] = (f32x4){0.f, 0.f, 0.f, 0.f};
  #pragma unroll
  for (int ks = 0; ks < 2; ++ks) {
    const int ko = ks * 32 + (l >> 4) * 8;
    short8 ah  = *(const short8*)(A2h + swz128(ar, ko * 2));
    short8 al8 = *(const short8*)(A2l + swz128(ar, ko * 2));
    #pragma unroll
    for (int fc = 0; fc < 4; ++fc) {
      const int c = ch2 * 64 + fc * 16 + (l & 15);
      short8 bh  = *(const short8*)(Byh + swz128(c, ko * 2));
      short8 bl8 = *(const short8*)(Byl + swz128(c, ko * 2));
      acc2[fc] = __builtin_amdgcn_mfma_f32_16x16x32_bf16(al8, bh, acc2[fc], 0, 0, 0);
      acc2[fc] = __builtin_amdgcn_mfma_f32_16x16x32_bf16(ah, bl8, acc2[fc], 0, 0, 0);
      acc2[fc] = __builtin_amdgcn_mfma_f32_16x16x32_bf16(ah, bh, acc2[fc], 0, 0, 0);
    }
  }
  __syncthreads();

  // ---- ph2b: bias+relu -> t1, write back into By ----
  #pragma unroll
  for (int fc = 0; fc < 4; ++fc) {
    int n = ch2 * 64 + fc * 16 + (l & 15);
    float bv = bg1[n];
    float t0 = fmaxf(acc2[fc][0] + bv, 0.f);
    float t1v = fmaxf(acc2[fc][1] + bv, 0.f);
    float t2v = fmaxf(acc2[fc][2] + bv, 0.f);
    float t3 = fmaxf(acc2[fc][3] + bv, 0.f);
    ushort4 h4, l4;
    h4.x = f2bf(t0); l4.x = f2bf(t0 - bf2f(h4.x));
    h4.y = f2bf(t1v); l4.y = f2bf(t1v - bf2f(h4.y));
    h4.z = f2bf(t2v); l4.z = f2bf(t2v - bf2f(h4.z));
    h4.w = f2bf(t3); l4.w = f2bf(t3 - bf2f(h4.w));
    *(ushort4*)(Byh + swz128(n, crow * 2)) = h4;
    *(ushort4*)(Byl + swz128(n, crow * 2)) = l4;
  }
  __syncthreads();

  // ---- ph3: agg2 = Abig@By (MFMA, K=64) ----
  #pragma unroll
  for (int fc = 0; fc < 4; ++fc) acc2[fc] = (f32x4){0.f, 0.f, 0.f, 0.f};
  #pragma unroll
  for (int ks = 0; ks < 2; ++ks) {
    const int ko = ks * 32 + (l >> 4) * 8;
    short8 ah  = *(const short8*)(A2h + swz128(ar, ko * 2));
    short8 al8 = *(const short8*)(A2l + swz128(ar, ko * 2));
    #pragma unroll
    for (int fc = 0; fc < 4; ++fc) {
      const int c = ch2 * 64 + fc * 16 + (l & 15);
      short8 bh  = *(const short8*)(Byh + swz128(c, ko * 2));
      short8 bl8 = *(const short8*)(Byl + swz128(c, ko * 2));
      acc2[fc] = __builtin_amdgcn_mfma_f32_16x16x32_bf16(al8, bh, acc2[fc], 0, 0, 0);
      acc2[fc] = __builtin_amdgcn_mfma_f32_16x16x32_bf16(ah, bl8, acc2[fc], 0, 0, 0);
      acc2[fc] = __builtin_amdgcn_mfma_f32_16x16x32_bf16(ah, bh, acc2[fc], 0, 0, 0);
    }
  }
  __syncthreads();

  // ---- ph4: agg2 acc -> swz256 bf16-split A-tile (rows 60-63 are zeros) ----
  #pragma unroll
  for (int fc = 0; fc < 4; ++fc) {
    int n = ch2 * 64 + fc * 16 + (l & 15);
    #pragma unroll
    for (int i = 0; i < 4; ++i) {
      int r = crow + i;
      ushort h = f2bf(acc2[fc][i]);
      *(ushort*)(AhB + swz256(r, n * 2)) = h;
      *(ushort*)(AlB + swz256(r, n * 2)) = f2bf(acc2[fc][i] - bf2f(h));
    }
  }

  // ---- ph5: t2 = relu(A@W2 + b2) (MFMA) + pool ----
  #pragma unroll
  for (int fc = 0; fc < 4; ++fc) acc[fc] = (f32x4){0.f, 0.f, 0.f, 0.f};
  for (int k0 = 0; k0 < 128; k0 += 64) {
    __syncthreads();
    #pragma unroll
    for (int q = 0; q < 2; ++q) {
      int lin = tid + 512 * q;
      int n = lin >> 3, k8 = (lin & 7) << 3;
      *(uint4*)(BhB + swz128(n, k8 * 2)) = *(const uint4*)&W2h[n * 128 + k0 + k8];
      *(uint4*)(BlB + swz128(n, k8 * 2)) = *(const uint4*)&W2l[n * 128 + k0 + k8];
    }
    __syncthreads();
    #pragma unroll
    for (int ks = 0; ks < 2; ++ks) {
      const int ko = ks * 32 + (l >> 4) * 8;
      short8 ah  = *(const short8*)(AhB + swz256(ar, (k0 + ko) * 2));
      short8 al8 = *(const short8*)(AlB + swz256(ar, (k0 + ko) * 2));
      #pragma unroll
      for (int fc = 0; fc < 4; ++fc) {
        const int c = ch2 * 64 + fc * 16 + (l & 15);
        short8 bh  = *(const short8*)(BhB + swz128(c, ko * 2));
        short8 bl8 = *(const short8*)(BlB + swz128(c, ko * 2));
        acc[fc] = __builtin_amdgcn_mfma_f32_16x16x32_bf16(al8, bh, acc[fc], 0, 0, 0);
        acc[fc] = __builtin_amdgcn_mfma_f32_16x16x32_bf16(ah, bl8, acc[fc], 0, 0, 0);
        acc[fc] = __builtin_amdgcn_mfma_f32_16x16x32_bf16(ah, bh, acc[fc], 0, 0, 0);
      }
    }
  }
  __syncthreads();

  // pool epilogue
  #pragma unroll
  for (int fc = 0; fc < 4; ++fc) {
    int col = ch2 * 64 + fc * 16 + (l & 15);
    float bv = bias2[col];
    float s0 = 0.f, s1 = 0.f;
    #pragma unroll
    for (int i = 0; i < 4; ++i) {
      int lr = crow + i;
      if (lr < 60) {
        float v = fmaxf(acc[fc][i] + bv, 0.f);
        if (lr < NPM) s0 += v; else s1 += v;
      }
    }
    s0 += __shfl_down(s0, 32); s0 += __shfl_down(s0, 16);
    s1 += __shfl_down(s1, 32); s1 += __shfl_down(s1, 16);
    if ((l >> 4) == 0) {
      atomicAdd(&cs[col], s0);
      atomicAdd(&cs[128 + col], s1);
    }
  }
  __syncthreads();
  if (tid < 256) {
    int moll = tid >> 7, c = tid & 127;
    int gm = p * 2 + moll;
    int gg = gm >> 11, mm = gm & 2047;
    float sf = gg ? (1.f - s1x[mm]) : s1x[mm];
    xcat[(long)gm * 128 + c] = cs[moll * 128 + c] * (1.f / 30.f) * sf;
  }
}

__global__ __launch_bounds__(256) void xin_kernel(
    const float* __restrict__ aggA, const float* __restrict__ aggB,
    const float* __restrict__ zb, const float* __restrict__ bnn,
    float* __restrict__ x_in)
{
  int idx = blockIdx.x * 256 + threadIdx.x;
  int i = idx >> 7, c = idx & 127;
  float zs = zb[i * 128 + c] + zb[(i + B2) * 128 + c] + bnn[c];
  x_in[i * 128 + c]        = fmaxf(aggA[idx] + zs, 0.f);
  x_in[(i + B2) * 128 + c] = fmaxf(aggB[idx] + zs, 0.f);
}

__global__ __launch_bounds__(256) void gru_kernel(
    const float* __restrict__ gi, const float* __restrict__ gh,
    const float* __restrict__ xp, float* __restrict__ xnew)
{
  int idx = blockIdx.x * 256 + threadIdx.x;
  int n = idx >> 7, j = idx & 127;
  float ir = gi[n * 384 + j], iz = gi[n * 384 + 128 + j], ih = gi[n * 384 + 256 + j];
  float hr = gh[n * 384 + j], hz = gh[n * 384 + 128 + j], hn = gh[n * 384 + 256 + j];
  float h  = xp[idx];
  float r  = 1.f / (1.f + expf(-(ir + hr)));
  float zg = 1.f / (1.f + expf(-(iz + hz)));
  float ng = tanhf(ih + r * hn);
  xnew[idx] = (1.f - zg) * ng + zg * h;
}

__global__ __launch_bounds__(256) void final_kernel(
    const float* __restrict__ o2, const float* __restrict__ Wcl3,
    const float* __restrict__ bcl3, float* __restrict__ out)
{
  int idx = blockIdx.x * 256 + threadIdx.x;
  int i = idx >> 1, c = idx & 1;
  float acc = bcl3[c];
  for (int k = 0; k < 128; ++k) acc = fmaf(o2[i * 128 + k], Wcl3[k * 2 + c], acc);
  out[idx] = acc;
}

// ---------------------------------------------------------------------------
extern "C" void kernel_launch(void* const* d_in, const int* in_sizes, int n_in,
                              void* d_out, int out_size, void* d_ws, size_t ws_size,
                              hipStream_t stream)
{
  const float* h1   = (const float*)d_in[0];
  const float* h2   = (const float*)d_in[1];
  const float* s1x  = (const float*)d_in[2];
  const float* ihb  = (const float*)d_in[3];
  const float* ia1  = (const float*)d_in[4];
  const float* ia2  = (const float*)d_in[5];
  const float* Wg1  = (const float*)d_in[6];
  const float* bg1  = (const float*)d_in[7];
  const float* Wg2  = (const float*)d_in[8];
  const float* bg2  = (const float*)d_in[9];
  const float* Wp   = (const float*)d_in[10];
  const float* bp   = (const float*)d_in[11];
  const float* We1  = (const float*)d_in[12];
  const float* be1  = (const float*)d_in[13];
  const float* We2  = (const float*)d_in[14];
  const float* be2  = (const float*)d_in[15];
  const float* bnn  = (const float*)d_in[16];
  const float* Wih  = (const float*)d_in[17];
  const float* bih  = (const float*)d_in[18];
  const float* Whh  = (const float*)d_in[19];
  const float* bhh  = (const float*)d_in[20];
  const float* Wcl1 = (const float*)d_in[21];
  const float* bcl1 = (const float*)d_in[22];
  const float* Wcl2 = (const float*)d_in[23];
  const float* bcl2 = (const float*)d_in[24];
  const float* Wcl3 = (const float*)d_in[25];
  const float* bcl3 = (const float*)d_in[26];
  const int*   src1 = (const int*)d_in[27];
  const int*   dst1 = (const int*)d_in[28];
  const int*   src2 = (const int*)d_in[29];
  const int*   dst2 = (const int*)d_in[30];
  float* out = (float*)d_out;
  float* ws  = (float*)d_ws;

  float* Abuf = ws;                          // 3,932,160
  float* dwn  = ws + 35389440;

  float* xcat = dwn;
  float* xp   = dwn + 524288;
  float* zb   = dwn + 1048576;
  float* aggA = dwn + 1572864;
  float* aggB = dwn + 1835008;
  float* x_in = dwn + 2097152;
  float* gi   = dwn + 2621440;
  float* gh   = dwn + 4194304;
  float* xnew = dwn + 5767168;
  float* o1   = dwn + 6291456;
  float* o2   = dwn + 6553600;

  ushort* wt     = (ushort*)(dwn + 6815744);
  ushort* WpTh   = wt;               ushort* WpTl   = wt + 16384;
  ushort* be2Th  = wt + 32768;       ushort* be2Tl  = wt + 49152;
  ushort* WihTh  = wt + 65536;       ushort* WihTl  = wt + 114688;
  ushort* WhhTh  = wt + 163840;      ushort* WhhTl  = wt + 212992;
  ushort* Wcl1Th = wt + 262144;      ushort* Wcl1Tl = wt + 294912;
  ushort* Wcl2Th = wt + 327680;      ushort* Wcl2Tl = wt + 344064;
  ushort* Wg1Th  = wt + 360448;      ushort* Wg1Tl  = wt + 376832;
  ushort* Wg2Th  = wt + 393216;      ushort* Wg2Tl  = wt + 409600;
  ushort* We2h   = wt + 425984;      ushort* We2l   = wt + 950272;

  // ---- weight prep ----
  prep_kernel<<<8, 256, 0, stream>>>(Wp,   WpTh,   WpTl,   128, 128, 128);
  prep_kernel<<<8, 256, 0, stream>>>(be2,  be2Th,  be2Tl,  128, 128, 128);
  prep_kernel<<<24, 256, 0, stream>>>(Wih,  WihTh,  WihTl,  128, 128, 384);
  prep_kernel<<<24, 256, 0, stream>>>(Whh,  WhhTh,  WhhTl,  128, 128, 384);
  prep_kernel<<<16, 256, 0, stream>>>(Wcl1, Wcl1Th, Wcl1Tl, 256, 256, 128);
  prep_kernel<<<8, 256, 0, stream>>>(Wcl2, Wcl2Th, Wcl2Tl, 128, 128, 128);
  prep_kernel<<<8, 256, 0, stream>>>(Wg1,  Wg1Th,  Wg1Tl,  74,  128, 128);
  prep_kernel<<<8, 256, 0, stream>>>(Wg2,  Wg2Th,  Wg2Tl,  128, 128, 128);
  prep_we2_kernel<<<256, 256, 0, stream>>>(We2, We2h, We2l);

  // ---- fully-fused GraphConv ----
  adj_kernel<<<1024, 256, 0, stream>>>(src1, dst1, src2, dst2, Abuf);
  gconv_kernel<<<2048, 512, 0, stream>>>(h1, h2, Abuf, bg1, Wg1Th, Wg1Tl,
                                         Wg2Th, Wg2Tl, bg2, s1x, xcat);

  // ---- solvent-system MPNN + GRU + classifier ----
  gemm_mfma_kernel<1, 1, 0><<<dim3(64, 4), 128, 0, stream>>>(
      xcat, nullptr, WpTh, WpTl, bp, xp, 4096, 128, 128, 128);
  gemm_mfma_kernel<0, 0, 0><<<dim3(64, 4), 128, 0, stream>>>(
      xp, nullptr, be2Th, be2Tl, nullptr, zb, 4096, 128, 128, 128);
  hipMemsetAsync(aggA, 0, 2 * 262144 * sizeof(float), stream);
  zfold_mfma_kernel<<<256, 256, 0, stream>>>(xp, We2h, We2l, ihb, ia1, ia2,
                                             We1, be1, aggA, aggB);
  xin_kernel<<<1024, 256, 0, stream>>>(aggA, aggB, zb, bnn, x_in);
  gemm_mfma_kernel<0, 1, 0><<<dim3(64, 12), 128, 0, stream>>>(
      x_in, nullptr, WihTh, WihTl, bih, gi, 4096, 384, 128, 128);
  gemm_mfma_kernel<0, 1, 0><<<dim3(64, 12), 128, 0, stream>>>(
      xp, nullptr, WhhTh, WhhTl, bhh, gh, 4096, 384, 128, 128);
  gru_kernel<<<2048, 256, 0, stream>>>(gi, gh, xp, xnew);
  gemm_mfma_kernel<1, 1, 1><<<dim3(32, 4), 128, 0, stream>>>(
      xnew, xnew + (long)B2 * 128, Wcl1Th, Wcl1Tl, bcl1, o1, 2048, 128, 256, 128);
  gemm_mfma_kernel<1, 1, 0><<<dim3(32, 4), 128, 0, stream>>>(
      o1, nullptr, Wcl2Th, Wcl2Tl, bcl2, o2, 2048, 128, 128, 128);
  final_kernel<<<16, 256, 0, stream>>>(o2, Wcl3, bcl3, out);
}

// Round 13
// 188.853 us; speedup vs baseline: 4.8625x; 1.1949x over previous
//
#include <hip/hip_runtime.h>
#include <hip/hip_bf16.h>
#include <math.h>

#define B2    2048
#define NPM   30
#define EPM   120

typedef __attribute__((ext_vector_type(8))) short short8;
typedef __attribute__((ext_vector_type(4))) float f32x4;

__device__ __forceinline__ ushort f2bf(float x) {
  unsigned u = __float_as_uint(x);
  return (ushort)((u + 0x7FFFu + ((u >> 16) & 1u)) >> 16);
}
__device__ __forceinline__ float bf2f(ushort h) {
  return __uint_as_float(((unsigned)h) << 16);
}

// swizzled byte offsets: 128B rows (per-chunk tiles) and 256B rows (full-K A)
__device__ __forceinline__ int swz128(int r, int kb) { return r * 128 + (kb ^ ((r & 7) << 4)); }
__device__ __forceinline__ int swz256(int r, int kb) { return r * 256 + (kb ^ ((r & 15) << 4)); }

// ---------------------------------------------------------------------------
// prep_all: 8 weight preps in one launch. W[Kreal][N] -> bf16 split [N][Kpad].
// ---------------------------------------------------------------------------
struct PrepDescs {
  const float* W[8];
  ushort* hi[8];
  ushort* lo[8];
  int Kreal[8], Kpad[8], N[8];
  int blk0[9];
};

__global__ __launch_bounds__(256) void prep_all_kernel(PrepDescs d)
{
  int b = blockIdx.x;
  int di = 0;
  #pragma unroll
  for (int j = 1; j < 8; ++j) if (b >= d.blk0[j]) di = j;
  int idx = (b - d.blk0[di]) * 256 + threadIdx.x;
  int Kp8 = d.Kpad[di] >> 3;
  int tot = d.N[di] * Kp8;
  if (idx >= tot) return;
  int n = idx / Kp8;
  int k8 = (idx - n * Kp8) << 3;
  const float* W = d.W[di];
  ushort* hi = d.hi[di];
  ushort* lo = d.lo[di];
  int Kreal = d.Kreal[di], Kpad = d.Kpad[di], N = d.N[di];
  #pragma unroll
  for (int j = 0; j < 8; ++j) {
    int k = k8 + j;
    float x = (k < Kreal) ? W[(long)k * N + n] : 0.f;
    ushort h = f2bf(x);
    hi[(long)n * Kpad + k] = h;
    lo[(long)n * Kpad + k] = f2bf(x - bf2f(h));
  }
}

// We2[32][128][128] -> per-k transposed bf16 split hi/lo[k][n][d]
__global__ __launch_bounds__(256) void prep_we2_kernel(
    const float* __restrict__ We2, ushort* __restrict__ hi, ushort* __restrict__ lo)
{
  int idx = blockIdx.x * 256 + threadIdx.x;
  int k = idx >> 11;
  int rem = idx & 2047;
  int n = rem >> 4;
  int d8 = (rem & 15) << 3;
  #pragma unroll
  for (int j = 0; j < 8; ++j) {
    int d = d8 + j;
    float x = We2[k * 16384 + d * 128 + n];
    ushort h = f2bf(x);
    hi[k * 16384 + n * 128 + d] = h;
    lo[k * 16384 + n * 128 + d] = f2bf(x - bf2f(h));
  }
}

// ---------------------------------------------------------------------------
// MFMA GEMM, split-bf16, tile 64x32, 2 waves, swizzled LDS. (gi / gh)
// ---------------------------------------------------------------------------
template<int RELU, int BIAS>
__global__ __launch_bounds__(128) void gemm_mfma_kernel(
    const float* __restrict__ A,
    const ushort* __restrict__ Wh, const ushort* __restrict__ Wl,
    const float* __restrict__ bias, float* __restrict__ C,
    int N, int K, int lda)
{
  __shared__ __align__(16) char AhB[8192], AlB[8192];
  __shared__ __align__(16) char BhB[4096], BlB[4096];
  const int tid = threadIdx.x;
  const int w = tid >> 6, l = tid & 63;
  const long rowBase = (long)blockIdx.x * 64;
  const int colBase = blockIdx.y * 32;

  f32x4 acc[2][2];
  #pragma unroll
  for (int fr = 0; fr < 2; ++fr)
    #pragma unroll
    for (int fc = 0; fc < 2; ++fc)
      acc[fr][fc] = (f32x4){0.f, 0.f, 0.f, 0.f};

  for (int k0 = 0; k0 < K; k0 += 64) {
    #pragma unroll
    for (int q = 0; q < 8; ++q) {
      int lin = tid + 128 * q;
      int r = lin >> 4, k4 = (lin & 15) << 2;
      float4 v = *(const float4*)&A[(rowBase + r) * lda + k0 + k4];
      ushort4 h4, l4;
      h4.x = f2bf(v.x); l4.x = f2bf(v.x - bf2f(h4.x));
      h4.y = f2bf(v.y); l4.y = f2bf(v.y - bf2f(h4.y));
      h4.z = f2bf(v.z); l4.z = f2bf(v.z - bf2f(h4.z));
      h4.w = f2bf(v.w); l4.w = f2bf(v.w - bf2f(h4.w));
      *(ushort4*)(AhB + swz128(r, k4 * 2)) = h4;
      *(ushort4*)(AlB + swz128(r, k4 * 2)) = l4;
    }
    #pragma unroll
    for (int q = 0; q < 2; ++q) {
      int lin = tid + 128 * q;
      int n = lin >> 3, k8 = (lin & 7) << 3;
      *(uint4*)(BhB + swz128(n, k8 * 2)) = *(const uint4*)&Wh[(long)(colBase + n) * K + k0 + k8];
      *(uint4*)(BlB + swz128(n, k8 * 2)) = *(const uint4*)&Wl[(long)(colBase + n) * K + k0 + k8];
    }
    __syncthreads();
    #pragma unroll
    for (int ks = 0; ks < 2; ++ks) {
      const int ko = ks * 32 + (l >> 4) * 8;
      short8 ah[2], al8[2], bh[2], bl8[2];
      #pragma unroll
      for (int fr = 0; fr < 2; ++fr) {
        int r = w * 32 + fr * 16 + (l & 15);
        ah[fr]  = *(const short8*)(AhB + swz128(r, ko * 2));
        al8[fr] = *(const short8*)(AlB + swz128(r, ko * 2));
      }
      #pragma unroll
      for (int fc = 0; fc < 2; ++fc) {
        int c = fc * 16 + (l & 15);
        bh[fc]  = *(const short8*)(BhB + swz128(c, ko * 2));
        bl8[fc] = *(const short8*)(BlB + swz128(c, ko * 2));
      }
      #pragma unroll
      for (int fr = 0; fr < 2; ++fr)
        #pragma unroll
        for (int fc = 0; fc < 2; ++fc) {
          acc[fr][fc] = __builtin_amdgcn_mfma_f32_16x16x32_bf16(al8[fr], bh[fc], acc[fr][fc], 0, 0, 0);
          acc[fr][fc] = __builtin_amdgcn_mfma_f32_16x16x32_bf16(ah[fr], bl8[fc], acc[fr][fc], 0, 0, 0);
          acc[fr][fc] = __builtin_amdgcn_mfma_f32_16x16x32_bf16(ah[fr], bh[fc], acc[fr][fc], 0, 0, 0);
        }
    }
    __syncthreads();
  }
  #pragma unroll
  for (int fc = 0; fc < 2; ++fc) {
    int col = colBase + fc * 16 + (l & 15);
    float bv = BIAS ? bias[col] : 0.f;
    #pragma unroll
    for (int fr = 0; fr < 2; ++fr) {
      #pragma unroll
      for (int i = 0; i < 4; ++i) {
        long row = rowBase + w * 32 + fr * 16 + ((l >> 4) << 2) + i;
        float v = acc[fr][fc][i] + bv;
        if (RELU) v = fmaxf(v, 0.f);
        C[row * N + col] = v;
      }
    }
  }
}

// ---------------------------------------------------------------------------
// xpzb: xp = relu(xcat@Wp+bp); zb = xp@be2 (xp kept in LDS, no re-read).
// 256 threads = 4 row-waves x 16 rows, 8 fc (full N=128). grid = 64.
// ---------------------------------------------------------------------------
__global__ __launch_bounds__(256) void xpzb_kernel(
    const float* __restrict__ xcat,
    const ushort* __restrict__ Wph, const ushort* __restrict__ Wpl,
    const float* __restrict__ bp,
    const ushort* __restrict__ be2h, const ushort* __restrict__ be2l,
    float* __restrict__ xp, float* __restrict__ zb)
{
  __shared__ __align__(16) char AhB[16384], AlB[16384];  // 64 x 256B swz
  __shared__ __align__(16) char BhB[16384], BlB[16384];  // 128 x 128B swz
  const int tid = threadIdx.x;
  const int w = tid >> 6, l = tid & 63;
  const long rowBase = (long)blockIdx.x * 64;
  const int ar = w * 16 + (l & 15);
  const int crow = w * 16 + ((l >> 4) << 2);

  // stage xcat full-K A-tile
  #pragma unroll
  for (int q = 0; q < 8; ++q) {
    int t = tid + 256 * q;                  // 0..2047
    int r = t >> 5, k4 = (t & 31) << 2;
    float4 v = *(const float4*)&xcat[(rowBase + r) * 128 + k4];
    ushort4 h4, l4;
    h4.x = f2bf(v.x); l4.x = f2bf(v.x - bf2f(h4.x));
    h4.y = f2bf(v.y); l4.y = f2bf(v.y - bf2f(h4.y));
    h4.z = f2bf(v.z); l4.z = f2bf(v.z - bf2f(h4.z));
    h4.w = f2bf(v.w); l4.w = f2bf(v.w - bf2f(h4.w));
    *(ushort4*)(AhB + swz256(r, k4 * 2)) = h4;
    *(ushort4*)(AlB + swz256(r, k4 * 2)) = l4;
  }
  __syncthreads();

  // GEMM1: xp = relu(xcat @ Wp + bp)
  f32x4 acc[8];
  #pragma unroll
  for (int fc = 0; fc < 8; ++fc) acc[fc] = (f32x4){0.f, 0.f, 0.f, 0.f};
  for (int k0 = 0; k0 < 128; k0 += 64) {
    #pragma unroll
    for (int q = 0; q < 4; ++q) {
      int lin = tid + 256 * q;
      int n = lin >> 3, k8 = (lin & 7) << 3;
      *(uint4*)(BhB + swz128(n, k8 * 2)) = *(const uint4*)&Wph[n * 128 + k0 + k8];
      *(uint4*)(BlB + swz128(n, k8 * 2)) = *(const uint4*)&Wpl[n * 128 + k0 + k8];
    }
    __syncthreads();
    #pragma unroll
    for (int ks = 0; ks < 2; ++ks) {
      const int ko = ks * 32 + (l >> 4) * 8;
      short8 ah  = *(const short8*)(AhB + swz256(ar, (k0 + ko) * 2));
      short8 al8 = *(const short8*)(AlB + swz256(ar, (k0 + ko) * 2));
      #pragma unroll
      for (int fc = 0; fc < 8; ++fc) {
        const int c = fc * 16 + (l & 15);
        short8 bh  = *(const short8*)(BhB + swz128(c, ko * 2));
        short8 bl8 = *(const short8*)(BlB + swz128(c, ko * 2));
        acc[fc] = __builtin_amdgcn_mfma_f32_16x16x32_bf16(al8, bh, acc[fc], 0, 0, 0);
        acc[fc] = __builtin_amdgcn_mfma_f32_16x16x32_bf16(ah, bl8, acc[fc], 0, 0, 0);
        acc[fc] = __builtin_amdgcn_mfma_f32_16x16x32_bf16(ah, bh, acc[fc], 0, 0, 0);
      }
    }
    __syncthreads();
  }

  // epilogue: write xp; overwrite A-tile with bf16-split xp
  #pragma unroll
  for (int fc = 0; fc < 8; ++fc) {
    int col = fc * 16 + (l & 15);
    float bv = bp[col];
    #pragma unroll
    for (int i = 0; i < 4; ++i) {
      int lr = crow + i;
      float v = fmaxf(acc[fc][i] + bv, 0.f);
      xp[(rowBase + lr) * 128 + col] = v;
      ushort h = f2bf(v);
      *(ushort*)(AhB + swz256(lr, col * 2)) = h;
      *(ushort*)(AlB + swz256(lr, col * 2)) = f2bf(v - bf2f(h));
    }
  }

  // GEMM2: zb = xp @ be2
  #pragma unroll
  for (int fc = 0; fc < 8; ++fc) acc[fc] = (f32x4){0.f, 0.f, 0.f, 0.f};
  for (int k0 = 0; k0 < 128; k0 += 64) {
    __syncthreads();
    #pragma unroll
    for (int q = 0; q < 4; ++q) {
      int lin = tid + 256 * q;
      int n = lin >> 3, k8 = (lin & 7) << 3;
      *(uint4*)(BhB + swz128(n, k8 * 2)) = *(const uint4*)&be2h[n * 128 + k0 + k8];
      *(uint4*)(BlB + swz128(n, k8 * 2)) = *(const uint4*)&be2l[n * 128 + k0 + k8];
    }
    __syncthreads();
    #pragma unroll
    for (int ks = 0; ks < 2; ++ks) {
      const int ko = ks * 32 + (l >> 4) * 8;
      short8 ah  = *(const short8*)(AhB + swz256(ar, (k0 + ko) * 2));
      short8 al8 = *(const short8*)(AlB + swz256(ar, (k0 + ko) * 2));
      #pragma unroll
      for (int fc = 0; fc < 8; ++fc) {
        const int c = fc * 16 + (l & 15);
        short8 bh  = *(const short8*)(BhB + swz128(c, ko * 2));
        short8 bl8 = *(const short8*)(BlB + swz128(c, ko * 2));
        acc[fc] = __builtin_amdgcn_mfma_f32_16x16x32_bf16(al8, bh, acc[fc], 0, 0, 0);
        acc[fc] = __builtin_amdgcn_mfma_f32_16x16x32_bf16(ah, bl8, acc[fc], 0, 0, 0);
        acc[fc] = __builtin_amdgcn_mfma_f32_16x16x32_bf16(ah, bh, acc[fc], 0, 0, 0);
      }
    }
  }
  #pragma unroll
  for (int fc = 0; fc < 8; ++fc) {
    int col = fc * 16 + (l & 15);
    #pragma unroll
    for (int i = 0; i < 4; ++i) {
      int lr = crow + i;
      zb[(rowBase + lr) * 128 + col] = acc[fc][i];
    }
  }
}

// ---------------------------------------------------------------------------
// cls: o1 = relu([xnew_lo|xnew_hi]@Wcl1+b1); o2 = relu(o1@Wcl2+b2);
//      out = o2@Wcl3 + bcl3 (N=2, shfl-reduced). grid = 32, 256 threads.
// ---------------------------------------------------------------------------
__global__ __launch_bounds__(256) void cls_kernel(
    const float* __restrict__ xnew,
    const ushort* __restrict__ W1h, const ushort* __restrict__ W1l,
    const float* __restrict__ b1,
    const ushort* __restrict__ W2h, const ushort* __restrict__ W2l,
    const float* __restrict__ b2,
    const float* __restrict__ Wcl3, const float* __restrict__ bcl3,
    float* __restrict__ out)
{
  __shared__ __align__(16) char O1h[16384], O1l[16384];  // o1 64 x 256B swz
  __shared__ __align__(16) char AhB[8192], AlB[8192];    // phase-1 A chunks
  __shared__ __align__(16) char BhB[16384], BlB[16384];  // B chunks 128 x 128B
  const int tid = threadIdx.x;
  const int w = tid >> 6, l = tid & 63;
  const long rowBase = (long)blockIdx.x * 64;
  const int ar = w * 16 + (l & 15);
  const int crow = w * 16 + ((l >> 4) << 2);

  // phase 1: o1 = relu(hg @ Wcl1 + b1), K=256 (hg = [xnew | xnew+B2*128])
  f32x4 acc[8];
  #pragma unroll
  for (int fc = 0; fc < 8; ++fc) acc[fc] = (f32x4){0.f, 0.f, 0.f, 0.f};
  for (int k0 = 0; k0 < 256; k0 += 64) {
    const float* Ab = (k0 < 128) ? xnew : (xnew + (long)B2 * 128);
    const int kc = k0 & 127;
    #pragma unroll
    for (int q = 0; q < 4; ++q) {
      int lin = tid + 256 * q;
      int r = lin >> 4, k4 = (lin & 15) << 2;
      float4 v = *(const float4*)&Ab[(rowBase + r) * 128 + kc + k4];
      ushort4 h4, l4;
      h4.x = f2bf(v.x); l4.x = f2bf(v.x - bf2f(h4.x));
      h4.y = f2bf(v.y); l4.y = f2bf(v.y - bf2f(h4.y));
      h4.z = f2bf(v.z); l4.z = f2bf(v.z - bf2f(h4.z));
      h4.w = f2bf(v.w); l4.w = f2bf(v.w - bf2f(h4.w));
      *(ushort4*)(AhB + swz128(r, k4 * 2)) = h4;
      *(ushort4*)(AlB + swz128(r, k4 * 2)) = l4;
    }
    #pragma unroll
    for (int q = 0; q < 4; ++q) {
      int lin = tid + 256 * q;
      int n = lin >> 3, k8 = (lin & 7) << 3;
      *(uint4*)(BhB + swz128(n, k8 * 2)) = *(const uint4*)&W1h[(long)n * 256 + k0 + k8];
      *(uint4*)(BlB + swz128(n, k8 * 2)) = *(const uint4*)&W1l[(long)n * 256 + k0 + k8];
    }
    __syncthreads();
    #pragma unroll
    for (int ks = 0; ks < 2; ++ks) {
      const int ko = ks * 32 + (l >> 4) * 8;
      short8 ah  = *(const short8*)(AhB + swz128(ar, ko * 2));
      short8 al8 = *(const short8*)(AlB + swz128(ar, ko * 2));
      #pragma unroll
      for (int fc = 0; fc < 8; ++fc) {
        const int c = fc * 16 + (l & 15);
        short8 bh  = *(const short8*)(BhB + swz128(c, ko * 2));
        short8 bl8 = *(const short8*)(BlB + swz128(c, ko * 2));
        acc[fc] = __builtin_amdgcn_mfma_f32_16x16x32_bf16(al8, bh, acc[fc], 0, 0, 0);
        acc[fc] = __builtin_amdgcn_mfma_f32_16x16x32_bf16(ah, bl8, acc[fc], 0, 0, 0);
        acc[fc] = __builtin_amdgcn_mfma_f32_16x16x32_bf16(ah, bh, acc[fc], 0, 0, 0);
      }
    }
    __syncthreads();
  }
  // o1 -> LDS bf16-split
  #pragma unroll
  for (int fc = 0; fc < 8; ++fc) {
    int col = fc * 16 + (l & 15);
    float bv = b1[col];
    #pragma unroll
    for (int i = 0; i < 4; ++i) {
      int lr = crow + i;
      float v = fmaxf(acc[fc][i] + bv, 0.f);
      ushort h = f2bf(v);
      *(ushort*)(O1h + swz256(lr, col * 2)) = h;
      *(ushort*)(O1l + swz256(lr, col * 2)) = f2bf(v - bf2f(h));
    }
  }

  // phase 2: o2 = relu(o1 @ Wcl2 + b2), K=128
  #pragma unroll
  for (int fc = 0; fc < 8; ++fc) acc[fc] = (f32x4){0.f, 0.f, 0.f, 0.f};
  for (int k0 = 0; k0 < 128; k0 += 64) {
    __syncthreads();
    #pragma unroll
    for (int q = 0; q < 4; ++q) {
      int lin = tid + 256 * q;
      int n = lin >> 3, k8 = (lin & 7) << 3;
      *(uint4*)(BhB + swz128(n, k8 * 2)) = *(const uint4*)&W2h[n * 128 + k0 + k8];
      *(uint4*)(BlB + swz128(n, k8 * 2)) = *(const uint4*)&W2l[n * 128 + k0 + k8];
    }
    __syncthreads();
    #pragma unroll
    for (int ks = 0; ks < 2; ++ks) {
      const int ko = ks * 32 + (l >> 4) * 8;
      short8 ah  = *(const short8*)(O1h + swz256(ar, (k0 + ko) * 2));
      short8 al8 = *(const short8*)(O1l + swz256(ar, (k0 + ko) * 2));
      #pragma unroll
      for (int fc = 0; fc < 8; ++fc) {
        const int c = fc * 16 + (l & 15);
        short8 bh  = *(const short8*)(BhB + swz128(c, ko * 2));
        short8 bl8 = *(const short8*)(BlB + swz128(c, ko * 2));
        acc[fc] = __builtin_amdgcn_mfma_f32_16x16x32_bf16(al8, bh, acc[fc], 0, 0, 0);
        acc[fc] = __builtin_amdgcn_mfma_f32_16x16x32_bf16(ah, bl8, acc[fc], 0, 0, 0);
        acc[fc] = __builtin_amdgcn_mfma_f32_16x16x32_bf16(ah, bh, acc[fc], 0, 0, 0);
      }
    }
  }

  // phase 3: out = o2 @ Wcl3 + bcl3 (N=2), 16-lane shfl reduce
  float p0[4] = {0.f, 0.f, 0.f, 0.f}, p1[4] = {0.f, 0.f, 0.f, 0.f};
  #pragma unroll
  for (int fc = 0; fc < 8; ++fc) {
    int col = fc * 16 + (l & 15);
    float bv = b2[col];
    float w0 = Wcl3[col * 2], w1 = Wcl3[col * 2 + 1];
    #pragma unroll
    for (int i = 0; i < 4; ++i) {
      float v = fmaxf(acc[fc][i] + bv, 0.f);
      p0[i] = fmaf(v, w0, p0[i]);
      p1[i] = fmaf(v, w1, p1[i]);
    }
  }
  #pragma unroll
  for (int i = 0; i < 4; ++i) {
    #pragma unroll
    for (int m = 1; m < 16; m <<= 1) {
      p0[i] += __shfl_xor(p0[i], m);
      p1[i] += __shfl_xor(p1[i], m);
    }
    if ((l & 15) == 0) {
      long row = rowBase + crow + i;
      out[row * 2 + 0] = p0[i] + bcl3[0];
      out[row * 2 + 1] = p1[i] + bcl3[1];
    }
  }
}

// ---------------------------------------------------------------------------
// zfold via MFMA (validated round 8, unchanged).
// ---------------------------------------------------------------------------
__global__ __launch_bounds__(256, 1) void zfold_mfma_kernel(
    const float* __restrict__ xp,
    const ushort* __restrict__ We2h, const ushort* __restrict__ We2l,
    const float* __restrict__ interhb, const float* __restrict__ ia1,
    const float* __restrict__ ia2, const float* __restrict__ We1,
    const float* __restrict__ be1,
    float* __restrict__ aggA, float* __restrict__ aggB)
{
  __shared__ __align__(16) ushort Ah[2][64 * 72], Al[2][64 * 72];
  __shared__ __align__(16) ushort Bh[128 * 72], Bl[128 * 72];
  __shared__ float accAs[32 * 128], accBs[32 * 128];
  __shared__ float ehs[3][32][8];
  const int tid = threadIdx.x;
  const int w = tid >> 6, l = tid & 63;
  const int rg = blockIdx.x >> 2, kq = blockIdx.x & 3;
  const int i0 = rg * 32;

  for (int t = tid; t < 2048; t += 256) {
    int r = t >> 5, k4 = (t & 31) << 2;
    int gr = (r < 32) ? (i0 + r) : (B2 + i0 + r - 32);
    float4 v = *(const float4*)&xp[(long)gr * 128 + k4];
    int ch = k4 >> 6, ko = k4 & 63;
    ushort4 h4, l4;
    h4.x = f2bf(v.x); l4.x = f2bf(v.x - bf2f(h4.x));
    h4.y = f2bf(v.y); l4.y = f2bf(v.y - bf2f(h4.y));
    h4.z = f2bf(v.z); l4.z = f2bf(v.z - bf2f(h4.z));
    h4.w = f2bf(v.w); l4.w = f2bf(v.w - bf2f(h4.w));
    *(ushort4*)&Ah[ch][r * 72 + ko] = h4;
    *(ushort4*)&Al[ch][r * 72 + ko] = l4;
  }
  for (int t = tid; t < 768; t += 256) {
    int grp = t >> 8, rem = t & 255;
    int mm = rem >> 3, kk = rem & 7;
    int k = kq * 8 + kk;
    float u = (grp == 0) ? interhb[i0 + mm] : (grp == 1) ? ia1[i0 + mm] : ia2[i0 + mm];
    ehs[grp][mm][kk] = fmaxf(fmaf(u, We1[k], be1[k]), 0.f);
  }
  for (int t = tid; t < 4096; t += 256) { accAs[t] = 0.f; accBs[t] = 0.f; }

  float foldA[8][4] = {{0.f}}, foldB[8][4] = {{0.f}};
  const int ar = w * 16 + (l & 15);

  for (int kk = 0; kk < 8; ++kk) {
    const int k = kq * 8 + kk;
    f32x4 acc[8];
    #pragma unroll
    for (int fc = 0; fc < 8; ++fc) acc[fc] = (f32x4){0.f, 0.f, 0.f, 0.f};
    for (int ch = 0; ch < 2; ++ch) {
      __syncthreads();
      #pragma unroll
      for (int q = 0; q < 4; ++q) {
        int lin = tid + 256 * q;
        int n = lin >> 3, k8 = (lin & 7) << 3;
        *(uint4*)&Bh[n * 72 + k8] = *(const uint4*)&We2h[k * 16384 + n * 128 + ch * 64 + k8];
        *(uint4*)&Bl[n * 72 + k8] = *(const uint4*)&We2l[k * 16384 + n * 128 + ch * 64 + k8];
      }
      __syncthreads();
      #pragma unroll
      for (int ks = 0; ks < 2; ++ks) {
        const int ko = ks * 32 + (l >> 4) * 8;
        short8 ah  = *(const short8*)&Ah[ch][ar * 72 + ko];
        short8 al8 = *(const short8*)&Al[ch][ar * 72 + ko];
        #pragma unroll
        for (int fc = 0; fc < 8; ++fc) {
          const int c = fc * 16 + (l & 15);
          short8 bh  = *(const short8*)&Bh[c * 72 + ko];
          short8 bl8 = *(const short8*)&Bl[c * 72 + ko];
          acc[fc] = __builtin_amdgcn_mfma_f32_16x16x32_bf16(al8, bh, acc[fc], 0, 0, 0);
          acc[fc] = __builtin_amdgcn_mfma_f32_16x16x32_bf16(ah, bl8, acc[fc], 0, 0, 0);
          acc[fc] = __builtin_amdgcn_mfma_f32_16x16x32_bf16(ah, bh, acc[fc], 0, 0, 0);
        }
      }
    }
    #pragma unroll
    for (int i = 0; i < 4; ++i) {
      int lr = w * 16 + ((l >> 4) << 2) + i;
      int m = lr & 31, up = lr >> 5;
      float eA = up ? ehs[0][m][kk] : ehs[1][m][kk];
      float eB = up ? ehs[2][m][kk] : ehs[0][m][kk];
      #pragma unroll
      for (int fc = 0; fc < 8; ++fc) {
        foldA[fc][i] = fmaf(eA, acc[fc][i], foldA[fc][i]);
        foldB[fc][i] = fmaf(eB, acc[fc][i], foldB[fc][i]);
      }
    }
  }
  #pragma unroll
  for (int i = 0; i < 4; ++i) {
    int lr = w * 16 + ((l >> 4) << 2) + i;
    int m = lr & 31;
    #pragma unroll
    for (int fc = 0; fc < 8; ++fc) {
      int c = fc * 16 + (l & 15);
      atomicAdd(&accAs[m * 128 + c], foldA[fc][i]);
      atomicAdd(&accBs[m * 128 + c], foldB[fc][i]);
    }
  }
  __syncthreads();
  for (int t = tid; t < 4096; t += 256) {
    int mm = t >> 7, c = t & 127;
    atomicAdd(&aggA[(long)(i0 + mm) * 128 + c], accAs[t]);
    atomicAdd(&aggB[(long)(i0 + mm) * 128 + c], accBs[t]);
  }
}

// ---------------------------------------------------------------------------
// adj: normalized dense adjacency Â[d][s] = cnt(s->d)*rsI[d]*rsO[s].
// ---------------------------------------------------------------------------
__global__ __launch_bounds__(256) void adj_kernel(
    const int* __restrict__ src1, const int* __restrict__ dst1,
    const int* __restrict__ src2, const int* __restrict__ dst2,
    float* __restrict__ Abuf)
{
  __shared__ float cnt[4][30 * 33];
  __shared__ float rsOa[4][32], rsIa[4][32];
  const int tid = threadIdx.x, wid = tid >> 6, lane = tid & 63;
  const int gm = blockIdx.x * 4 + wid;
  const int g = gm >> 11, m = gm & 2047;
  const int* src = g ? src2 : src1;
  const int* dst = g ? dst2 : dst1;

  for (int i = lane; i < 30 * 33; i += 64) cnt[wid][i] = 0.f;
  __syncthreads();
  for (int e = lane; e < EPM; e += 64) {
    int s = src[m * EPM + e] - m * NPM;
    int d = dst[m * EPM + e] - m * NPM;
    atomicAdd(&cnt[wid][d * 33 + s], 1.0f);
  }
  __syncthreads();
  if (lane < NPM) {
    float sum = 0.f;
    for (int s = 0; s < NPM; ++s) sum += cnt[wid][lane * 33 + s];
    rsIa[wid][lane] = rsqrtf(fmaxf(sum, 1.f));
  } else if (lane >= 32 && lane < 32 + NPM) {
    int s = lane - 32; float sum = 0.f;
    for (int d = 0; d < NPM; ++d) sum += cnt[wid][d * 33 + s];
    rsOa[wid][s] = rsqrtf(fmaxf(sum, 1.f));
  }
  __syncthreads();
  const long base = (long)gm * 960;
  for (int i = lane; i < 960; i += 64) {
    int d = i >> 5, s = i & 31;
    float v = (d < NPM && s < NPM)
            ? cnt[wid][d * 33 + s] * rsIa[wid][d] * rsOa[wid][s] : 0.f;
    Abuf[base + i] = v;
  }
}

// ---------------------------------------------------------------------------
// FULLY-FUSED ALL-MFMA GraphConv (validated round 12, unchanged).
// ---------------------------------------------------------------------------
__global__ __launch_bounds__(512, 4) void gconv_kernel(
    const float* __restrict__ h1, const float* __restrict__ h2,
    const float* __restrict__ Abuf, const float* __restrict__ bg1,
    const ushort* __restrict__ W1h, const ushort* __restrict__ W1l,
    const ushort* __restrict__ W2h, const ushort* __restrict__ W2l,
    const float* __restrict__ bias2, const float* __restrict__ s1x,
    float* __restrict__ xcat)
{
  __shared__ __align__(16) char pool[66560];
  char* AhB = pool;
  char* AlB = pool + 16384;
  char* BhB = pool + 32768;
  char* BlB = pool + 49152;
  char* A2h = pool;
  char* A2l = pool + 8192;
  char* Byh = pool + 32768;
  char* Byl = pool + 49152;
  float* cs = (float*)(pool + 65536);

  const int tid = threadIdx.x;
  const int p = blockIdx.x;
  const int g = p >> 10;
  const int mloc = (p & 1023) * 2;
  const float* hsrc = g ? h2 : h1;
  if (tid < 256) cs[tid] = 0.f;

  const int w8 = tid >> 6, l = tid & 63;
  const int rw = w8 & 3;
  const int ch2 = w8 >> 2;
  const int ar = rw * 16 + (l & 15);
  const int crow = rw * 16 + ((l >> 4) << 2);

  #pragma unroll
  for (int q = 0; q < 4; ++q) {
    int lin = tid + 512 * q;
    int r = lin >> 5, k4 = (lin & 31) << 2;
    float4 v = make_float4(0.f, 0.f, 0.f, 0.f);
    if (r < 60) {
      const float* Ar = &hsrc[(long)(mloc * 30 + r) * 74];
      if (k4 + 4 <= 74) {
        float2 a = *(const float2*)&Ar[k4];
        float2 b = *(const float2*)&Ar[k4 + 2];
        v = make_float4(a.x, a.y, b.x, b.y);
      } else if (k4 + 2 <= 74) {
        float2 a = *(const float2*)&Ar[k4];
        v.x = a.x; v.y = a.y;
      }
    }
    ushort4 h4, l4;
    h4.x = f2bf(v.x); l4.x = f2bf(v.x - bf2f(h4.x));
    h4.y = f2bf(v.y); l4.y = f2bf(v.y - bf2f(h4.y));
    h4.z = f2bf(v.z); l4.z = f2bf(v.z - bf2f(h4.z));
    h4.w = f2bf(v.w); l4.w = f2bf(v.w - bf2f(h4.w));
    *(ushort4*)(AhB + swz256(r, k4 * 2)) = h4;
    *(ushort4*)(AlB + swz256(r, k4 * 2)) = l4;
  }
  __syncthreads();

  f32x4 acc[4];
  #pragma unroll
  for (int fc = 0; fc < 4; ++fc) acc[fc] = (f32x4){0.f, 0.f, 0.f, 0.f};
  for (int k0 = 0; k0 < 128; k0 += 64) {
    #pragma unroll
    for (int q = 0; q < 2; ++q) {
      int lin = tid + 512 * q;
      int n = lin >> 3, k8 = (lin & 7) << 3;
      *(uint4*)(BhB + swz128(n, k8 * 2)) = *(const uint4*)&W1h[n * 128 + k0 + k8];
      *(uint4*)(BlB + swz128(n, k8 * 2)) = *(const uint4*)&W1l[n * 128 + k0 + k8];
    }
    __syncthreads();
    #pragma unroll
    for (int ks = 0; ks < 2; ++ks) {
      const int ko = ks * 32 + (l >> 4) * 8;
      short8 ah  = *(const short8*)(AhB + swz256(ar, (k0 + ko) * 2));
      short8 al8 = *(const short8*)(AlB + swz256(ar, (k0 + ko) * 2));
      #pragma unroll
      for (int fc = 0; fc < 4; ++fc) {
        const int c = ch2 * 64 + fc * 16 + (l & 15);
        short8 bh  = *(const short8*)(BhB + swz128(c, ko * 2));
        short8 bl8 = *(const short8*)(BlB + swz128(c, ko * 2));
        acc[fc] = __builtin_amdgcn_mfma_f32_16x16x32_bf16(al8, bh, acc[fc], 0, 0, 0);
        acc[fc] = __builtin_amdgcn_mfma_f32_16x16x32_bf16(ah, bl8, acc[fc], 0, 0, 0);
        acc[fc] = __builtin_amdgcn_mfma_f32_16x16x32_bf16(ah, bh, acc[fc], 0, 0, 0);
      }
    }
    __syncthreads();
  }

  {
    const long ab0 = (long)(g * 2048 + mloc) * 960;
    for (int t = tid; t < 4096; t += 512) {
      int row = t >> 6, k = t & 63;
      float v = 0.f;
      if (row < 30) { if (k < 30) v = Abuf[ab0 + row * 32 + k]; }
      else if (row < 60) { if (k >= 30 && k < 60) v = Abuf[ab0 + 960 + (row - 30) * 32 + (k - 30)]; }
      ushort h = f2bf(v);
      *(ushort*)(A2h + swz128(row, k * 2)) = h;
      *(ushort*)(A2l + swz128(row, k * 2)) = f2bf(v - bf2f(h));
    }
  }
  #pragma unroll
  for (int fc = 0; fc < 4; ++fc) {
    int n = ch2 * 64 + fc * 16 + (l & 15);
    ushort4 h4, l4;
    h4.x = f2bf(acc[fc][0]); l4.x = f2bf(acc[fc][0] - bf2f(h4.x));
    h4.y = f2bf(acc[fc][1]); l4.y = f2bf(acc[fc][1] - bf2f(h4.y));
    h4.z = f2bf(acc[fc][2]); l4.z = f2bf(acc[fc][2] - bf2f(h4.z));
    h4.w = f2bf(acc[fc][3]); l4.w = f2bf(acc[fc][3] - bf2f(h4.w));
    *(ushort4*)(Byh + swz128(n, crow * 2)) = h4;
    *(ushort4*)(Byl + swz128(n, crow * 2)) = l4;
  }
  __syncthreads();

  f32x4 acc2[4];
  #pragma unroll
  for (int fc = 0; fc < 4; ++fc) acc2[fc] = (f32x4){0.f, 0.f, 0.f, 0.f};
  #pragma unroll
  for (int ks = 0; ks < 2; ++ks) {
    const int ko = ks * 32 + (l >> 4) * 8;
    short8 ah  = *(const short8*)(A2h + swz128(ar, ko * 2));
    short8 al8 = *(const short8*)(A2l + swz128(ar, ko * 2));
    #pragma unroll
    for (int fc = 0; fc < 4; ++fc) {
      const int c = ch2 * 64 + fc * 16 + (l & 15);
      short8 bh  = *(const short8*)(Byh + swz128(c, ko * 2));
      short8 bl8 = *(const short8*)(Byl + swz128(c, ko * 2));
      acc2[fc] = __builtin_amdgcn_mfma_f32_16x16x32_bf16(al8, bh, acc2[fc], 0, 0, 0);
      acc2[fc] = __builtin_amdgcn_mfma_f32_16x16x32_bf16(ah, bl8, acc2[fc], 0, 0, 0);
      acc2[fc] = __builtin_amdgcn_mfma_f32_16x16x32_bf16(ah, bh, acc2[fc], 0, 0, 0);
    }
  }
  __syncthreads();

  #pragma unroll
  for (int fc = 0; fc < 4; ++fc) {
    int n = ch2 * 64 + fc * 16 + (l & 15);
    float bv = bg1[n];
    float t0 = fmaxf(acc2[fc][0] + bv, 0.f);
    float t1v = fmaxf(acc2[fc][1] + bv, 0.f);
    float t2v = fmaxf(acc2[fc][2] + bv, 0.f);
    float t3 = fmaxf(acc2[fc][3] + bv, 0.f);
    ushort4 h4, l4;
    h4.x = f2bf(t0); l4.x = f2bf(t0 - bf2f(h4.x));
    h4.y = f2bf(t1v); l4.y = f2bf(t1v - bf2f(h4.y));
    h4.z = f2bf(t2v); l4.z = f2bf(t2v - bf2f(h4.z));
    h4.w = f2bf(t3); l4.w = f2bf(t3 - bf2f(h4.w));
    *(ushort4*)(Byh + swz128(n, crow * 2)) = h4;
    *(ushort4*)(Byl + swz128(n, crow * 2)) = l4;
  }
  __syncthreads();

  #pragma unroll
  for (int fc = 0; fc < 4; ++fc) acc2[fc] = (f32x4){0.f, 0.f, 0.f, 0.f};
  #pragma unroll
  for (int ks = 0; ks < 2; ++ks) {
    const int ko = ks * 32 + (l >> 4) * 8;
    short8 ah  = *(const short8*)(A2h + swz128(ar, ko * 2));
    short8 al8 = *(const short8*)(A2l + swz128(ar, ko * 2));
    #pragma unroll
    for (int fc = 0; fc < 4; ++fc) {
      const int c = ch2 * 64 + fc * 16 + (l & 15);
      short8 bh  = *(const short8*)(Byh + swz128(c, ko * 2));
      short8 bl8 = *(const short8*)(Byl + swz128(c, ko * 2));
      acc2[fc] = __builtin_amdgcn_mfma_f32_16x16x32_bf16(al8, bh, acc2[fc], 0, 0, 0);
      acc2[fc] = __builtin_amdgcn_mfma_f32_16x16x32_bf16(ah, bl8, acc2[fc], 0, 0, 0);
      acc2[fc] = __builtin_amdgcn_mfma_f32_16x16x32_bf16(ah, bh, acc2[fc], 0, 0, 0);
    }
  }
  __syncthreads();

  #pragma unroll
  for (int fc = 0; fc < 4; ++fc) {
    int n = ch2 * 64 + fc * 16 + (l & 15);
    #pragma unroll
    for (int i = 0; i < 4; ++i) {
      int r = crow + i;
      ushort h = f2bf(acc2[fc][i]);
      *(ushort*)(AhB + swz256(r, n * 2)) = h;
      *(ushort*)(AlB + swz256(r, n * 2)) = f2bf(acc2[fc][i] - bf2f(h));
    }
  }

  #pragma unroll
  for (int fc = 0; fc < 4; ++fc) acc[fc] = (f32x4){0.f, 0.f, 0.f, 0.f};
  for (int k0 = 0; k0 < 128; k0 += 64) {
    __syncthreads();
    #pragma unroll
    for (int q = 0; q < 2; ++q) {
      int lin = tid + 512 * q;
      int n = lin >> 3, k8 = (lin & 7) << 3;
      *(uint4*)(BhB + swz128(n, k8 * 2)) = *(const uint4*)&W2h[n * 128 + k0 + k8];
      *(uint4*)(BlB + swz128(n, k8 * 2)) = *(const uint4*)&W2l[n * 128 + k0 + k8];
    }
    __syncthreads();
    #pragma unroll
    for (int ks = 0; ks < 2; ++ks) {
      const int ko = ks * 32 + (l >> 4) * 8;
      short8 ah  = *(const short8*)(AhB + swz256(ar, (k0 + ko) * 2));
      short8 al8 = *(const short8*)(AlB + swz256(ar, (k0 + ko) * 2));
      #pragma unroll
      for (int fc = 0; fc < 4; ++fc) {
        const int c = ch2 * 64 + fc * 16 + (l & 15);
        short8 bh  = *(const short8*)(BhB + swz128(c, ko * 2));
        short8 bl8 = *(const short8*)(BlB + swz128(c, ko * 2));
        acc[fc] = __builtin_amdgcn_mfma_f32_16x16x32_bf16(al8, bh, acc[fc], 0, 0, 0);
        acc[fc] = __builtin_amdgcn_mfma_f32_16x16x32_bf16(ah, bl8, acc[fc], 0, 0, 0);
        acc[fc] = __builtin_amdgcn_mfma_f32_16x16x32_bf16(ah, bh, acc[fc], 0, 0, 0);
      }
    }
  }
  __syncthreads();

  #pragma unroll
  for (int fc = 0; fc < 4; ++fc) {
    int col = ch2 * 64 + fc * 16 + (l & 15);
    float bv = bias2[col];
    float s0 = 0.f, s1 = 0.f;
    #pragma unroll
    for (int i = 0; i < 4; ++i) {
      int lr = crow + i;
      if (lr < 60) {
        float v = fmaxf(acc[fc][i] + bv, 0.f);
        if (lr < NPM) s0 += v; else s1 += v;
      }
    }
    s0 += __shfl_down(s0, 32); s0 += __shfl_down(s0, 16);
    s1 += __shfl_down(s1, 32); s1 += __shfl_down(s1, 16);
    if ((l >> 4) == 0) {
      atomicAdd(&cs[col], s0);
      atomicAdd(&cs[128 + col], s1);
    }
  }
  __syncthreads();
  if (tid < 256) {
    int moll = tid >> 7, c = tid & 127;
    int gm = p * 2 + moll;
    int gg = gm >> 11, mm = gm & 2047;
    float sf = gg ? (1.f - s1x[mm]) : s1x[mm];
    xcat[(long)gm * 128 + c] = cs[moll * 128 + c] * (1.f / 30.f) * sf;
  }
}

__global__ __launch_bounds__(256) void xin_kernel(
    const float* __restrict__ aggA, const float* __restrict__ aggB,
    const float* __restrict__ zb, const float* __restrict__ bnn,
    float* __restrict__ x_in)
{
  int idx = blockIdx.x * 256 + threadIdx.x;
  int i = idx >> 7, c = idx & 127;
  float zs = zb[i * 128 + c] + zb[(i + B2) * 128 + c] + bnn[c];
  x_in[i * 128 + c]        = fmaxf(aggA[idx] + zs, 0.f);
  x_in[(i + B2) * 128 + c] = fmaxf(aggB[idx] + zs, 0.f);
}

__global__ __launch_bounds__(256) void gru_kernel(
    const float* __restrict__ gi, const float* __restrict__ gh,
    const float* __restrict__ xp, float* __restrict__ xnew)
{
  int idx = blockIdx.x * 256 + threadIdx.x;
  int n = idx >> 7, j = idx & 127;
  float ir = gi[n * 384 + j], iz = gi[n * 384 + 128 + j], ih = gi[n * 384 + 256 + j];
  float hr = gh[n * 384 + j], hz = gh[n * 384 + 128 + j], hn = gh[n * 384 + 256 + j];
  float h  = xp[idx];
  float r  = 1.f / (1.f + expf(-(ir + hr)));
  float zg = 1.f / (1.f + expf(-(iz + hz)));
  float ng = tanhf(ih + r * hn);
  xnew[idx] = (1.f - zg) * ng + zg * h;
}

// ---------------------------------------------------------------------------
extern "C" void kernel_launch(void* const* d_in, const int* in_sizes, int n_in,
                              void* d_out, int out_size, void* d_ws, size_t ws_size,
                              hipStream_t stream)
{
  const float* h1   = (const float*)d_in[0];
  const float* h2   = (const float*)d_in[1];
  const float* s1x  = (const float*)d_in[2];
  const float* ihb  = (const float*)d_in[3];
  const float* ia1  = (const float*)d_in[4];
  const float* ia2  = (const float*)d_in[5];
  const float* Wg1  = (const float*)d_in[6];
  const float* bg1  = (const float*)d_in[7];
  const float* Wg2  = (const float*)d_in[8];
  const float* bg2  = (const float*)d_in[9];
  const float* Wp   = (const float*)d_in[10];
  const float* bp   = (const float*)d_in[11];
  const float* We1  = (const float*)d_in[12];
  const float* be1  = (const float*)d_in[13];
  const float* We2  = (const float*)d_in[14];
  const float* be2  = (const float*)d_in[15];
  const float* bnn  = (const float*)d_in[16];
  const float* Wih  = (const float*)d_in[17];
  const float* bih  = (const float*)d_in[18];
  const float* Whh  = (const float*)d_in[19];
  const float* bhh  = (const float*)d_in[20];
  const float* Wcl1 = (const float*)d_in[21];
  const float* bcl1 = (const float*)d_in[22];
  const float* Wcl2 = (const float*)d_in[23];
  const float* bcl2 = (const float*)d_in[24];
  const float* Wcl3 = (const float*)d_in[25];
  const float* bcl3 = (const float*)d_in[26];
  const int*   src1 = (const int*)d_in[27];
  const int*   dst1 = (const int*)d_in[28];
  const int*   src2 = (const int*)d_in[29];
  const int*   dst2 = (const int*)d_in[30];
  float* out = (float*)d_out;
  float* ws  = (float*)d_ws;

  float* Abuf = ws;                          // 3,932,160
  float* dwn  = ws + 35389440;

  float* xcat = dwn;
  float* xp   = dwn + 524288;
  float* zb   = dwn + 1048576;
  float* aggA = dwn + 1572864;
  float* aggB = dwn + 1835008;
  float* x_in = dwn + 2097152;
  float* gi   = dwn + 2621440;
  float* gh   = dwn + 4194304;
  float* xnew = dwn + 5767168;

  ushort* wt     = (ushort*)(dwn + 6815744);
  ushort* WpTh   = wt;               ushort* WpTl   = wt + 16384;
  ushort* be2Th  = wt + 32768;       ushort* be2Tl  = wt + 49152;
  ushort* WihTh  = wt + 65536;       ushort* WihTl  = wt + 114688;
  ushort* WhhTh  = wt + 163840;      ushort* WhhTl  = wt + 212992;
  ushort* Wcl1Th = wt + 262144;      ushort* Wcl1Tl = wt + 294912;
  ushort* Wcl2Th = wt + 327680;      ushort* Wcl2Tl = wt + 344064;
  ushort* Wg1Th  = wt + 360448;      ushort* Wg1Tl  = wt + 376832;
  ushort* Wg2Th  = wt + 393216;      ushort* Wg2Tl  = wt + 409600;
  ushort* We2h   = wt + 425984;      ushort* We2l   = wt + 950272;

  // ---- fused weight prep (8 weights in one launch) ----
  PrepDescs pd;
  const float* Ws_[8]  = {Wp, be2, Wih, Whh, Wcl1, Wcl2, Wg1, Wg2};
  ushort* his[8]       = {WpTh, be2Th, WihTh, WhhTh, Wcl1Th, Wcl2Th, Wg1Th, Wg2Th};
  ushort* los[8]       = {WpTl, be2Tl, WihTl, WhhTl, Wcl1Tl, Wcl2Tl, Wg1Tl, Wg2Tl};
  int kr[8]   = {128, 128, 128, 128, 256, 128, 74, 128};
  int kp[8]   = {128, 128, 128, 128, 256, 128, 128, 128};
  int nn[8]   = {128, 128, 384, 384, 128, 128, 128, 128};
  int acc_blk = 0;
  for (int i = 0; i < 8; ++i) {
    pd.W[i] = Ws_[i]; pd.hi[i] = his[i]; pd.lo[i] = los[i];
    pd.Kreal[i] = kr[i]; pd.Kpad[i] = kp[i]; pd.N[i] = nn[i];
    pd.blk0[i] = acc_blk;
    acc_blk += (nn[i] * (kp[i] >> 3) + 255) / 256;
  }
  pd.blk0[8] = acc_blk;
  prep_all_kernel<<<acc_blk, 256, 0, stream>>>(pd);
  prep_we2_kernel<<<256, 256, 0, stream>>>(We2, We2h, We2l);

  // ---- fully-fused GraphConv ----
  adj_kernel<<<1024, 256, 0, stream>>>(src1, dst1, src2, dst2, Abuf);
  gconv_kernel<<<2048, 512, 0, stream>>>(h1, h2, Abuf, bg1, Wg1Th, Wg1Tl,
                                         Wg2Th, Wg2Tl, bg2, s1x, xcat);

  // ---- solvent-system MPNN + GRU + classifier ----
  xpzb_kernel<<<64, 256, 0, stream>>>(xcat, WpTh, WpTl, bp, be2Th, be2Tl, xp, zb);
  hipMemsetAsync(aggA, 0, 2 * 262144 * sizeof(float), stream);
  zfold_mfma_kernel<<<256, 256, 0, stream>>>(xp, We2h, We2l, ihb, ia1, ia2,
                                             We1, be1, aggA, aggB);
  xin_kernel<<<1024, 256, 0, stream>>>(aggA, aggB, zb, bnn, x_in);
  gemm_mfma_kernel<0, 1><<<dim3(64, 12), 128, 0, stream>>>(
      x_in, WihTh, WihTl, bih, gi, 384, 128, 128);
  gemm_mfma_kernel<0, 1><<<dim3(64, 12), 128, 0, stream>>>(
      xp, WhhTh, WhhTl, bhh, gh, 384, 128, 128);
  gru_kernel<<<2048, 256, 0, stream>>>(gi, gh, xp, xnew);
  cls_kernel<<<32, 256, 0, stream>>>(xnew, Wcl1Th, Wcl1Tl, bcl1,
                                     Wcl2Th, Wcl2Tl, bcl2, Wcl3, bcl3, out);
}